// Round 10
// baseline (238.395 us; speedup 1.0000x reference)
//
#include <hip/hip_runtime.h>
#include <hip/hip_bf16.h>

#define NU 50000
#define NI 20000
#define NN 70000
#define DD 128
#define BB 8192
#define EE 500000
#define ET 570000   // EE + NN self loops
#define NTASK 16384 // 2*BB

__device__ __forceinline__ float lrelu(float x) { return x > 0.f ? x : 0.2f * x; }

typedef __attribute__((ext_vector_type(8))) short bf16x8;   // 8 bf16 = 4 VGPRs
typedef __attribute__((ext_vector_type(8))) unsigned short u16x8;
typedef __attribute__((ext_vector_type(4))) float f32x4;

__device__ __forceinline__ unsigned short f2bf_rne(float f) {
  unsigned int u = __builtin_bit_cast(unsigned int, f);
  u += 0x7FFFu + ((u >> 16) & 1u);
  return (unsigned short)(u >> 16);
}
__device__ __forceinline__ float bf2f(unsigned short h) {
  unsigned int u = ((unsigned int)h) << 16;
  return __builtin_bit_cast(float, u);
}

// ---------------- MFMA GEMM core (device fn): C[M,N] = A * Bt^T (+bias)(+relu) ----
template <int GATHER, int MODE>
__device__ __forceinline__ void gemm_core(
    int bm, int bn,
    const float* __restrict__ A,
    const unsigned short* __restrict__ Bh, const unsigned short* __restrict__ Bl,
    const float* __restrict__ bias, float* __restrict__ C,
    unsigned short* __restrict__ Cb, int ldc,
    int M, int N, int K, int act,
    const int* __restrict__ idx0, const int* __restrict__ idx1,
    const int* __restrict__ mapv,
    const float* __restrict__ gA0, const float* __restrict__ gA1,
    const float* __restrict__ att_s, const float* __restrict__ att_d,
    float* __restrict__ a1s, float* __restrict__ a1d) {
  __shared__ __align__(16) unsigned short sAh[8][64][8];
  __shared__ __align__(16) unsigned short sAl[8][64][8];
  __shared__ __align__(16) unsigned short sBh[8][64][8];
  __shared__ __align__(16) unsigned short sBl[8][64][8];
  int tid = threadIdx.x;
  int lane = tid & 63, w = tid >> 6;
  int wr = (w >> 1) * 32, wc = (w & 1) * 32;
  int fr = lane & 15, fk = lane >> 4;
  f32x4 acc[2][2] = {};

  for (int k0 = 0; k0 < K; k0 += 64) {
    __syncthreads();
#pragma unroll
    for (int t = 0; t < 2; t++) {
      int f = tid + t * 256;
      int row = f >> 3, kb = f & 7;
      int kg = k0 + kb * 8;
      const float* ap;
      if (GATHER == 1) {
        int sec = kg >> 7;           // 64-tiles never straddle 128-col sections
        int kc = kg & 127;
        int r = bm + row;
        if (sec == 0)      ap = &gA0[(size_t)idx0[r] * 128 + kc];
        else if (sec == 1) ap = &gA1[(size_t)mapv[NU + idx1[r]] * 128 + kc];
        else               ap = &gA1[(size_t)mapv[idx0[r]] * 128 + kc];
      } else if (GATHER == 2) {
        ap = &gA0[(size_t)idx0[bm + row] * K + kg];
      } else {
        ap = &A[(size_t)(bm + row) * K + kg];
      }
      float4 v0 = *reinterpret_cast<const float4*>(ap);
      float4 v1 = *reinterpret_cast<const float4*>(ap + 4);
      float vv[8] = {v0.x, v0.y, v0.z, v0.w, v1.x, v1.y, v1.z, v1.w};
      u16x8 hv, lv;
#pragma unroll
      for (int j = 0; j < 8; j++) {
        unsigned short hh = f2bf_rne(vv[j]);
        hv[j] = hh;
        lv[j] = (unsigned short)(__builtin_bit_cast(unsigned int, vv[j] - bf2f(hh)) >> 16);
      }
      *reinterpret_cast<u16x8*>(&sAh[kb][row][0]) = hv;
      *reinterpret_cast<u16x8*>(&sAl[kb][row][0]) = lv;
    }
#pragma unroll
    for (int t = 0; t < 2; t++) {
      int f = tid + t * 256;
      int row = f >> 3, kb = f & 7;
      int kg = k0 + kb * 8;
      *reinterpret_cast<u16x8*>(&sBh[kb][row][0]) =
          *reinterpret_cast<const u16x8*>(&Bh[(size_t)(bn + row) * K + kg]);
      *reinterpret_cast<u16x8*>(&sBl[kb][row][0]) =
          *reinterpret_cast<const u16x8*>(&Bl[(size_t)(bn + row) * K + kg]);
    }
    __syncthreads();
#pragma unroll
    for (int s = 0; s < 2; s++) {
      int kb = s * 4 + fk;
      bf16x8 ah0 = *reinterpret_cast<const bf16x8*>(&sAh[kb][wr + fr][0]);
      bf16x8 ah1 = *reinterpret_cast<const bf16x8*>(&sAh[kb][wr + 16 + fr][0]);
      bf16x8 al0 = *reinterpret_cast<const bf16x8*>(&sAl[kb][wr + fr][0]);
      bf16x8 al1 = *reinterpret_cast<const bf16x8*>(&sAl[kb][wr + 16 + fr][0]);
      bf16x8 bh0 = *reinterpret_cast<const bf16x8*>(&sBh[kb][wc + fr][0]);
      bf16x8 bh1 = *reinterpret_cast<const bf16x8*>(&sBh[kb][wc + 16 + fr][0]);
      bf16x8 bl0 = *reinterpret_cast<const bf16x8*>(&sBl[kb][wc + fr][0]);
      bf16x8 bl1 = *reinterpret_cast<const bf16x8*>(&sBl[kb][wc + 16 + fr][0]);
      acc[0][0] = __builtin_amdgcn_mfma_f32_16x16x32_bf16(al0, bh0, acc[0][0], 0, 0, 0);
      acc[0][0] = __builtin_amdgcn_mfma_f32_16x16x32_bf16(ah0, bl0, acc[0][0], 0, 0, 0);
      acc[0][0] = __builtin_amdgcn_mfma_f32_16x16x32_bf16(ah0, bh0, acc[0][0], 0, 0, 0);
      acc[0][1] = __builtin_amdgcn_mfma_f32_16x16x32_bf16(al0, bh1, acc[0][1], 0, 0, 0);
      acc[0][1] = __builtin_amdgcn_mfma_f32_16x16x32_bf16(ah0, bl1, acc[0][1], 0, 0, 0);
      acc[0][1] = __builtin_amdgcn_mfma_f32_16x16x32_bf16(ah0, bh1, acc[0][1], 0, 0, 0);
      acc[1][0] = __builtin_amdgcn_mfma_f32_16x16x32_bf16(al1, bh0, acc[1][0], 0, 0, 0);
      acc[1][0] = __builtin_amdgcn_mfma_f32_16x16x32_bf16(ah1, bl0, acc[1][0], 0, 0, 0);
      acc[1][0] = __builtin_amdgcn_mfma_f32_16x16x32_bf16(ah1, bh0, acc[1][0], 0, 0, 0);
      acc[1][1] = __builtin_amdgcn_mfma_f32_16x16x32_bf16(al1, bh1, acc[1][1], 0, 0, 0);
      acc[1][1] = __builtin_amdgcn_mfma_f32_16x16x32_bf16(ah1, bl1, acc[1][1], 0, 0, 0);
      acc[1][1] = __builtin_amdgcn_mfma_f32_16x16x32_bf16(ah1, bh1, acc[1][1], 0, 0, 0);
    }
  }
  if (MODE == 1) {
    int head = bn >> 7;
    float ps[2][4] = {{0.f}}, pd[2][4] = {{0.f}};
#pragma unroll
    for (int j = 0; j < 2; j++) {
      int col = bn + wc + j * 16 + fr;
      float asc = att_s[col], adc = att_d[col];
#pragma unroll
      for (int i = 0; i < 2; i++) {
#pragma unroll
        for (int r = 0; r < 4; r++) {
          float v = acc[i][j][r];
          ps[i][r] += v * asc;
          pd[i][r] += v * adc;
          Cb[(size_t)(bm + wr + i * 16 + fk * 4 + r) * ldc + col] = f2bf_rne(v);
        }
      }
    }
#pragma unroll
    for (int o = 1; o < 16; o <<= 1) {
#pragma unroll
      for (int i = 0; i < 2; i++)
#pragma unroll
        for (int r = 0; r < 4; r++) {
          ps[i][r] += __shfl_xor(ps[i][r], o);
          pd[i][r] += __shfl_xor(pd[i][r], o);
        }
    }
    if (fr == 0) {
#pragma unroll
      for (int i = 0; i < 2; i++) {
#pragma unroll
        for (int r = 0; r < 4; r++) {
          int t = bm + wr + i * 16 + fk * 4 + r;
          int v = (t < BB) ? idx0[t] : NU + idx1[t - BB];
          if (mapv[v] == t) {   // rep task only (dups would double-count)
            atomicAdd(&a1s[(size_t)v * 2 + head], ps[i][r]);
            atomicAdd(&a1d[(size_t)v * 2 + head], pd[i][r]);
          }
        }
      }
    }
    return;
  }
#pragma unroll
  for (int j = 0; j < 2; j++) {
    int col = bn + wc + j * 16 + fr;
    float bj = bias ? bias[col] : 0.f;
#pragma unroll
    for (int i = 0; i < 2; i++) {
#pragma unroll
      for (int r = 0; r < 4; r++) {
        int row = bm + wr + i * 16 + fk * 4 + r;
        float v = acc[i][j][r] + bj;
        if (act == 1) v = fmaxf(v, 0.f);
        C[(size_t)row * ldc + col] = v;
      }
    }
  }
}

template <int GATHER, int MODE>
__global__ __launch_bounds__(256) void gemm_mfma(
    const float* __restrict__ A,
    const unsigned short* __restrict__ Bh, const unsigned short* __restrict__ Bl,
    const float* __restrict__ bias, float* __restrict__ C,
    unsigned short* __restrict__ Cb, int ldc,
    int M, int N, int K, int act,
    const int* __restrict__ idx0, const int* __restrict__ idx1,
    const int* __restrict__ mapv,
    const float* __restrict__ gA0, const float* __restrict__ gA1,
    const float* __restrict__ att_s, const float* __restrict__ att_d,
    float* __restrict__ a1s, float* __restrict__ a1d) {
  gemm_core<GATHER, MODE>(blockIdx.x * 64, blockIdx.y * 64,
                          A, Bh, Bl, bias, C, Cb, ldc, M, N, K, act,
                          idx0, idx1, mapv, gA0, gA1, att_s, att_d, a1s, a1d);
}

// cemb GEMM (gather-A) + CSR fill + needed-mark in ONE launch (independent work).
#define GEMMB 256  // (BB/64) * (DD/64)
__global__ __launch_bounds__(256) void cembfill_kernel(
    const unsigned short* __restrict__ wch, const unsigned short* __restrict__ wcl,
    const float* __restrict__ bc, float* __restrict__ XaC,
    const int* __restrict__ widx, const float* __restrict__ content,
    const int* __restrict__ ei, int* __restrict__ fill, int* __restrict__ col,
    const int* __restrict__ mapv, unsigned char* __restrict__ needed) {
  int bid = blockIdx.x;
  if (bid < GEMMB) {
    gemm_core<2, 0>((bid >> 1) * 64, (bid & 1) * 64,
                    nullptr, wch, wcl, bc, XaC, nullptr, 256,
                    BB, DD, 512, 0, widx, nullptr, nullptr, content, nullptr,
                    nullptr, nullptr, nullptr, nullptr);
    return;
  }
  int e = (bid - GEMMB) * 256 + threadIdx.x;
  if (e >= ET) return;
  int src, dst;
  if (e < EE) { src = ei[e]; dst = ei[EE + e]; }
  else { src = e - EE; dst = src; }
  int pos = atomicAdd(&fill[dst], 1);
  col[pos] = src;
  if (mapv[dst] >= 0) needed[src] = 1;
}

// ---------------- mega-setup: deg+winner atomics | weight split | Xa-emb+map ------
#define EB 2227    // ceil(ET/256)
#define SPLB 832   // (65536+65536+32768+49152)/256
#define XAB 4096   // NTASK/4
__global__ __launch_bounds__(256) void setup_kernel(
    const int* __restrict__ ei, const int* __restrict__ uid, const int* __restrict__ iid,
    int* __restrict__ deg, int* __restrict__ winner,
    const float* __restrict__ wc, unsigned short* wch, unsigned short* wcl,
    const float* __restrict__ w1, unsigned short* w1h, unsigned short* w1l,
    const float* __restrict__ w2, unsigned short* w2h, unsigned short* w2l,
    const float* __restrict__ pw1, unsigned short* p1h, unsigned short* p1l,
    const float* __restrict__ uemb, const float* __restrict__ iemb,
    float* __restrict__ Xa, int* __restrict__ map) {
  int bid = blockIdx.x, tid = threadIdx.x;
  if (bid < EB) {
    int e = bid * 256 + tid;
    if (e < BB) atomicMax(&winner[iid[e]], e);
    if (e >= ET) return;
    int dst = (e < EE) ? ei[EE + e] : (e - EE);
    atomicAdd(&deg[dst], 1);
    return;
  }
  if (bid < EB + SPLB) {
    int i = (bid - EB) * 256 + tid;
    const float* w; unsigned short* h; unsigned short* l; int idx;
    if (i < 65536) { w = wc; h = wch; l = wcl; idx = i; }
    else if (i < 131072) { w = w1; h = w1h; l = w1l; idx = i - 65536; }
    else if (i < 163840) { w = w2; h = w2h; l = w2l; idx = i - 131072; }
    else { w = pw1; h = p1h; l = p1l; idx = i - 163840; }
    float f = w[idx];
    unsigned short hh = f2bf_rne(f);
    h[idx] = hh;
    l[idx] = (unsigned short)(__builtin_bit_cast(unsigned int, f - bf2f(hh)) >> 16);
    return;
  }
  int t = (bid - EB - SPLB) * 4 + (tid >> 6);
  int lane = tid & 63;
  int c4 = lane * 4;
  if (t < BB) {
    int u = uid[t];
    float4 v = make_float4(0.f, 0.f, 0.f, 0.f);
    if (c4 < DD) v = *reinterpret_cast<const float4*>(&uemb[(size_t)u * DD + c4]);
    *reinterpret_cast<float4*>(&Xa[(size_t)t * 256 + c4]) = v;
    if (lane == 0) map[u] = t;
  } else {
    int it = iid[t - BB];
    if (c4 < DD) {
      float4 v = *reinterpret_cast<const float4*>(&iemb[(size_t)it * DD + c4]);
      *reinterpret_cast<float4*>(&Xa[(size_t)t * 256 + c4]) = v;
    }
    if (lane == 0) map[NU + it] = t;
  }
}

// rowstart + widx; last block computes the conv2 q-vectors.
__global__ void rowstart_kernel(const int* __restrict__ deg, const int* __restrict__ winner,
                                const int* __restrict__ iid,
                                int* __restrict__ rowstart, int* __restrict__ fill,
                                int* __restrict__ counter, int* __restrict__ widx,
                                const float* __restrict__ w2,
                                const float* __restrict__ att2s, const float* __restrict__ att2d,
                                float* __restrict__ qs, float* __restrict__ qd) {
  int blk = blockIdx.x;
  if (blk == (NN + 255) / 256) {
    int k = threadIdx.x;
    float s = 0.f, d = 0.f;
#pragma unroll 4
    for (int j = 0; j < DD; j++) {
      float w = w2[(size_t)j * 256 + k];
      s += att2s[j] * w;
      d += att2d[j] * w;
    }
    qs[k] = s;
    qd[k] = d;
    return;
  }
  int v = blk * 256 + threadIdx.x;
  if (v < BB) widx[v] = winner[iid[v]];
  if (v >= NN) return;
  int s = atomicAdd(counter, deg[v]);
  rowstart[v] = s;
  fill[v] = s;
}

// W1: per-edge normalized conv1 softmax weights (both heads) + gather row index.
// 8 lanes per node, 32 nodes per 256-thread block.
__global__ __launch_bounds__(256) void w1_kernel(
    const int* __restrict__ col, const int* __restrict__ rowstart,
    const int* __restrict__ deg, const int* __restrict__ map,
    const unsigned char* __restrict__ needed,
    const float* __restrict__ a1s, const float* __restrict__ a1d,
    int* __restrict__ rbuf, float2* __restrict__ wbuf) {
  int v = blockIdx.x * 32 + (threadIdx.x >> 3);
  if (v >= NN || !needed[v]) return;
  int gl = threadIdx.x & 7;
  int d = deg[v], s0 = rowstart[v];
  float2 adv = *reinterpret_cast<const float2*>(&a1d[(size_t)v * 2]);
  // pass 1: max
  float m0 = -1e30f, m1 = -1e30f;
  for (int c0 = 0; c0 < d; c0 += 8) {
    int i = c0 + gl;
    if (i < d) {
      float2 as = *reinterpret_cast<const float2*>(&a1s[(size_t)col[s0 + i] * 2]);
      m0 = fmaxf(m0, lrelu(as.x + adv.x));
      m1 = fmaxf(m1, lrelu(as.y + adv.y));
    }
  }
#pragma unroll
  for (int o = 1; o < 8; o <<= 1) {
    m0 = fmaxf(m0, __shfl_xor(m0, o));
    m1 = fmaxf(m1, __shfl_xor(m1, o));
  }
  // pass 2: exp, den, write masked ex
  float den0 = 0.f, den1 = 0.f;
  for (int c0 = 0; c0 < d; c0 += 8) {
    int i = c0 + gl;
    if (i < d) {
      int c = col[s0 + i];
      float2 as = *reinterpret_cast<const float2*>(&a1s[(size_t)c * 2]);
      float e0 = __expf(lrelu(as.x + adv.x) - m0);
      float e1 = __expf(lrelu(as.y + adv.y) - m1);
      den0 += e0; den1 += e1;
      int r = map[c];
      float msk = r >= 0 ? 1.f : 0.f;
      rbuf[s0 + i] = r >= 0 ? r : 0;
      wbuf[s0 + i] = make_float2(e0 * msk, e1 * msk);
    }
  }
#pragma unroll
  for (int o = 1; o < 8; o <<= 1) {
    den0 += __shfl_xor(den0, o);
    den1 += __shfl_xor(den1, o);
  }
  float i0 = 1.f / den0, i1 = 1.f / den1;
  // pass 3: normalize
  for (int c0 = 0; c0 < d; c0 += 8) {
    int i = c0 + gl;
    if (i < d) {
      float2 w = wbuf[s0 + i];
      wbuf[s0 + i] = make_float2(w.x * i0, w.y * i1);
    }
  }
}

// W2: per-edge normalized conv2 softmax weights for rep tasks.
__global__ __launch_bounds__(256) void w2_kernel(
    const int* __restrict__ uid, const int* __restrict__ iid,
    const int* __restrict__ col, const int* __restrict__ rowstart,
    const int* __restrict__ deg, const int* __restrict__ map,
    const float* __restrict__ a2s, const float* __restrict__ a2d,
    float* __restrict__ wbuf2) {
  int t = blockIdx.x * 32 + (threadIdx.x >> 3);
  int v = (t < BB) ? uid[t] : NU + iid[t - BB];
  if (map[v] != t) return;
  int gl = threadIdx.x & 7;
  int d = deg[v], s0 = rowstart[v];
  float ad = a2d[v];
  float m = -1e30f;
  for (int c0 = 0; c0 < d; c0 += 8) {
    int i = c0 + gl;
    if (i < d) m = fmaxf(m, lrelu(a2s[col[s0 + i]] + ad));
  }
#pragma unroll
  for (int o = 1; o < 8; o <<= 1) m = fmaxf(m, __shfl_xor(m, o));
  float den = 0.f;
  for (int c0 = 0; c0 < d; c0 += 8) {
    int i = c0 + gl;
    if (i < d) {
      float e = __expf(lrelu(a2s[col[s0 + i]] + ad) - m);
      den += e;
      wbuf2[s0 + i] = e;
    }
  }
#pragma unroll
  for (int o = 1; o < 8; o <<= 1) den += __shfl_xor(den, o);
  float inv = 1.f / den;
  for (int c0 = 0; c0 < d; c0 += 8) {
    int i = c0 + gl;
    if (i < d) wbuf2[s0 + i] *= inv;
  }
}

// conv1 gather: branchless, shfl-free; weights prenormalized. 4 nodes/block.
__global__ __launch_bounds__(256) void conv1_agg_kernel(
    const int* __restrict__ rowstart, const int* __restrict__ deg,
    const unsigned short* __restrict__ Hb,
    const unsigned char* __restrict__ needed,
    const int* __restrict__ rbuf, const float2* __restrict__ wbuf,
    const float* __restrict__ bias,
    const float* __restrict__ qs, const float* __restrict__ qd,
    unsigned short* __restrict__ x1b, float* __restrict__ a2s, float* __restrict__ a2d) {
  int v = blockIdx.x * 4 + (threadIdx.x >> 6);
  int lane = threadIdx.x & 63;
  if (!needed[v]) return;
  int chead = lane >> 5;   // channels lane*4..+3; head = ch>=128
  int d = deg[v], s0 = rowstart[v];
  float4 acc = make_float4(0.f, 0.f, 0.f, 0.f);
#pragma unroll 2
  for (int i = 0; i < d; i++) {
    int r = rbuf[s0 + i];               // uniform -> broadcast
    float2 wv = wbuf[s0 + i];           // uniform -> broadcast
    float w = chead ? wv.y : wv.x;
    ushort4 hv = *reinterpret_cast<const ushort4*>(&Hb[((size_t)r << 8) + (lane << 2)]);
    acc.x += w * bf2f(hv.x); acc.y += w * bf2f(hv.y);
    acc.z += w * bf2f(hv.z); acc.w += w * bf2f(hv.w);
  }
  float4 b4 = *reinterpret_cast<const float4*>(&bias[lane << 2]);
  float4 o;
  o.x = acc.x + b4.x;
  o.y = acc.y + b4.y;
  o.z = acc.z + b4.z;
  o.w = acc.w + b4.w;
  o.x = o.x > 0.f ? o.x : __expf(o.x) - 1.f;
  o.y = o.y > 0.f ? o.y : __expf(o.y) - 1.f;
  o.z = o.z > 0.f ? o.z : __expf(o.z) - 1.f;
  o.w = o.w > 0.f ? o.w : __expf(o.w) - 1.f;
  ushort4 st;
  st.x = f2bf_rne(o.x); st.y = f2bf_rne(o.y);
  st.z = f2bf_rne(o.z); st.w = f2bf_rne(o.w);
  *reinterpret_cast<ushort4*>(&x1b[((size_t)v << 8) + (lane << 2)]) = st;
  // fused conv2 scores
  float4 sv = *reinterpret_cast<const float4*>(&qs[lane << 2]);
  float4 dv = *reinterpret_cast<const float4*>(&qd[lane << 2]);
  float ps = o.x * sv.x + o.y * sv.y + o.z * sv.z + o.w * sv.w;
  float pd = o.x * dv.x + o.y * dv.y + o.z * dv.z + o.w * dv.w;
#pragma unroll
  for (int of = 1; of < 64; of <<= 1) { ps += __shfl_xor(ps, of); pd += __shfl_xor(pd, of); }
  if (lane == 0) { a2s[v] = ps; a2d[v] = pd; }
}

// conv2 gather: rep tasks only; branchless, weights prenormalized.
__global__ __launch_bounds__(256) void conv2_agg_kernel(
    const int* __restrict__ uid, const int* __restrict__ iid,
    const int* __restrict__ col, const int* __restrict__ rowstart,
    const int* __restrict__ deg, const int* __restrict__ map,
    const unsigned short* __restrict__ x1b, const float* __restrict__ wbuf2,
    float* __restrict__ agg) {
  int t = blockIdx.x * 4 + (threadIdx.x >> 6);
  int lane = threadIdx.x & 63;
  int v = (t < BB) ? uid[t] : NU + iid[t - BB];
  if (map[v] != t) return;
  int d = deg[v], s0 = rowstart[v];
  float4 acc = make_float4(0.f, 0.f, 0.f, 0.f);
#pragma unroll 2
  for (int i = 0; i < d; i++) {
    int c = col[s0 + i];                // uniform
    float w = wbuf2[s0 + i];            // uniform
    ushort4 hv = *reinterpret_cast<const ushort4*>(&x1b[((size_t)c << 8) + (lane << 2)]);
    acc.x += w * bf2f(hv.x); acc.y += w * bf2f(hv.y);
    acc.z += w * bf2f(hv.z); acc.w += w * bf2f(hv.w);
  }
  *reinterpret_cast<float4*>(&agg[((size_t)t << 8) + (lane << 2)]) = acc;
}

__global__ __launch_bounds__(256) void final_kernel(
    const float* __restrict__ ph, const float* __restrict__ w2,
    const float* __restrict__ b2, float* __restrict__ out) {
  int b = blockIdx.x * 4 + (threadIdx.x >> 6);
  int lane = threadIdx.x & 63;
  float2 hv = *reinterpret_cast<const float2*>(&ph[((size_t)b << 7) + (lane << 1)]);
  float2 wv = *reinterpret_cast<const float2*>(&w2[lane << 1]);
  float s = hv.x * wv.x + hv.y * wv.y;
  for (int o = 1; o < 64; o <<= 1) s += __shfl_xor(s, o);
  if (lane == 0) out[b] = s + b2[0];
}

// ---------------- launcher ----------------
extern "C" void kernel_launch(void* const* d_in, const int* in_sizes, int n_in,
                              void* d_out, int out_size, void* d_ws, size_t ws_size,
                              hipStream_t stream) {
  const int* uid = (const int*)d_in[0];
  const int* iid = (const int*)d_in[1];
  const float* content = (const float*)d_in[2];
  const int* ei = (const int*)d_in[3];
  const float* uemb = (const float*)d_in[4];
  const float* iemb = (const float*)d_in[5];
  const float* wc = (const float*)d_in[6];
  const float* bc = (const float*)d_in[7];
  const float* w1 = (const float*)d_in[8];
  const float* att1s = (const float*)d_in[9];
  const float* att1d = (const float*)d_in[10];
  const float* b1 = (const float*)d_in[11];
  const float* w2 = (const float*)d_in[12];
  const float* att2s = (const float*)d_in[13];
  const float* att2d = (const float*)d_in[14];
  const float* b2c = (const float*)d_in[15];
  const float* pw1 = (const float*)d_in[16];
  const float* pb1 = (const float*)d_in[17];
  const float* pw2 = (const float*)d_in[18];
  const float* pb2 = (const float*)d_in[19];
  float* out = (float*)d_out;
  char* ws = (char*)d_ws;

  size_t off = 0;
  auto alloc = [&](size_t bytes) {
    size_t o = off;
    off += (bytes + 255) & ~(size_t)255;
    return o;
  };
  size_t o_winner  = alloc(NI * 4);
  size_t o_map     = alloc(NN * 4);
  size_t o_a1s     = alloc((size_t)NN * 2 * 4);
  size_t o_a1d     = alloc((size_t)NN * 2 * 4);
  size_t o_deg     = alloc(NN * 4);
  size_t o_rs      = alloc(NN * 4);
  size_t o_fill    = alloc(NN * 4);
  size_t o_cnt     = alloc(4);
  size_t o_needed  = alloc(NN);
  size_t o_col     = alloc((size_t)ET * 4);
  size_t o_rbuf    = alloc((size_t)ET * 4);   // conv1 gather idx; later wbuf2
  size_t o_wbuf    = alloc((size_t)ET * 8);   // conv1 weights (float2)
  size_t o_a2s     = alloc(NN * 4);
  size_t o_a2d     = alloc(NN * 4);
  size_t o_qs      = alloc(256 * 4);
  size_t o_qd      = alloc(256 * 4);
  size_t o_widx    = alloc(BB * 4);
  size_t o_wch = alloc(65536 * 2),  o_wcl = alloc(65536 * 2);
  size_t o_w1h = alloc(65536 * 2),  o_w1l = alloc(65536 * 2);
  size_t o_w2h = alloc(32768 * 2),  o_w2l = alloc(32768 * 2);
  size_t o_p1h = alloc(49152 * 2),  o_p1l = alloc(49152 * 2);
  // region R1 (25.2MB): Xa f32 (16.78M) | Hb bf16 (8.39M)
  size_t o_r1    = alloc(16777216 + 8388608);
  size_t o_xa    = o_r1;
  size_t o_hb    = o_r1 + 16777216;
  size_t o_agg   = o_r1;
  size_t o_out2c = o_r1 + 16777216;
  size_t o_ph    = o_r1;
  size_t o_x1b   = alloc((size_t)NN * 256 * 2);
  (void)ws_size; (void)in_sizes; (void)n_in; (void)out_size;

  int*   winner = (int*)(ws + o_winner);
  int*   map    = (int*)(ws + o_map);
  float* a1s    = (float*)(ws + o_a1s);
  float* a1d    = (float*)(ws + o_a1d);
  int*   deg    = (int*)(ws + o_deg);
  int*   rs     = (int*)(ws + o_rs);
  int*   fill   = (int*)(ws + o_fill);
  int*   cnt    = (int*)(ws + o_cnt);
  unsigned char* needed = (unsigned char*)(ws + o_needed);
  int*   col    = (int*)(ws + o_col);
  int*   rbuf   = (int*)(ws + o_rbuf);
  float* wbuf2  = (float*)(ws + o_rbuf);   // aliases rbuf (dead after conv1 gather)
  float2* wbuf  = (float2*)(ws + o_wbuf);
  float* a2s    = (float*)(ws + o_a2s);
  float* a2d    = (float*)(ws + o_a2d);
  float* qs     = (float*)(ws + o_qs);
  float* qd     = (float*)(ws + o_qd);
  int*   widx   = (int*)(ws + o_widx);
  unsigned short* wch = (unsigned short*)(ws + o_wch);
  unsigned short* wcl = (unsigned short*)(ws + o_wcl);
  unsigned short* w1h = (unsigned short*)(ws + o_w1h);
  unsigned short* w1l = (unsigned short*)(ws + o_w1l);
  unsigned short* w2h = (unsigned short*)(ws + o_w2h);
  unsigned short* w2l = (unsigned short*)(ws + o_w2l);
  unsigned short* p1h = (unsigned short*)(ws + o_p1h);
  unsigned short* p1l = (unsigned short*)(ws + o_p1l);
  float* Xa     = (float*)(ws + o_xa);
  unsigned short* Hb = (unsigned short*)(ws + o_hb);
  float* agg    = (float*)(ws + o_agg);
  float* out2c  = (float*)(ws + o_out2c);
  float* ph     = (float*)(ws + o_ph);
  unsigned short* x1b = (unsigned short*)(ws + o_x1b);

  hipMemsetAsync(ws + o_winner, 0xFF, o_map - o_winner + (size_t)NN * 4, stream);   // winner|map
  hipMemsetAsync(ws + o_a1s, 0, o_a1d - o_a1s + (size_t)NN * 2 * 4, stream);         // a1s|a1d
  hipMemsetAsync(ws + o_deg, 0, o_needed - o_deg + NN, stream);                      // deg|rs|fill|cnt|needed

  setup_kernel<<<EB + SPLB + XAB, 256, 0, stream>>>(
      ei, uid, iid, deg, winner,
      wc, wch, wcl, w1, w1h, w1l, w2, w2h, w2l, pw1, p1h, p1l,
      uemb, iemb, Xa, map);
  rowstart_kernel<<<(NN + 255) / 256 + 1, 256, 0, stream>>>(
      deg, winner, iid, rs, fill, cnt, widx, w2, att2s, att2d, qs, qd);
  cembfill_kernel<<<GEMMB + EB, 256, 0, stream>>>(
      wch, wcl, bc, Xa + (size_t)BB * 256 + 128, widx, content,
      ei, fill, col, map, needed);
  // Hb = bf16(Xa @ W1^T), with fused a1 score atomics
  {
    dim3 g(NTASK / 64, 256 / 64);
    gemm_mfma<0, 1><<<g, 256, 0, stream>>>(
        Xa, w1h, w1l, nullptr, nullptr, Hb, 256,
        NTASK, 256, 256, 0, uid, iid, map, nullptr, nullptr,
        att1s, att1d, a1s, a1d);
  }
  w1_kernel<<<(NN + 31) / 32, 256, 0, stream>>>(col, rs, deg, map, needed,
                                                a1s, a1d, rbuf, wbuf);
  conv1_agg_kernel<<<NN / 4, 256, 0, stream>>>(rs, deg, Hb, needed, rbuf, wbuf,
                                               b1, qs, qd, x1b, a2s, a2d);
  w2_kernel<<<NTASK / 32, 256, 0, stream>>>(uid, iid, col, rs, deg, map,
                                            a2s, a2d, wbuf2);
  conv2_agg_kernel<<<NTASK / 4, 256, 0, stream>>>(uid, iid, col, rs, deg, map,
                                                  x1b, wbuf2, agg);
  // out2c = agg @ W2^T + b2c
  {
    dim3 g(NTASK / 64, DD / 64);
    gemm_mfma<0, 0><<<g, 256, 0, stream>>>(
        agg, w2h, w2l, b2c, out2c, nullptr, 128,
        NTASK, DD, 256, 0, nullptr, nullptr, nullptr, nullptr, nullptr,
        nullptr, nullptr, nullptr, nullptr);
  }
  // ph = relu([uemb[uid] | out2c[map[item]] | out2c[map[user]]] @ pw1^T + pb1)
  {
    dim3 g(BB / 64, DD / 64);
    gemm_mfma<1, 0><<<g, 256, 0, stream>>>(
        nullptr, p1h, p1l, pb1, ph, nullptr, 128,
        BB, DD, 384, 1, uid, iid, map, uemb, out2c,
        nullptr, nullptr, nullptr, nullptr);
  }
  final_kernel<<<BB / 4, 256, 0, stream>>>(ph, pw2, pb2, out);
}

// Round 11
// 205.807 us; speedup vs baseline: 1.1583x; 1.1583x over previous
//
#include <hip/hip_runtime.h>
#include <hip/hip_bf16.h>

#define NU 50000
#define NI 20000
#define NN 70000
#define DD 128
#define BB 8192
#define EE 500000
#define ET 570000   // EE + NN self loops
#define NTASK 16384 // 2*BB

__device__ __forceinline__ float lrelu(float x) { return x > 0.f ? x : 0.2f * x; }

typedef __attribute__((ext_vector_type(8))) short bf16x8;   // 8 bf16 = 4 VGPRs
typedef __attribute__((ext_vector_type(8))) unsigned short u16x8;
typedef __attribute__((ext_vector_type(4))) float f32x4;

__device__ __forceinline__ unsigned short f2bf_rne(float f) {
  unsigned int u = __builtin_bit_cast(unsigned int, f);
  u += 0x7FFFu + ((u >> 16) & 1u);
  return (unsigned short)(u >> 16);
}
__device__ __forceinline__ float bf2f(unsigned short h) {
  unsigned int u = ((unsigned int)h) << 16;
  return __builtin_bit_cast(float, u);
}

// ---------------- MFMA GEMM core: C[M,N] = A * Bt^T (+bias)(+relu) ----------------
// GATHER=0: A linear. GATHER=1: ph-style 3-section row gather. GATHER=2: row gather.
// MODE=0: f32 C. MODE=1: bf16 Cb + fused a1 attention-score atomics.
// MODE=2: fused final layer: relu(acc+bias) dot att_s(=pw2), + att_d[0](=pb2),
//         atomicAdd into a1s(=out). No C write.
template <int GATHER, int MODE>
__device__ __forceinline__ void gemm_core(
    int bm, int bn,
    const float* __restrict__ A,
    const unsigned short* __restrict__ Bh, const unsigned short* __restrict__ Bl,
    const float* __restrict__ bias, float* __restrict__ C,
    unsigned short* __restrict__ Cb, int ldc,
    int M, int N, int K, int act,
    const int* __restrict__ idx0, const int* __restrict__ idx1,
    const int* __restrict__ mapv,
    const float* __restrict__ gA0, const float* __restrict__ gA1,
    const float* __restrict__ att_s, const float* __restrict__ att_d,
    float* __restrict__ a1s, float* __restrict__ a1d) {
  __shared__ __align__(16) unsigned short sAh[8][64][8];
  __shared__ __align__(16) unsigned short sAl[8][64][8];
  __shared__ __align__(16) unsigned short sBh[8][64][8];
  __shared__ __align__(16) unsigned short sBl[8][64][8];
  int tid = threadIdx.x;
  int lane = tid & 63, w = tid >> 6;
  int wr = (w >> 1) * 32, wc = (w & 1) * 32;
  int fr = lane & 15, fk = lane >> 4;
  f32x4 acc[2][2] = {};

  for (int k0 = 0; k0 < K; k0 += 64) {
    __syncthreads();
#pragma unroll
    for (int t = 0; t < 2; t++) {
      int f = tid + t * 256;
      int row = f >> 3, kb = f & 7;
      int kg = k0 + kb * 8;
      const float* ap;
      if (GATHER == 1) {
        int sec = kg >> 7;           // 64-tiles never straddle 128-col sections
        int kc = kg & 127;
        int r = bm + row;
        if (sec == 0)      ap = &gA0[(size_t)idx0[r] * 128 + kc];
        else if (sec == 1) ap = &gA1[(size_t)mapv[NU + idx1[r]] * 128 + kc];
        else               ap = &gA1[(size_t)mapv[idx0[r]] * 128 + kc];
      } else if (GATHER == 2) {
        ap = &gA0[(size_t)idx0[bm + row] * K + kg];
      } else {
        ap = &A[(size_t)(bm + row) * K + kg];
      }
      float4 v0 = *reinterpret_cast<const float4*>(ap);
      float4 v1 = *reinterpret_cast<const float4*>(ap + 4);
      float vv[8] = {v0.x, v0.y, v0.z, v0.w, v1.x, v1.y, v1.z, v1.w};
      u16x8 hv, lv;
#pragma unroll
      for (int j = 0; j < 8; j++) {
        unsigned short hh = f2bf_rne(vv[j]);
        hv[j] = hh;
        lv[j] = (unsigned short)(__builtin_bit_cast(unsigned int, vv[j] - bf2f(hh)) >> 16);
      }
      *reinterpret_cast<u16x8*>(&sAh[kb][row][0]) = hv;
      *reinterpret_cast<u16x8*>(&sAl[kb][row][0]) = lv;
    }
#pragma unroll
    for (int t = 0; t < 2; t++) {
      int f = tid + t * 256;
      int row = f >> 3, kb = f & 7;
      int kg = k0 + kb * 8;
      *reinterpret_cast<u16x8*>(&sBh[kb][row][0]) =
          *reinterpret_cast<const u16x8*>(&Bh[(size_t)(bn + row) * K + kg]);
      *reinterpret_cast<u16x8*>(&sBl[kb][row][0]) =
          *reinterpret_cast<const u16x8*>(&Bl[(size_t)(bn + row) * K + kg]);
    }
    __syncthreads();
#pragma unroll
    for (int s = 0; s < 2; s++) {
      int kb = s * 4 + fk;
      bf16x8 ah0 = *reinterpret_cast<const bf16x8*>(&sAh[kb][wr + fr][0]);
      bf16x8 ah1 = *reinterpret_cast<const bf16x8*>(&sAh[kb][wr + 16 + fr][0]);
      bf16x8 al0 = *reinterpret_cast<const bf16x8*>(&sAl[kb][wr + fr][0]);
      bf16x8 al1 = *reinterpret_cast<const bf16x8*>(&sAl[kb][wr + 16 + fr][0]);
      bf16x8 bh0 = *reinterpret_cast<const bf16x8*>(&sBh[kb][wc + fr][0]);
      bf16x8 bh1 = *reinterpret_cast<const bf16x8*>(&sBh[kb][wc + 16 + fr][0]);
      bf16x8 bl0 = *reinterpret_cast<const bf16x8*>(&sBl[kb][wc + fr][0]);
      bf16x8 bl1 = *reinterpret_cast<const bf16x8*>(&sBl[kb][wc + 16 + fr][0]);
      acc[0][0] = __builtin_amdgcn_mfma_f32_16x16x32_bf16(al0, bh0, acc[0][0], 0, 0, 0);
      acc[0][0] = __builtin_amdgcn_mfma_f32_16x16x32_bf16(ah0, bl0, acc[0][0], 0, 0, 0);
      acc[0][0] = __builtin_amdgcn_mfma_f32_16x16x32_bf16(ah0, bh0, acc[0][0], 0, 0, 0);
      acc[0][1] = __builtin_amdgcn_mfma_f32_16x16x32_bf16(al0, bh1, acc[0][1], 0, 0, 0);
      acc[0][1] = __builtin_amdgcn_mfma_f32_16x16x32_bf16(ah0, bl1, acc[0][1], 0, 0, 0);
      acc[0][1] = __builtin_amdgcn_mfma_f32_16x16x32_bf16(ah0, bh1, acc[0][1], 0, 0, 0);
      acc[1][0] = __builtin_amdgcn_mfma_f32_16x16x32_bf16(al1, bh0, acc[1][0], 0, 0, 0);
      acc[1][0] = __builtin_amdgcn_mfma_f32_16x16x32_bf16(ah1, bl0, acc[1][0], 0, 0, 0);
      acc[1][0] = __builtin_amdgcn_mfma_f32_16x16x32_bf16(ah1, bh0, acc[1][0], 0, 0, 0);
      acc[1][1] = __builtin_amdgcn_mfma_f32_16x16x32_bf16(al1, bh1, acc[1][1], 0, 0, 0);
      acc[1][1] = __builtin_amdgcn_mfma_f32_16x16x32_bf16(ah1, bl1, acc[1][1], 0, 0, 0);
      acc[1][1] = __builtin_amdgcn_mfma_f32_16x16x32_bf16(ah1, bh1, acc[1][1], 0, 0, 0);
    }
  }
  if (MODE == 1) {
    int head = bn >> 7;
    float ps[2][4] = {{0.f}}, pd[2][4] = {{0.f}};
#pragma unroll
    for (int j = 0; j < 2; j++) {
      int col = bn + wc + j * 16 + fr;
      float asc = att_s[col], adc = att_d[col];
#pragma unroll
      for (int i = 0; i < 2; i++) {
#pragma unroll
        for (int r = 0; r < 4; r++) {
          float v = acc[i][j][r];
          ps[i][r] += v * asc;
          pd[i][r] += v * adc;
          Cb[(size_t)(bm + wr + i * 16 + fk * 4 + r) * ldc + col] = f2bf_rne(v);
        }
      }
    }
#pragma unroll
    for (int o = 1; o < 16; o <<= 1) {
#pragma unroll
      for (int i = 0; i < 2; i++)
#pragma unroll
        for (int r = 0; r < 4; r++) {
          ps[i][r] += __shfl_xor(ps[i][r], o);
          pd[i][r] += __shfl_xor(pd[i][r], o);
        }
    }
    if (fr == 0) {
#pragma unroll
      for (int i = 0; i < 2; i++) {
#pragma unroll
        for (int r = 0; r < 4; r++) {
          int t = bm + wr + i * 16 + fk * 4 + r;
          int v = (t < BB) ? idx0[t] : NU + idx1[t - BB];
          if (mapv[v] == t) {   // rep task only (dups would double-count)
            atomicAdd(&a1s[(size_t)v * 2 + head], ps[i][r]);
            atomicAdd(&a1d[(size_t)v * 2 + head], pd[i][r]);
          }
        }
      }
    }
    return;
  }
  if (MODE == 2) {
    // fused prediction head: out[row] += sum_col relu(acc+pb1[col]) * pw2[col]
    float part[2][4] = {{0.f}};
#pragma unroll
    for (int j = 0; j < 2; j++) {
      int col = bn + wc + j * 16 + fr;
      float bj = bias[col];
      float wv = att_s[col];
#pragma unroll
      for (int i = 0; i < 2; i++) {
#pragma unroll
        for (int r = 0; r < 4; r++) {
          float v = fmaxf(acc[i][j][r] + bj, 0.f);
          part[i][r] += v * wv;
        }
      }
    }
#pragma unroll
    for (int o = 1; o < 16; o <<= 1) {
#pragma unroll
      for (int i = 0; i < 2; i++)
#pragma unroll
        for (int r = 0; r < 4; r++) part[i][r] += __shfl_xor(part[i][r], o);
    }
    if (fr == 0) {
#pragma unroll
      for (int i = 0; i < 2; i++) {
#pragma unroll
        for (int r = 0; r < 4; r++) {
          int row = bm + wr + i * 16 + fk * 4 + r;
          float add = part[i][r];
          if (bn == 0 && wc == 0) add += att_d[0];   // pb2 exactly once per row
          atomicAdd(&a1s[row], add);
        }
      }
    }
    return;
  }
#pragma unroll
  for (int j = 0; j < 2; j++) {
    int col = bn + wc + j * 16 + fr;
    float bj = bias ? bias[col] : 0.f;
#pragma unroll
    for (int i = 0; i < 2; i++) {
#pragma unroll
      for (int r = 0; r < 4; r++) {
        int row = bm + wr + i * 16 + fk * 4 + r;
        float v = acc[i][j][r] + bj;
        if (act == 1) v = fmaxf(v, 0.f);
        C[(size_t)row * ldc + col] = v;
      }
    }
  }
}

template <int GATHER, int MODE>
__global__ __launch_bounds__(256) void gemm_mfma(
    const float* __restrict__ A,
    const unsigned short* __restrict__ Bh, const unsigned short* __restrict__ Bl,
    const float* __restrict__ bias, float* __restrict__ C,
    unsigned short* __restrict__ Cb, int ldc,
    int M, int N, int K, int act,
    const int* __restrict__ idx0, const int* __restrict__ idx1,
    const int* __restrict__ mapv,
    const float* __restrict__ gA0, const float* __restrict__ gA1,
    const float* __restrict__ att_s, const float* __restrict__ att_d,
    float* __restrict__ a1s, float* __restrict__ a1d) {
  gemm_core<GATHER, MODE>(blockIdx.x * 64, blockIdx.y * 64,
                          A, Bh, Bl, bias, C, Cb, ldc, M, N, K, act,
                          idx0, idx1, mapv, gA0, gA1, att_s, att_d, a1s, a1d);
}

// cemb GEMM (gather-A) + CSR fill + needed-mark in ONE launch (independent work).
#define GEMMB 256  // (BB/64) * (DD/64)
__global__ __launch_bounds__(256) void cembfill_kernel(
    const unsigned short* __restrict__ wch, const unsigned short* __restrict__ wcl,
    const float* __restrict__ bc, float* __restrict__ XaC,
    const int* __restrict__ widx, const float* __restrict__ content,
    const int* __restrict__ ei, int* __restrict__ fill, int* __restrict__ col,
    const int* __restrict__ mapv, unsigned char* __restrict__ needed) {
  int bid = blockIdx.x;
  if (bid < GEMMB) {
    gemm_core<2, 0>((bid >> 1) * 64, (bid & 1) * 64,
                    nullptr, wch, wcl, bc, XaC, nullptr, 256,
                    BB, DD, 512, 0, widx, nullptr, nullptr, content, nullptr,
                    nullptr, nullptr, nullptr, nullptr);
    return;
  }
  int e = (bid - GEMMB) * 256 + threadIdx.x;
  if (e >= ET) return;
  int src, dst;
  if (e < EE) { src = ei[e]; dst = ei[EE + e]; }
  else { src = e - EE; dst = src; }
  int pos = atomicAdd(&fill[dst], 1);
  col[pos] = src;
  if (mapv[dst] >= 0) needed[src] = 1;
}

// ---------------- mega-setup: deg+winner atomics | weight split | Xa-emb+map ------
#define EB 2227    // ceil(ET/256)
#define SPLB 832   // (65536+65536+32768+49152)/256
#define XAB 4096   // NTASK/4
__global__ __launch_bounds__(256) void setup_kernel(
    const int* __restrict__ ei, const int* __restrict__ uid, const int* __restrict__ iid,
    int* __restrict__ deg, int* __restrict__ winner,
    const float* __restrict__ wc, unsigned short* wch, unsigned short* wcl,
    const float* __restrict__ w1, unsigned short* w1h, unsigned short* w1l,
    const float* __restrict__ w2, unsigned short* w2h, unsigned short* w2l,
    const float* __restrict__ pw1, unsigned short* p1h, unsigned short* p1l,
    const float* __restrict__ uemb, const float* __restrict__ iemb,
    float* __restrict__ Xa, int* __restrict__ map) {
  int bid = blockIdx.x, tid = threadIdx.x;
  if (bid < EB) {
    int e = bid * 256 + tid;
    if (e < BB) atomicMax(&winner[iid[e]], e);
    if (e >= ET) return;
    int dst = (e < EE) ? ei[EE + e] : (e - EE);
    atomicAdd(&deg[dst], 1);
    return;
  }
  if (bid < EB + SPLB) {
    int i = (bid - EB) * 256 + tid;
    const float* w; unsigned short* h; unsigned short* l; int idx;
    if (i < 65536) { w = wc; h = wch; l = wcl; idx = i; }
    else if (i < 131072) { w = w1; h = w1h; l = w1l; idx = i - 65536; }
    else if (i < 163840) { w = w2; h = w2h; l = w2l; idx = i - 131072; }
    else { w = pw1; h = p1h; l = p1l; idx = i - 163840; }
    float f = w[idx];
    unsigned short hh = f2bf_rne(f);
    h[idx] = hh;
    l[idx] = (unsigned short)(__builtin_bit_cast(unsigned int, f - bf2f(hh)) >> 16);
    return;
  }
  int t = (bid - EB - SPLB) * 4 + (tid >> 6);
  int lane = tid & 63;
  int c4 = lane * 4;
  if (t < BB) {
    int u = uid[t];
    float4 v = make_float4(0.f, 0.f, 0.f, 0.f);
    if (c4 < DD) v = *reinterpret_cast<const float4*>(&uemb[(size_t)u * DD + c4]);
    *reinterpret_cast<float4*>(&Xa[(size_t)t * 256 + c4]) = v;
    if (lane == 0) map[u] = t;
  } else {
    int it = iid[t - BB];
    if (c4 < DD) {
      float4 v = *reinterpret_cast<const float4*>(&iemb[(size_t)it * DD + c4]);
      *reinterpret_cast<float4*>(&Xa[(size_t)t * 256 + c4]) = v;
    }
    if (lane == 0) map[NU + it] = t;
  }
}

// rowstart + widx; last block computes the conv2 q-vectors.
__global__ void rowstart_kernel(const int* __restrict__ deg, const int* __restrict__ winner,
                                const int* __restrict__ iid,
                                int* __restrict__ rowstart, int* __restrict__ fill,
                                int* __restrict__ counter, int* __restrict__ widx,
                                const float* __restrict__ w2,
                                const float* __restrict__ att2s, const float* __restrict__ att2d,
                                float* __restrict__ qs, float* __restrict__ qd) {
  int blk = blockIdx.x;
  if (blk == (NN + 255) / 256) {
    int k = threadIdx.x;
    float s = 0.f, d = 0.f;
#pragma unroll 4
    for (int j = 0; j < DD; j++) {
      float w = w2[(size_t)j * 256 + k];
      s += att2s[j] * w;
      d += att2d[j] * w;
    }
    qs[k] = s;
    qd[k] = d;
    return;
  }
  int v = blk * 256 + threadIdx.x;
  if (v < BB) widx[v] = winner[iid[v]];
  if (v >= NN) return;
  int s = atomicAdd(counter, deg[v]);
  rowstart[v] = s;
  fill[v] = s;
}

// conv1 aggregation: bf16 Hb gather, needed-skip, online softmax, fused a2 scores.
// Fast path d<=64 with BALLOT-COMPACTED gather (only edges with map[src]>=0 ~20%).
__global__ __launch_bounds__(256) void conv1_agg_kernel(
    const int* __restrict__ col, const int* __restrict__ rowstart,
    const int* __restrict__ deg, const unsigned short* __restrict__ Hb,
    const int* __restrict__ map, const unsigned char* __restrict__ needed,
    const float* __restrict__ a1s, const float* __restrict__ a1d,
    const float* __restrict__ bias,
    const float* __restrict__ qs, const float* __restrict__ qd,
    unsigned short* __restrict__ x1b, float* __restrict__ a2s, float* __restrict__ a2d) {
  int v = blockIdx.x * 4 + (threadIdx.x >> 6);
  int lane = threadIdx.x & 63;
  if (!needed[v]) return;
  int head = lane >> 5;
  int d = deg[v], s0 = rowstart[v];
  float2 adv = *reinterpret_cast<const float2*>(&a1d[(size_t)v * 2]);
  float4 acc = make_float4(0.f, 0.f, 0.f, 0.f);
  float den;
  const unsigned short* hb = Hb + (lane << 2);
  if (d <= 64) {
    bool act = lane < d;
    int ci = act ? col[s0 + lane] : 0;
    float2 asv = make_float2(0.f, 0.f);
    int ri = -1;
    if (act) {
      asv = *reinterpret_cast<const float2*>(&a1s[(size_t)ci * 2]);
      ri = map[ci];
    }
    float al0 = act ? lrelu(asv.x + adv.x) : -1e30f;
    float al1 = act ? lrelu(asv.y + adv.y) : -1e30f;
    float m0 = al0, m1 = al1;
#pragma unroll
    for (int o = 1; o < 64; o <<= 1) {
      m0 = fmaxf(m0, __shfl_xor(m0, o));
      m1 = fmaxf(m1, __shfl_xor(m1, o));
    }
    float ex0 = act ? __expf(al0 - m0) : 0.f;
    float ex1 = act ? __expf(al1 - m1) : 0.f;
    float cs0 = ex0, cs1 = ex1;
#pragma unroll
    for (int o = 1; o < 64; o <<= 1) {
      cs0 += __shfl_xor(cs0, o);
      cs1 += __shfl_xor(cs1, o);
    }
    den = head ? cs1 : cs0;
    // compacted gather: only lanes whose edge source is a batch node
    unsigned long long msk = __ballot(act && ri >= 0);
    while (msk) {
      int s = __ffsll((unsigned long long)msk) - 1;
      msk &= msk - 1;
      int r = __shfl(ri, s);
      float e0 = __shfl(ex0, s), e1 = __shfl(ex1, s);
      float ex = head ? e1 : e0;
      ushort4 hv = *reinterpret_cast<const ushort4*>(&hb[(size_t)r << 8]);
      acc.x += ex * bf2f(hv.x); acc.y += ex * bf2f(hv.y);
      acc.z += ex * bf2f(hv.z); acc.w += ex * bf2f(hv.w);
    }
  } else {
    float m0 = -1e30f, m1 = -1e30f, den0 = 0.f, den1 = 0.f;
    for (int c0 = 0; c0 < d; c0 += 64) {
      int i = c0 + lane;
      bool act = i < d;
      int ci = act ? col[s0 + i] : 0;
      float2 asv = make_float2(0.f, 0.f);
      int ri = -1;
      if (act) {
        asv = *reinterpret_cast<const float2*>(&a1s[(size_t)ci * 2]);
        ri = map[ci];
      }
      float al0 = act ? lrelu(asv.x + adv.x) : -1e30f;
      float al1 = act ? lrelu(asv.y + adv.y) : -1e30f;
      float cm0 = al0, cm1 = al1;
#pragma unroll
      for (int o = 1; o < 64; o <<= 1) {
        cm0 = fmaxf(cm0, __shfl_xor(cm0, o));
        cm1 = fmaxf(cm1, __shfl_xor(cm1, o));
      }
      float nm0 = fmaxf(m0, cm0), nm1 = fmaxf(m1, cm1);
      float ex0 = act ? __expf(al0 - nm0) : 0.f;
      float ex1 = act ? __expf(al1 - nm1) : 0.f;
      float s0f = __expf(m0 - nm0), s1f = __expf(m1 - nm1);
      float cs0 = ex0, cs1 = ex1;
#pragma unroll
      for (int o = 1; o < 64; o <<= 1) {
        cs0 += __shfl_xor(cs0, o);
        cs1 += __shfl_xor(cs1, o);
      }
      den0 = den0 * s0f + cs0;
      den1 = den1 * s1f + cs1;
      float sc = head ? s1f : s0f;
      acc.x *= sc; acc.y *= sc; acc.z *= sc; acc.w *= sc;
      unsigned long long msk = __ballot(act && ri >= 0);
      while (msk) {
        int s = __ffsll((unsigned long long)msk) - 1;
        msk &= msk - 1;
        int r = __shfl(ri, s);
        float e0 = __shfl(ex0, s), e1 = __shfl(ex1, s);
        float ex = head ? e1 : e0;
        ushort4 hv = *reinterpret_cast<const ushort4*>(&hb[(size_t)r << 8]);
        acc.x += ex * bf2f(hv.x); acc.y += ex * bf2f(hv.y);
        acc.z += ex * bf2f(hv.z); acc.w += ex * bf2f(hv.w);
      }
      m0 = nm0; m1 = nm1;
    }
    den = head ? den1 : den0;
  }
  float inv = 1.f / den;
  float4 b4 = *reinterpret_cast<const float4*>(&bias[lane << 2]);
  float4 o;
  o.x = fmaf(acc.x, inv, b4.x);
  o.y = fmaf(acc.y, inv, b4.y);
  o.z = fmaf(acc.z, inv, b4.z);
  o.w = fmaf(acc.w, inv, b4.w);
  o.x = o.x > 0.f ? o.x : __expf(o.x) - 1.f;
  o.y = o.y > 0.f ? o.y : __expf(o.y) - 1.f;
  o.z = o.z > 0.f ? o.z : __expf(o.z) - 1.f;
  o.w = o.w > 0.f ? o.w : __expf(o.w) - 1.f;
  ushort4 st;
  st.x = f2bf_rne(o.x); st.y = f2bf_rne(o.y);
  st.z = f2bf_rne(o.z); st.w = f2bf_rne(o.w);
  *reinterpret_cast<ushort4*>(&x1b[((size_t)v << 8) + (lane << 2)]) = st;
  float4 sv = *reinterpret_cast<const float4*>(&qs[lane << 2]);
  float4 dv = *reinterpret_cast<const float4*>(&qd[lane << 2]);
  float ps = o.x * sv.x + o.y * sv.y + o.z * sv.z + o.w * sv.w;
  float pd = o.x * dv.x + o.y * dv.y + o.z * dv.z + o.w * dv.w;
#pragma unroll
  for (int of = 1; of < 64; of <<= 1) { ps += __shfl_xor(ps, of); pd += __shfl_xor(pd, of); }
  if (lane == 0) { a2s[v] = ps; a2d[v] = pd; }
}

// conv2 aggregation, representative tasks only (map[v]==t); bf16 x1 gather.
__global__ __launch_bounds__(256) void conv2_agg_kernel(
    const int* __restrict__ uid, const int* __restrict__ iid,
    const int* __restrict__ col, const int* __restrict__ rowstart,
    const int* __restrict__ deg, const int* __restrict__ map,
    const unsigned short* __restrict__ x1b,
    const float* __restrict__ a2s, const float* __restrict__ a2d,
    float* __restrict__ agg) {
  int t = blockIdx.x * 4 + (threadIdx.x >> 6);
  int lane = threadIdx.x & 63;
  int v = (t < BB) ? uid[t] : NU + iid[t - BB];
  if (map[v] != t) return;  // duplicates gather the rep's row via map in the ph GEMM
  int d = deg[v], s0 = rowstart[v];
  float ad = a2d[v];
  float4 acc = make_float4(0.f, 0.f, 0.f, 0.f);
  float den;
  const unsigned short* xb = x1b + (lane << 2);
  if (d <= 64) {
    bool act = lane < d;
    int ci = act ? col[s0 + lane] : 0;
    float as = act ? a2s[ci] : 0.f;
    float al = act ? lrelu(as + ad) : -1e30f;
    float m = al;
#pragma unroll
    for (int o = 1; o < 64; o <<= 1) m = fmaxf(m, __shfl_xor(m, o));
    float ex = act ? __expf(al - m) : 0.f;
    float cs = ex;
#pragma unroll
    for (int o = 1; o < 64; o <<= 1) cs += __shfl_xor(cs, o);
    den = cs;
    for (int i2 = 0; i2 < d; i2++) {
      int r = __shfl(ci, i2);
      float e = __shfl(ex, i2);
      ushort4 hv = *reinterpret_cast<const ushort4*>(&xb[(size_t)r << 8]);
      acc.x += e * bf2f(hv.x); acc.y += e * bf2f(hv.y);
      acc.z += e * bf2f(hv.z); acc.w += e * bf2f(hv.w);
    }
  } else {
    float m = -1e30f; den = 0.f;
    for (int c0 = 0; c0 < d; c0 += 64) {
      int i = c0 + lane;
      bool act = i < d;
      int ci = act ? col[s0 + i] : 0;
      float as = act ? a2s[ci] : 0.f;
      float al = act ? lrelu(as + ad) : -1e30f;
      float cm = al;
#pragma unroll
      for (int o = 1; o < 64; o <<= 1) cm = fmaxf(cm, __shfl_xor(cm, o));
      float nm = fmaxf(m, cm);
      float ex = act ? __expf(al - nm) : 0.f;
      float sf = __expf(m - nm);
      float cs = ex;
#pragma unroll
      for (int o = 1; o < 64; o <<= 1) cs += __shfl_xor(cs, o);
      den = den * sf + cs;
      acc.x *= sf; acc.y *= sf; acc.z *= sf; acc.w *= sf;
      int n = min(64, d - c0);
      for (int i2 = 0; i2 < n; i2++) {
        int r = __shfl(ci, i2);
        float e = __shfl(ex, i2);
        ushort4 hv = *reinterpret_cast<const ushort4*>(&xb[(size_t)r << 8]);
        acc.x += e * bf2f(hv.x); acc.y += e * bf2f(hv.y);
        acc.z += e * bf2f(hv.z); acc.w += e * bf2f(hv.w);
      }
      m = nm;
    }
  }
  float inv = 1.f / den;
  float4 o = make_float4(acc.x * inv, acc.y * inv, acc.z * inv, acc.w * inv);
  *reinterpret_cast<float4*>(&agg[((size_t)t << 8) + (lane << 2)]) = o;
}

// ---------------- launcher ----------------
extern "C" void kernel_launch(void* const* d_in, const int* in_sizes, int n_in,
                              void* d_out, int out_size, void* d_ws, size_t ws_size,
                              hipStream_t stream) {
  const int* uid = (const int*)d_in[0];
  const int* iid = (const int*)d_in[1];
  const float* content = (const float*)d_in[2];
  const int* ei = (const int*)d_in[3];
  const float* uemb = (const float*)d_in[4];
  const float* iemb = (const float*)d_in[5];
  const float* wc = (const float*)d_in[6];
  const float* bc = (const float*)d_in[7];
  const float* w1 = (const float*)d_in[8];
  const float* att1s = (const float*)d_in[9];
  const float* att1d = (const float*)d_in[10];
  const float* b1 = (const float*)d_in[11];
  const float* w2 = (const float*)d_in[12];
  const float* att2s = (const float*)d_in[13];
  const float* att2d = (const float*)d_in[14];
  const float* b2c = (const float*)d_in[15];
  const float* pw1 = (const float*)d_in[16];
  const float* pb1 = (const float*)d_in[17];
  const float* pw2 = (const float*)d_in[18];
  const float* pb2 = (const float*)d_in[19];
  float* out = (float*)d_out;
  char* ws = (char*)d_ws;

  size_t off = 0;
  auto alloc = [&](size_t bytes) {
    size_t o = off;
    off += (bytes + 255) & ~(size_t)255;
    return o;
  };
  size_t o_winner  = alloc(NI * 4);
  size_t o_map     = alloc(NN * 4);
  size_t o_a1s     = alloc((size_t)NN * 2 * 4);
  size_t o_a1d     = alloc((size_t)NN * 2 * 4);
  size_t o_deg     = alloc(NN * 4);
  size_t o_rs      = alloc(NN * 4);
  size_t o_fill    = alloc(NN * 4);
  size_t o_cnt     = alloc(4);
  size_t o_needed  = alloc(NN);
  size_t o_col     = alloc((size_t)ET * 4);
  size_t o_a2s     = alloc(NN * 4);
  size_t o_a2d     = alloc(NN * 4);
  size_t o_qs      = alloc(256 * 4);
  size_t o_qd      = alloc(256 * 4);
  size_t o_widx    = alloc(BB * 4);
  size_t o_wch = alloc(65536 * 2),  o_wcl = alloc(65536 * 2);
  size_t o_w1h = alloc(65536 * 2),  o_w1l = alloc(65536 * 2);
  size_t o_w2h = alloc(32768 * 2),  o_w2l = alloc(32768 * 2);
  size_t o_p1h = alloc(49152 * 2),  o_p1l = alloc(49152 * 2);
  // region R1 (25.2MB): Xa f32 (16.78M) | Hb bf16 (8.39M)
  size_t o_r1    = alloc(16777216 + 8388608);
  size_t o_xa    = o_r1;
  size_t o_hb    = o_r1 + 16777216;
  size_t o_agg   = o_r1;
  size_t o_out2c = o_r1 + 16777216;
  size_t o_x1b   = alloc((size_t)NN * 256 * 2);
  (void)ws_size; (void)in_sizes; (void)n_in; (void)out_size;

  int*   winner = (int*)(ws + o_winner);
  int*   map    = (int*)(ws + o_map);
  float* a1s    = (float*)(ws + o_a1s);
  float* a1d    = (float*)(ws + o_a1d);
  int*   deg    = (int*)(ws + o_deg);
  int*   rs     = (int*)(ws + o_rs);
  int*   fill   = (int*)(ws + o_fill);
  int*   cnt    = (int*)(ws + o_cnt);
  unsigned char* needed = (unsigned char*)(ws + o_needed);
  int*   col    = (int*)(ws + o_col);
  float* a2s    = (float*)(ws + o_a2s);
  float* a2d    = (float*)(ws + o_a2d);
  float* qs     = (float*)(ws + o_qs);
  float* qd     = (float*)(ws + o_qd);
  int*   widx   = (int*)(ws + o_widx);
  unsigned short* wch = (unsigned short*)(ws + o_wch);
  unsigned short* wcl = (unsigned short*)(ws + o_wcl);
  unsigned short* w1h = (unsigned short*)(ws + o_w1h);
  unsigned short* w1l = (unsigned short*)(ws + o_w1l);
  unsigned short* w2h = (unsigned short*)(ws + o_w2h);
  unsigned short* w2l = (unsigned short*)(ws + o_w2l);
  unsigned short* p1h = (unsigned short*)(ws + o_p1h);
  unsigned short* p1l = (unsigned short*)(ws + o_p1l);
  float* Xa     = (float*)(ws + o_xa);
  unsigned short* Hb = (unsigned short*)(ws + o_hb);
  float* agg    = (float*)(ws + o_agg);
  float* out2c  = (float*)(ws + o_out2c);
  unsigned short* x1b = (unsigned short*)(ws + o_x1b);

  hipMemsetAsync(ws + o_winner, 0xFF, o_map - o_winner + (size_t)NN * 4, stream);   // winner|map
  hipMemsetAsync(ws + o_a1s, 0, o_a1d - o_a1s + (size_t)NN * 2 * 4, stream);         // a1s|a1d
  hipMemsetAsync(ws + o_deg, 0, o_needed - o_deg + NN, stream);                      // deg|rs|fill|cnt|needed
  hipMemsetAsync(out, 0, BB * 4, stream);                                            // fused-final atomics target

  setup_kernel<<<EB + SPLB + XAB, 256, 0, stream>>>(
      ei, uid, iid, deg, winner,
      wc, wch, wcl, w1, w1h, w1l, w2, w2h, w2l, pw1, p1h, p1l,
      uemb, iemb, Xa, map);
  rowstart_kernel<<<(NN + 255) / 256 + 1, 256, 0, stream>>>(
      deg, winner, iid, rs, fill, cnt, widx, w2, att2s, att2d, qs, qd);
  cembfill_kernel<<<GEMMB + EB, 256, 0, stream>>>(
      wch, wcl, bc, Xa + (size_t)BB * 256 + 128, widx, content,
      ei, fill, col, map, needed);
  // Hb = bf16(Xa @ W1^T), with fused a1 score atomics
  {
    dim3 g(NTASK / 64, 256 / 64);
    gemm_mfma<0, 1><<<g, 256, 0, stream>>>(
        Xa, w1h, w1l, nullptr, nullptr, Hb, 256,
        NTASK, 256, 256, 0, uid, iid, map, nullptr, nullptr,
        att1s, att1d, a1s, a1d);
  }
  conv1_agg_kernel<<<NN / 4, 256, 0, stream>>>(col, rs, deg, Hb, map, needed,
                                               a1s, a1d, b1, qs, qd, x1b, a2s, a2d);
  conv2_agg_kernel<<<NTASK / 4, 256, 0, stream>>>(uid, iid, col, rs, deg, map,
                                                  x1b, a2s, a2d, agg);
  // out2c = agg @ W2^T + b2c
  {
    dim3 g(NTASK / 64, DD / 64);
    gemm_mfma<0, 0><<<g, 256, 0, stream>>>(
        agg, w2h, w2l, b2c, out2c, nullptr, 128,
        NTASK, DD, 256, 0, nullptr, nullptr, nullptr, nullptr, nullptr,
        nullptr, nullptr, nullptr, nullptr);
  }
  // fused: out[b] = relu([uemb|out2c_i|out2c_u] @ pw1^T + pb1) . pw2 + pb2
  {
    dim3 g(BB / 64, DD / 64);
    gemm_mfma<1, 2><<<g, 256, 0, stream>>>(
        nullptr, p1h, p1l, pb1, nullptr, nullptr, 128,
        BB, DD, 384, 0, uid, iid, map, uemb, out2c,
        pw2, pb2, out, nullptr);
  }
}

// Round 12
// 198.990 us; speedup vs baseline: 1.1980x; 1.0343x over previous
//
#include <hip/hip_runtime.h>
#include <hip/hip_bf16.h>

#define NU 50000
#define NI 20000
#define NN 70000
#define DD 128
#define BB 8192
#define EE 500000
#define ET 570000   // EE + NN self loops
#define NTASK 16384 // 2*BB

__device__ __forceinline__ float lrelu(float x) { return x > 0.f ? x : 0.2f * x; }

typedef __attribute__((ext_vector_type(8))) short bf16x8;   // 8 bf16 = 4 VGPRs
typedef __attribute__((ext_vector_type(8))) unsigned short u16x8;
typedef __attribute__((ext_vector_type(4))) float f32x4;

__device__ __forceinline__ unsigned short f2bf_rne(float f) {
  unsigned int u = __builtin_bit_cast(unsigned int, f);
  u += 0x7FFFu + ((u >> 16) & 1u);
  return (unsigned short)(u >> 16);
}
__device__ __forceinline__ float bf2f(unsigned short h) {
  unsigned int u = ((unsigned int)h) << 16;
  return __builtin_bit_cast(float, u);
}

// ---------------- fast workspace clear (replaces slow hipMemsetAsync fills) -------
// rangeA: -1 words (winner|map); rangeB,C: zero; out: zero (atomic target).
__global__ __launch_bounds__(256) void clear_kernel(
    unsigned int* __restrict__ wsw,
    unsigned int offA, unsigned int nA,
    unsigned int offB, unsigned int nB,
    unsigned int offC, unsigned int nC,
    float* __restrict__ out) {
  unsigned int idx = blockIdx.x * 256 + threadIdx.x;
  unsigned int stride = gridDim.x * 256;
  for (unsigned int i = idx; i < nA; i += stride) wsw[offA + i] = 0xFFFFFFFFu;
  for (unsigned int i = idx; i < nB; i += stride) wsw[offB + i] = 0u;
  for (unsigned int i = idx; i < nC; i += stride) wsw[offC + i] = 0u;
  for (unsigned int i = idx; i < BB; i += stride) out[i] = 0.f;
}

// ---------------- MFMA GEMM core: C[M,N] = A * Bt^T (+bias)(+relu) ----------------
// GATHER=0: A linear. GATHER=1: ph-style 3-section row gather. GATHER=2: row gather.
// MODE=0: f32 C. MODE=1: bf16 Cb + fused a1 attention-score atomics.
// MODE=2: fused final layer: relu(acc+bias) dot att_s(=pw2), + att_d[0](=pb2),
//         atomicAdd into a1s(=out). No C write.
template <int GATHER, int MODE>
__device__ __forceinline__ void gemm_core(
    int bm, int bn,
    const float* __restrict__ A,
    const unsigned short* __restrict__ Bh, const unsigned short* __restrict__ Bl,
    const float* __restrict__ bias, float* __restrict__ C,
    unsigned short* __restrict__ Cb, int ldc,
    int M, int N, int K, int act,
    const int* __restrict__ idx0, const int* __restrict__ idx1,
    const int* __restrict__ mapv,
    const float* __restrict__ gA0, const float* __restrict__ gA1,
    const float* __restrict__ att_s, const float* __restrict__ att_d,
    float* __restrict__ a1s, float* __restrict__ a1d) {
  __shared__ __align__(16) unsigned short sAh[8][64][8];
  __shared__ __align__(16) unsigned short sAl[8][64][8];
  __shared__ __align__(16) unsigned short sBh[8][64][8];
  __shared__ __align__(16) unsigned short sBl[8][64][8];
  int tid = threadIdx.x;
  int lane = tid & 63, w = tid >> 6;
  int wr = (w >> 1) * 32, wc = (w & 1) * 32;
  int fr = lane & 15, fk = lane >> 4;
  f32x4 acc[2][2] = {};

  for (int k0 = 0; k0 < K; k0 += 64) {
    __syncthreads();
#pragma unroll
    for (int t = 0; t < 2; t++) {
      int f = tid + t * 256;
      int row = f >> 3, kb = f & 7;
      int kg = k0 + kb * 8;
      const float* ap;
      if (GATHER == 1) {
        int sec = kg >> 7;           // 64-tiles never straddle 128-col sections
        int kc = kg & 127;
        int r = bm + row;
        if (sec == 0)      ap = &gA0[(size_t)idx0[r] * 128 + kc];
        else if (sec == 1) ap = &gA1[(size_t)mapv[NU + idx1[r]] * 128 + kc];
        else               ap = &gA1[(size_t)mapv[idx0[r]] * 128 + kc];
      } else if (GATHER == 2) {
        ap = &gA0[(size_t)idx0[bm + row] * K + kg];
      } else {
        ap = &A[(size_t)(bm + row) * K + kg];
      }
      float4 v0 = *reinterpret_cast<const float4*>(ap);
      float4 v1 = *reinterpret_cast<const float4*>(ap + 4);
      float vv[8] = {v0.x, v0.y, v0.z, v0.w, v1.x, v1.y, v1.z, v1.w};
      u16x8 hv, lv;
#pragma unroll
      for (int j = 0; j < 8; j++) {
        unsigned short hh = f2bf_rne(vv[j]);
        hv[j] = hh;
        lv[j] = (unsigned short)(__builtin_bit_cast(unsigned int, vv[j] - bf2f(hh)) >> 16);
      }
      *reinterpret_cast<u16x8*>(&sAh[kb][row][0]) = hv;
      *reinterpret_cast<u16x8*>(&sAl[kb][row][0]) = lv;
    }
#pragma unroll
    for (int t = 0; t < 2; t++) {
      int f = tid + t * 256;
      int row = f >> 3, kb = f & 7;
      int kg = k0 + kb * 8;
      *reinterpret_cast<u16x8*>(&sBh[kb][row][0]) =
          *reinterpret_cast<const u16x8*>(&Bh[(size_t)(bn + row) * K + kg]);
      *reinterpret_cast<u16x8*>(&sBl[kb][row][0]) =
          *reinterpret_cast<const u16x8*>(&Bl[(size_t)(bn + row) * K + kg]);
    }
    __syncthreads();
#pragma unroll
    for (int s = 0; s < 2; s++) {
      int kb = s * 4 + fk;
      bf16x8 ah0 = *reinterpret_cast<const bf16x8*>(&sAh[kb][wr + fr][0]);
      bf16x8 ah1 = *reinterpret_cast<const bf16x8*>(&sAh[kb][wr + 16 + fr][0]);
      bf16x8 al0 = *reinterpret_cast<const bf16x8*>(&sAl[kb][wr + fr][0]);
      bf16x8 al1 = *reinterpret_cast<const bf16x8*>(&sAl[kb][wr + 16 + fr][0]);
      bf16x8 bh0 = *reinterpret_cast<const bf16x8*>(&sBh[kb][wc + fr][0]);
      bf16x8 bh1 = *reinterpret_cast<const bf16x8*>(&sBh[kb][wc + 16 + fr][0]);
      bf16x8 bl0 = *reinterpret_cast<const bf16x8*>(&sBl[kb][wc + fr][0]);
      bf16x8 bl1 = *reinterpret_cast<const bf16x8*>(&sBl[kb][wc + 16 + fr][0]);
      acc[0][0] = __builtin_amdgcn_mfma_f32_16x16x32_bf16(al0, bh0, acc[0][0], 0, 0, 0);
      acc[0][0] = __builtin_amdgcn_mfma_f32_16x16x32_bf16(ah0, bl0, acc[0][0], 0, 0, 0);
      acc[0][0] = __builtin_amdgcn_mfma_f32_16x16x32_bf16(ah0, bh0, acc[0][0], 0, 0, 0);
      acc[0][1] = __builtin_amdgcn_mfma_f32_16x16x32_bf16(al0, bh1, acc[0][1], 0, 0, 0);
      acc[0][1] = __builtin_amdgcn_mfma_f32_16x16x32_bf16(ah0, bl1, acc[0][1], 0, 0, 0);
      acc[0][1] = __builtin_amdgcn_mfma_f32_16x16x32_bf16(ah0, bh1, acc[0][1], 0, 0, 0);
      acc[1][0] = __builtin_amdgcn_mfma_f32_16x16x32_bf16(al1, bh0, acc[1][0], 0, 0, 0);
      acc[1][0] = __builtin_amdgcn_mfma_f32_16x16x32_bf16(ah1, bl0, acc[1][0], 0, 0, 0);
      acc[1][0] = __builtin_amdgcn_mfma_f32_16x16x32_bf16(ah1, bh0, acc[1][0], 0, 0, 0);
      acc[1][1] = __builtin_amdgcn_mfma_f32_16x16x32_bf16(al1, bh1, acc[1][1], 0, 0, 0);
      acc[1][1] = __builtin_amdgcn_mfma_f32_16x16x32_bf16(ah1, bl1, acc[1][1], 0, 0, 0);
      acc[1][1] = __builtin_amdgcn_mfma_f32_16x16x32_bf16(ah1, bh1, acc[1][1], 0, 0, 0);
    }
  }
  if (MODE == 1) {
    int head = bn >> 7;
    float ps[2][4] = {{0.f}}, pd[2][4] = {{0.f}};
#pragma unroll
    for (int j = 0; j < 2; j++) {
      int col = bn + wc + j * 16 + fr;
      float asc = att_s[col], adc = att_d[col];
#pragma unroll
      for (int i = 0; i < 2; i++) {
#pragma unroll
        for (int r = 0; r < 4; r++) {
          float v = acc[i][j][r];
          ps[i][r] += v * asc;
          pd[i][r] += v * adc;
          Cb[(size_t)(bm + wr + i * 16 + fk * 4 + r) * ldc + col] = f2bf_rne(v);
        }
      }
    }
#pragma unroll
    for (int o = 1; o < 16; o <<= 1) {
#pragma unroll
      for (int i = 0; i < 2; i++)
#pragma unroll
        for (int r = 0; r < 4; r++) {
          ps[i][r] += __shfl_xor(ps[i][r], o);
          pd[i][r] += __shfl_xor(pd[i][r], o);
        }
    }
    if (fr == 0) {
#pragma unroll
      for (int i = 0; i < 2; i++) {
#pragma unroll
        for (int r = 0; r < 4; r++) {
          int t = bm + wr + i * 16 + fk * 4 + r;
          int v = (t < BB) ? idx0[t] : NU + idx1[t - BB];
          if (mapv[v] == t) {   // rep task only (dups would double-count)
            atomicAdd(&a1s[(size_t)v * 2 + head], ps[i][r]);
            atomicAdd(&a1d[(size_t)v * 2 + head], pd[i][r]);
          }
        }
      }
    }
    return;
  }
  if (MODE == 2) {
    // fused prediction head: out[row] += sum_col relu(acc+pb1[col]) * pw2[col]
    float part[2][4] = {{0.f}};
#pragma unroll
    for (int j = 0; j < 2; j++) {
      int col = bn + wc + j * 16 + fr;
      float bj = bias[col];
      float wv = att_s[col];
#pragma unroll
      for (int i = 0; i < 2; i++) {
#pragma unroll
        for (int r = 0; r < 4; r++) {
          float v = fmaxf(acc[i][j][r] + bj, 0.f);
          part[i][r] += v * wv;
        }
      }
    }
#pragma unroll
    for (int o = 1; o < 16; o <<= 1) {
#pragma unroll
      for (int i = 0; i < 2; i++)
#pragma unroll
        for (int r = 0; r < 4; r++) part[i][r] += __shfl_xor(part[i][r], o);
    }
    if (fr == 0) {
#pragma unroll
      for (int i = 0; i < 2; i++) {
#pragma unroll
        for (int r = 0; r < 4; r++) {
          int row = bm + wr + i * 16 + fk * 4 + r;
          float add = part[i][r];
          if (bn == 0 && wc == 0) add += att_d[0];   // pb2 exactly once per row
          atomicAdd(&a1s[row], add);
        }
      }
    }
    return;
  }
#pragma unroll
  for (int j = 0; j < 2; j++) {
    int col = bn + wc + j * 16 + fr;
    float bj = bias ? bias[col] : 0.f;
#pragma unroll
    for (int i = 0; i < 2; i++) {
#pragma unroll
      for (int r = 0; r < 4; r++) {
        int row = bm + wr + i * 16 + fk * 4 + r;
        float v = acc[i][j][r] + bj;
        if (act == 1) v = fmaxf(v, 0.f);
        C[(size_t)row * ldc + col] = v;
      }
    }
  }
}

template <int GATHER, int MODE>
__global__ __launch_bounds__(256) void gemm_mfma(
    const float* __restrict__ A,
    const unsigned short* __restrict__ Bh, const unsigned short* __restrict__ Bl,
    const float* __restrict__ bias, float* __restrict__ C,
    unsigned short* __restrict__ Cb, int ldc,
    int M, int N, int K, int act,
    const int* __restrict__ idx0, const int* __restrict__ idx1,
    const int* __restrict__ mapv,
    const float* __restrict__ gA0, const float* __restrict__ gA1,
    const float* __restrict__ att_s, const float* __restrict__ att_d,
    float* __restrict__ a1s, float* __restrict__ a1d) {
  gemm_core<GATHER, MODE>(blockIdx.x * 64, blockIdx.y * 64,
                          A, Bh, Bl, bias, C, Cb, ldc, M, N, K, act,
                          idx0, idx1, mapv, gA0, gA1, att_s, att_d, a1s, a1d);
}

// cemb GEMM (gather-A) + CSR fill + needed-mark in ONE launch (independent work).
#define GEMMB 256  // (BB/64) * (DD/64)
__global__ __launch_bounds__(256) void cembfill_kernel(
    const unsigned short* __restrict__ wch, const unsigned short* __restrict__ wcl,
    const float* __restrict__ bc, float* __restrict__ XaC,
    const int* __restrict__ widx, const float* __restrict__ content,
    const int* __restrict__ ei, int* __restrict__ fill, int* __restrict__ col,
    const int* __restrict__ mapv, unsigned char* __restrict__ needed) {
  int bid = blockIdx.x;
  if (bid < GEMMB) {
    gemm_core<2, 0>((bid >> 1) * 64, (bid & 1) * 64,
                    nullptr, wch, wcl, bc, XaC, nullptr, 256,
                    BB, DD, 512, 0, widx, nullptr, nullptr, content, nullptr,
                    nullptr, nullptr, nullptr, nullptr);
    return;
  }
  int e = (bid - GEMMB) * 256 + threadIdx.x;
  if (e >= ET) return;
  int src, dst;
  if (e < EE) { src = ei[e]; dst = ei[EE + e]; }
  else { src = e - EE; dst = src; }
  int pos = atomicAdd(&fill[dst], 1);
  col[pos] = src;
  if (mapv[dst] >= 0) needed[src] = 1;
}

// ---------------- mega-setup: deg+winner atomics | weight split | Xa-emb+map ------
#define EB 2227    // ceil(ET/256)
#define SPLB 832   // (65536+65536+32768+49152)/256
#define XAB 4096   // NTASK/4
__global__ __launch_bounds__(256) void setup_kernel(
    const int* __restrict__ ei, const int* __restrict__ uid, const int* __restrict__ iid,
    int* __restrict__ deg, int* __restrict__ winner,
    const float* __restrict__ wc, unsigned short* wch, unsigned short* wcl,
    const float* __restrict__ w1, unsigned short* w1h, unsigned short* w1l,
    const float* __restrict__ w2, unsigned short* w2h, unsigned short* w2l,
    const float* __restrict__ pw1, unsigned short* p1h, unsigned short* p1l,
    const float* __restrict__ uemb, const float* __restrict__ iemb,
    float* __restrict__ Xa, int* __restrict__ map) {
  int bid = blockIdx.x, tid = threadIdx.x;
  if (bid < EB) {
    int e = bid * 256 + tid;
    if (e < BB) atomicMax(&winner[iid[e]], e);
    if (e >= ET) return;
    int dst = (e < EE) ? ei[EE + e] : (e - EE);
    atomicAdd(&deg[dst], 1);
    return;
  }
  if (bid < EB + SPLB) {
    int i = (bid - EB) * 256 + tid;
    const float* w; unsigned short* h; unsigned short* l; int idx;
    if (i < 65536) { w = wc; h = wch; l = wcl; idx = i; }
    else if (i < 131072) { w = w1; h = w1h; l = w1l; idx = i - 65536; }
    else if (i < 163840) { w = w2; h = w2h; l = w2l; idx = i - 131072; }
    else { w = pw1; h = p1h; l = p1l; idx = i - 163840; }
    float f = w[idx];
    unsigned short hh = f2bf_rne(f);
    h[idx] = hh;
    l[idx] = (unsigned short)(__builtin_bit_cast(unsigned int, f - bf2f(hh)) >> 16);
    return;
  }
  int t = (bid - EB - SPLB) * 4 + (tid >> 6);
  int lane = tid & 63;
  int c4 = lane * 4;
  if (t < BB) {
    int u = uid[t];
    float4 v = make_float4(0.f, 0.f, 0.f, 0.f);
    if (c4 < DD) v = *reinterpret_cast<const float4*>(&uemb[(size_t)u * DD + c4]);
    *reinterpret_cast<float4*>(&Xa[(size_t)t * 256 + c4]) = v;
    if (lane == 0) map[u] = t;
  } else {
    int it = iid[t - BB];
    if (c4 < DD) {
      float4 v = *reinterpret_cast<const float4*>(&iemb[(size_t)it * DD + c4]);
      *reinterpret_cast<float4*>(&Xa[(size_t)t * 256 + c4]) = v;
    }
    if (lane == 0) map[NU + it] = t;
  }
}

// rowstart + widx; last block computes the conv2 q-vectors.
__global__ void rowstart_kernel(const int* __restrict__ deg, const int* __restrict__ winner,
                                const int* __restrict__ iid,
                                int* __restrict__ rowstart, int* __restrict__ fill,
                                int* __restrict__ counter, int* __restrict__ widx,
                                const float* __restrict__ w2,
                                const float* __restrict__ att2s, const float* __restrict__ att2d,
                                float* __restrict__ qs, float* __restrict__ qd) {
  int blk = blockIdx.x;
  if (blk == (NN + 255) / 256) {
    int k = threadIdx.x;
    float s = 0.f, d = 0.f;
#pragma unroll 4
    for (int j = 0; j < DD; j++) {
      float w = w2[(size_t)j * 256 + k];
      s += att2s[j] * w;
      d += att2d[j] * w;
    }
    qs[k] = s;
    qd[k] = d;
    return;
  }
  int v = blk * 256 + threadIdx.x;
  if (v < BB) widx[v] = winner[iid[v]];
  if (v >= NN) return;
  int s = atomicAdd(counter, deg[v]);
  rowstart[v] = s;
  fill[v] = s;
}

// conv1 aggregation: bf16 Hb gather, needed-skip, online softmax, fused a2 scores.
// Fast path d<=64 with BALLOT-COMPACTED gather (only edges with map[src]>=0 ~20%).
__global__ __launch_bounds__(256) void conv1_agg_kernel(
    const int* __restrict__ col, const int* __restrict__ rowstart,
    const int* __restrict__ deg, const unsigned short* __restrict__ Hb,
    const int* __restrict__ map, const unsigned char* __restrict__ needed,
    const float* __restrict__ a1s, const float* __restrict__ a1d,
    const float* __restrict__ bias,
    const float* __restrict__ qs, const float* __restrict__ qd,
    unsigned short* __restrict__ x1b, float* __restrict__ a2s, float* __restrict__ a2d) {
  int v = blockIdx.x * 4 + (threadIdx.x >> 6);
  int lane = threadIdx.x & 63;
  if (!needed[v]) return;
  int head = lane >> 5;
  int d = deg[v], s0 = rowstart[v];
  float2 adv = *reinterpret_cast<const float2*>(&a1d[(size_t)v * 2]);
  float4 acc = make_float4(0.f, 0.f, 0.f, 0.f);
  float den;
  const unsigned short* hb = Hb + (lane << 2);
  if (d <= 64) {
    bool act = lane < d;
    int ci = act ? col[s0 + lane] : 0;
    float2 asv = make_float2(0.f, 0.f);
    int ri = -1;
    if (act) {
      asv = *reinterpret_cast<const float2*>(&a1s[(size_t)ci * 2]);
      ri = map[ci];
    }
    float al0 = act ? lrelu(asv.x + adv.x) : -1e30f;
    float al1 = act ? lrelu(asv.y + adv.y) : -1e30f;
    float m0 = al0, m1 = al1;
#pragma unroll
    for (int o = 1; o < 64; o <<= 1) {
      m0 = fmaxf(m0, __shfl_xor(m0, o));
      m1 = fmaxf(m1, __shfl_xor(m1, o));
    }
    float ex0 = act ? __expf(al0 - m0) : 0.f;
    float ex1 = act ? __expf(al1 - m1) : 0.f;
    float cs0 = ex0, cs1 = ex1;
#pragma unroll
    for (int o = 1; o < 64; o <<= 1) {
      cs0 += __shfl_xor(cs0, o);
      cs1 += __shfl_xor(cs1, o);
    }
    den = head ? cs1 : cs0;
    // compacted gather: only lanes whose edge source is a batch node
    unsigned long long msk = __ballot(act && ri >= 0);
    while (msk) {
      int s = __ffsll((unsigned long long)msk) - 1;
      msk &= msk - 1;
      int r = __shfl(ri, s);
      float e0 = __shfl(ex0, s), e1 = __shfl(ex1, s);
      float ex = head ? e1 : e0;
      ushort4 hv = *reinterpret_cast<const ushort4*>(&hb[(size_t)r << 8]);
      acc.x += ex * bf2f(hv.x); acc.y += ex * bf2f(hv.y);
      acc.z += ex * bf2f(hv.z); acc.w += ex * bf2f(hv.w);
    }
  } else {
    float m0 = -1e30f, m1 = -1e30f, den0 = 0.f, den1 = 0.f;
    for (int c0 = 0; c0 < d; c0 += 64) {
      int i = c0 + lane;
      bool act = i < d;
      int ci = act ? col[s0 + i] : 0;
      float2 asv = make_float2(0.f, 0.f);
      int ri = -1;
      if (act) {
        asv = *reinterpret_cast<const float2*>(&a1s[(size_t)ci * 2]);
        ri = map[ci];
      }
      float al0 = act ? lrelu(asv.x + adv.x) : -1e30f;
      float al1 = act ? lrelu(asv.y + adv.y) : -1e30f;
      float cm0 = al0, cm1 = al1;
#pragma unroll
      for (int o = 1; o < 64; o <<= 1) {
        cm0 = fmaxf(cm0, __shfl_xor(cm0, o));
        cm1 = fmaxf(cm1, __shfl_xor(cm1, o));
      }
      float nm0 = fmaxf(m0, cm0), nm1 = fmaxf(m1, cm1);
      float ex0 = act ? __expf(al0 - nm0) : 0.f;
      float ex1 = act ? __expf(al1 - nm1) : 0.f;
      float s0f = __expf(m0 - nm0), s1f = __expf(m1 - nm1);
      float cs0 = ex0, cs1 = ex1;
#pragma unroll
      for (int o = 1; o < 64; o <<= 1) {
        cs0 += __shfl_xor(cs0, o);
        cs1 += __shfl_xor(cs1, o);
      }
      den0 = den0 * s0f + cs0;
      den1 = den1 * s1f + cs1;
      float sc = head ? s1f : s0f;
      acc.x *= sc; acc.y *= sc; acc.z *= sc; acc.w *= sc;
      unsigned long long msk = __ballot(act && ri >= 0);
      while (msk) {
        int s = __ffsll((unsigned long long)msk) - 1;
        msk &= msk - 1;
        int r = __shfl(ri, s);
        float e0 = __shfl(ex0, s), e1 = __shfl(ex1, s);
        float ex = head ? e1 : e0;
        ushort4 hv = *reinterpret_cast<const ushort4*>(&hb[(size_t)r << 8]);
        acc.x += ex * bf2f(hv.x); acc.y += ex * bf2f(hv.y);
        acc.z += ex * bf2f(hv.z); acc.w += ex * bf2f(hv.w);
      }
      m0 = nm0; m1 = nm1;
    }
    den = head ? den1 : den0;
  }
  float inv = 1.f / den;
  float4 b4 = *reinterpret_cast<const float4*>(&bias[lane << 2]);
  float4 o;
  o.x = fmaf(acc.x, inv, b4.x);
  o.y = fmaf(acc.y, inv, b4.y);
  o.z = fmaf(acc.z, inv, b4.z);
  o.w = fmaf(acc.w, inv, b4.w);
  o.x = o.x > 0.f ? o.x : __expf(o.x) - 1.f;
  o.y = o.y > 0.f ? o.y : __expf(o.y) - 1.f;
  o.z = o.z > 0.f ? o.z : __expf(o.z) - 1.f;
  o.w = o.w > 0.f ? o.w : __expf(o.w) - 1.f;
  ushort4 st;
  st.x = f2bf_rne(o.x); st.y = f2bf_rne(o.y);
  st.z = f2bf_rne(o.z); st.w = f2bf_rne(o.w);
  *reinterpret_cast<ushort4*>(&x1b[((size_t)v << 8) + (lane << 2)]) = st;
  float4 sv = *reinterpret_cast<const float4*>(&qs[lane << 2]);
  float4 dv = *reinterpret_cast<const float4*>(&qd[lane << 2]);
  float ps = o.x * sv.x + o.y * sv.y + o.z * sv.z + o.w * sv.w;
  float pd = o.x * dv.x + o.y * dv.y + o.z * dv.z + o.w * dv.w;
#pragma unroll
  for (int of = 1; of < 64; of <<= 1) { ps += __shfl_xor(ps, of); pd += __shfl_xor(pd, of); }
  if (lane == 0) { a2s[v] = ps; a2d[v] = pd; }
}

// conv2 aggregation, representative tasks only (map[v]==t); bf16 x1 gather.
__global__ __launch_bounds__(256) void conv2_agg_kernel(
    const int* __restrict__ uid, const int* __restrict__ iid,
    const int* __restrict__ col, const int* __restrict__ rowstart,
    const int* __restrict__ deg, const int* __restrict__ map,
    const unsigned short* __restrict__ x1b,
    const float* __restrict__ a2s, const float* __restrict__ a2d,
    float* __restrict__ agg) {
  int t = blockIdx.x * 4 + (threadIdx.x >> 6);
  int lane = threadIdx.x & 63;
  int v = (t < BB) ? uid[t] : NU + iid[t - BB];
  if (map[v] != t) return;  // duplicates gather the rep's row via map in the ph GEMM
  int d = deg[v], s0 = rowstart[v];
  float ad = a2d[v];
  float4 acc = make_float4(0.f, 0.f, 0.f, 0.f);
  float den;
  const unsigned short* xb = x1b + (lane << 2);
  if (d <= 64) {
    bool act = lane < d;
    int ci = act ? col[s0 + lane] : 0;
    float as = act ? a2s[ci] : 0.f;
    float al = act ? lrelu(as + ad) : -1e30f;
    float m = al;
#pragma unroll
    for (int o = 1; o < 64; o <<= 1) m = fmaxf(m, __shfl_xor(m, o));
    float ex = act ? __expf(al - m) : 0.f;
    float cs = ex;
#pragma unroll
    for (int o = 1; o < 64; o <<= 1) cs += __shfl_xor(cs, o);
    den = cs;
    for (int i2 = 0; i2 < d; i2++) {
      int r = __shfl(ci, i2);
      float e = __shfl(ex, i2);
      ushort4 hv = *reinterpret_cast<const ushort4*>(&xb[(size_t)r << 8]);
      acc.x += e * bf2f(hv.x); acc.y += e * bf2f(hv.y);
      acc.z += e * bf2f(hv.z); acc.w += e * bf2f(hv.w);
    }
  } else {
    float m = -1e30f; den = 0.f;
    for (int c0 = 0; c0 < d; c0 += 64) {
      int i = c0 + lane;
      bool act = i < d;
      int ci = act ? col[s0 + i] : 0;
      float as = act ? a2s[ci] : 0.f;
      float al = act ? lrelu(as + ad) : -1e30f;
      float cm = al;
#pragma unroll
      for (int o = 1; o < 64; o <<= 1) cm = fmaxf(cm, __shfl_xor(cm, o));
      float nm = fmaxf(m, cm);
      float ex = act ? __expf(al - nm) : 0.f;
      float sf = __expf(m - nm);
      float cs = ex;
#pragma unroll
      for (int o = 1; o < 64; o <<= 1) cs += __shfl_xor(cs, o);
      den = den * sf + cs;
      acc.x *= sf; acc.y *= sf; acc.z *= sf; acc.w *= sf;
      int n = min(64, d - c0);
      for (int i2 = 0; i2 < n; i2++) {
        int r = __shfl(ci, i2);
        float e = __shfl(ex, i2);
        ushort4 hv = *reinterpret_cast<const ushort4*>(&xb[(size_t)r << 8]);
        acc.x += e * bf2f(hv.x); acc.y += e * bf2f(hv.y);
        acc.z += e * bf2f(hv.z); acc.w += e * bf2f(hv.w);
      }
      m = nm;
    }
  }
  float inv = 1.f / den;
  float4 o = make_float4(acc.x * inv, acc.y * inv, acc.z * inv, acc.w * inv);
  *reinterpret_cast<float4*>(&agg[((size_t)t << 8) + (lane << 2)]) = o;
}

// ---------------- launcher ----------------
extern "C" void kernel_launch(void* const* d_in, const int* in_sizes, int n_in,
                              void* d_out, int out_size, void* d_ws, size_t ws_size,
                              hipStream_t stream) {
  const int* uid = (const int*)d_in[0];
  const int* iid = (const int*)d_in[1];
  const float* content = (const float*)d_in[2];
  const int* ei = (const int*)d_in[3];
  const float* uemb = (const float*)d_in[4];
  const float* iemb = (const float*)d_in[5];
  const float* wc = (const float*)d_in[6];
  const float* bc = (const float*)d_in[7];
  const float* w1 = (const float*)d_in[8];
  const float* att1s = (const float*)d_in[9];
  const float* att1d = (const float*)d_in[10];
  const float* b1 = (const float*)d_in[11];
  const float* w2 = (const float*)d_in[12];
  const float* att2s = (const float*)d_in[13];
  const float* att2d = (const float*)d_in[14];
  const float* b2c = (const float*)d_in[15];
  const float* pw1 = (const float*)d_in[16];
  const float* pb1 = (const float*)d_in[17];
  const float* pw2 = (const float*)d_in[18];
  const float* pb2 = (const float*)d_in[19];
  float* out = (float*)d_out;
  char* ws = (char*)d_ws;

  size_t off = 0;
  auto alloc = [&](size_t bytes) {
    size_t o = off;
    off += (bytes + 255) & ~(size_t)255;
    return o;
  };
  size_t o_winner  = alloc(NI * 4);
  size_t o_map     = alloc(NN * 4);
  size_t o_a1s     = alloc((size_t)NN * 2 * 4);
  size_t o_a1d     = alloc((size_t)NN * 2 * 4);
  size_t o_deg     = alloc(NN * 4);
  size_t o_rs      = alloc(NN * 4);
  size_t o_fill    = alloc(NN * 4);
  size_t o_cnt     = alloc(4);
  size_t o_needed  = alloc(NN);
  size_t o_col     = alloc((size_t)ET * 4);
  size_t o_a2s     = alloc(NN * 4);
  size_t o_a2d     = alloc(NN * 4);
  size_t o_qs      = alloc(256 * 4);
  size_t o_qd      = alloc(256 * 4);
  size_t o_widx    = alloc(BB * 4);
  size_t o_wch = alloc(65536 * 2),  o_wcl = alloc(65536 * 2);
  size_t o_w1h = alloc(65536 * 2),  o_w1l = alloc(65536 * 2);
  size_t o_w2h = alloc(32768 * 2),  o_w2l = alloc(32768 * 2);
  size_t o_p1h = alloc(49152 * 2),  o_p1l = alloc(49152 * 2);
  // region R1 (25.2MB): Xa f32 (16.78M) | Hb bf16 (8.39M)
  size_t o_r1    = alloc(16777216 + 8388608);
  size_t o_xa    = o_r1;
  size_t o_hb    = o_r1 + 16777216;
  size_t o_agg   = o_r1;
  size_t o_out2c = o_r1 + 16777216;
  size_t o_x1b   = alloc((size_t)NN * 256 * 2);
  (void)ws_size; (void)in_sizes; (void)n_in; (void)out_size;

  int*   winner = (int*)(ws + o_winner);
  int*   map    = (int*)(ws + o_map);
  float* a1s    = (float*)(ws + o_a1s);
  float* a1d    = (float*)(ws + o_a1d);
  int*   deg    = (int*)(ws + o_deg);
  int*   rs     = (int*)(ws + o_rs);
  int*   fill   = (int*)(ws + o_fill);
  int*   cnt    = (int*)(ws + o_cnt);
  unsigned char* needed = (unsigned char*)(ws + o_needed);
  int*   col    = (int*)(ws + o_col);
  float* a2s    = (float*)(ws + o_a2s);
  float* a2d    = (float*)(ws + o_a2d);
  float* qs     = (float*)(ws + o_qs);
  float* qd     = (float*)(ws + o_qd);
  int*   widx   = (int*)(ws + o_widx);
  unsigned short* wch = (unsigned short*)(ws + o_wch);
  unsigned short* wcl = (unsigned short*)(ws + o_wcl);
  unsigned short* w1h = (unsigned short*)(ws + o_w1h);
  unsigned short* w1l = (unsigned short*)(ws + o_w1l);
  unsigned short* w2h = (unsigned short*)(ws + o_w2h);
  unsigned short* w2l = (unsigned short*)(ws + o_w2l);
  unsigned short* p1h = (unsigned short*)(ws + o_p1h);
  unsigned short* p1l = (unsigned short*)(ws + o_p1l);
  float* Xa     = (float*)(ws + o_xa);
  unsigned short* Hb = (unsigned short*)(ws + o_hb);
  float* agg    = (float*)(ws + o_agg);
  float* out2c  = (float*)(ws + o_out2c);
  unsigned short* x1b = (unsigned short*)(ws + o_x1b);

  // one fast grid-strided clear replaces 4 slow runtime fills:
  //  A: winner|map -> -1 words ; B: a1s|a1d -> 0 ; C: deg..needed -> 0 ; out -> 0
  {
    unsigned int offA = (unsigned int)(o_winner >> 2);
    unsigned int nA   = (unsigned int)((o_map - o_winner) / 4 + NN);
    unsigned int offB = (unsigned int)(o_a1s >> 2);
    unsigned int nB   = (unsigned int)((o_a1d - o_a1s) / 4 + (size_t)NN * 2);
    unsigned int offC = (unsigned int)(o_deg >> 2);
    unsigned int nC   = (unsigned int)((o_needed - o_deg) / 4 + NN / 4);
    clear_kernel<<<1024, 256, 0, stream>>>((unsigned int*)ws, offA, nA, offB, nB,
                                           offC, nC, out);
  }

  setup_kernel<<<EB + SPLB + XAB, 256, 0, stream>>>(
      ei, uid, iid, deg, winner,
      wc, wch, wcl, w1, w1h, w1l, w2, w2h, w2l, pw1, p1h, p1l,
      uemb, iemb, Xa, map);
  rowstart_kernel<<<(NN + 255) / 256 + 1, 256, 0, stream>>>(
      deg, winner, iid, rs, fill, cnt, widx, w2, att2s, att2d, qs, qd);
  cembfill_kernel<<<GEMMB + EB, 256, 0, stream>>>(
      wch, wcl, bc, Xa + (size_t)BB * 256 + 128, widx, content,
      ei, fill, col, map, needed);
  // Hb = bf16(Xa @ W1^T), with fused a1 score atomics
  {
    dim3 g(NTASK / 64, 256 / 64);
    gemm_mfma<0, 1><<<g, 256, 0, stream>>>(
        Xa, w1h, w1l, nullptr, nullptr, Hb, 256,
        NTASK, 256, 256, 0, uid, iid, map, nullptr, nullptr,
        att1s, att1d, a1s, a1d);
  }
  conv1_agg_kernel<<<NN / 4, 256, 0, stream>>>(col, rs, deg, Hb, map, needed,
                                               a1s, a1d, b1, qs, qd, x1b, a2s, a2d);
  conv2_agg_kernel<<<NTASK / 4, 256, 0, stream>>>(uid, iid, col, rs, deg, map,
                                                  x1b, a2s, a2d, agg);
  // out2c = agg @ W2^T + b2c
  {
    dim3 g(NTASK / 64, DD / 64);
    gemm_mfma<0, 0><<<g, 256, 0, stream>>>(
        agg, w2h, w2l, b2c, out2c, nullptr, 128,
        NTASK, DD, 256, 0, nullptr, nullptr, nullptr, nullptr, nullptr,
        nullptr, nullptr, nullptr, nullptr);
  }
  // fused: out[b] = relu([uemb|out2c_i|out2c_u] @ pw1^T + pb1) . pw2 + pb2
  {
    dim3 g(BB / 64, DD / 64);
    gemm_mfma<1, 2><<<g, 256, 0, stream>>>(
        nullptr, p1h, p1l, pb1, nullptr, nullptr, 128,
        BB, DD, 384, 0, uid, iid, map, uemb, out2c,
        pw2, pb2, out, nullptr);
  }
}

// Round 13
// 196.331 us; speedup vs baseline: 1.2143x; 1.0135x over previous
//
#include <hip/hip_runtime.h>
#include <hip/hip_bf16.h>

#define NU 50000
#define NI 20000
#define NN 70000
#define DD 128
#define BB 8192
#define EE 500000
#define ET 570000   // EE + NN self loops
#define NTASK 16384 // 2*BB

__device__ __forceinline__ float lrelu(float x) { return x > 0.f ? x : 0.2f * x; }

typedef __attribute__((ext_vector_type(8))) short bf16x8;   // 8 bf16 = 4 VGPRs
typedef __attribute__((ext_vector_type(8))) unsigned short u16x8;
typedef __attribute__((ext_vector_type(4))) float f32x4;

__device__ __forceinline__ unsigned short f2bf_rne(float f) {
  unsigned int u = __builtin_bit_cast(unsigned int, f);
  u += 0x7FFFu + ((u >> 16) & 1u);
  return (unsigned short)(u >> 16);
}
__device__ __forceinline__ float bf2f(unsigned short h) {
  unsigned int u = ((unsigned int)h) << 16;
  return __builtin_bit_cast(float, u);
}

// ---------------- fast workspace clear (replaces slow hipMemsetAsync fills) -------
__global__ __launch_bounds__(256) void clear_kernel(
    unsigned int* __restrict__ wsw,
    unsigned int offA, unsigned int nA,
    unsigned int offB, unsigned int nB,
    unsigned int offC, unsigned int nC,
    float* __restrict__ out) {
  unsigned int idx = blockIdx.x * 256 + threadIdx.x;
  unsigned int stride = gridDim.x * 256;
  for (unsigned int i = idx; i < nA; i += stride) wsw[offA + i] = 0xFFFFFFFFu;
  for (unsigned int i = idx; i < nB; i += stride) wsw[offB + i] = 0u;
  for (unsigned int i = idx; i < nC; i += stride) wsw[offC + i] = 0u;
  for (unsigned int i = idx; i < BB; i += stride) out[i] = 0.f;
}

// ---------------- MFMA GEMM core: C[M,N] = A * Bt^T (+bias)(+relu) ----------------
// GATHER=0: A linear. GATHER=1: ph-style 3-section row gather. GATHER=2: row gather.
// MODE=0: f32 C. MODE=1: bf16 Cb + fused a1 attention-score atomics.
// MODE=2: fused final layer: relu(acc+bias) dot att_s(=pw2), + att_d[0](=pb2),
//         atomicAdd into a1s(=out). No C write.
template <int GATHER, int MODE>
__device__ __forceinline__ void gemm_core(
    int bm, int bn,
    const float* __restrict__ A,
    const unsigned short* __restrict__ Bh, const unsigned short* __restrict__ Bl,
    const float* __restrict__ bias, float* __restrict__ C,
    unsigned short* __restrict__ Cb, int ldc,
    int M, int N, int K, int act,
    const int* __restrict__ idx0, const int* __restrict__ idx1,
    const int* __restrict__ mapv,
    const float* __restrict__ gA0, const float* __restrict__ gA1,
    const float* __restrict__ att_s, const float* __restrict__ att_d,
    float* __restrict__ a1s, float* __restrict__ a1d) {
  __shared__ __align__(16) unsigned short sAh[8][64][8];
  __shared__ __align__(16) unsigned short sAl[8][64][8];
  __shared__ __align__(16) unsigned short sBh[8][64][8];
  __shared__ __align__(16) unsigned short sBl[8][64][8];
  int tid = threadIdx.x;
  int lane = tid & 63, w = tid >> 6;
  int wr = (w >> 1) * 32, wc = (w & 1) * 32;
  int fr = lane & 15, fk = lane >> 4;
  f32x4 acc[2][2] = {};

  for (int k0 = 0; k0 < K; k0 += 64) {
    __syncthreads();
#pragma unroll
    for (int t = 0; t < 2; t++) {
      int f = tid + t * 256;
      int row = f >> 3, kb = f & 7;
      int kg = k0 + kb * 8;
      const float* ap;
      if (GATHER == 1) {
        int sec = kg >> 7;           // 64-tiles never straddle 128-col sections
        int kc = kg & 127;
        int r = bm + row;
        if (sec == 0)      ap = &gA0[(size_t)idx0[r] * 128 + kc];
        else if (sec == 1) ap = &gA1[(size_t)mapv[NU + idx1[r]] * 128 + kc];
        else               ap = &gA1[(size_t)mapv[idx0[r]] * 128 + kc];
      } else if (GATHER == 2) {
        ap = &gA0[(size_t)idx0[bm + row] * K + kg];
      } else {
        ap = &A[(size_t)(bm + row) * K + kg];
      }
      float4 v0 = *reinterpret_cast<const float4*>(ap);
      float4 v1 = *reinterpret_cast<const float4*>(ap + 4);
      float vv[8] = {v0.x, v0.y, v0.z, v0.w, v1.x, v1.y, v1.z, v1.w};
      u16x8 hv, lv;
#pragma unroll
      for (int j = 0; j < 8; j++) {
        unsigned short hh = f2bf_rne(vv[j]);
        hv[j] = hh;
        lv[j] = (unsigned short)(__builtin_bit_cast(unsigned int, vv[j] - bf2f(hh)) >> 16);
      }
      *reinterpret_cast<u16x8*>(&sAh[kb][row][0]) = hv;
      *reinterpret_cast<u16x8*>(&sAl[kb][row][0]) = lv;
    }
#pragma unroll
    for (int t = 0; t < 2; t++) {
      int f = tid + t * 256;
      int row = f >> 3, kb = f & 7;
      int kg = k0 + kb * 8;
      *reinterpret_cast<u16x8*>(&sBh[kb][row][0]) =
          *reinterpret_cast<const u16x8*>(&Bh[(size_t)(bn + row) * K + kg]);
      *reinterpret_cast<u16x8*>(&sBl[kb][row][0]) =
          *reinterpret_cast<const u16x8*>(&Bl[(size_t)(bn + row) * K + kg]);
    }
    __syncthreads();
#pragma unroll
    for (int s = 0; s < 2; s++) {
      int kb = s * 4 + fk;
      bf16x8 ah0 = *reinterpret_cast<const bf16x8*>(&sAh[kb][wr + fr][0]);
      bf16x8 ah1 = *reinterpret_cast<const bf16x8*>(&sAh[kb][wr + 16 + fr][0]);
      bf16x8 al0 = *reinterpret_cast<const bf16x8*>(&sAl[kb][wr + fr][0]);
      bf16x8 al1 = *reinterpret_cast<const bf16x8*>(&sAl[kb][wr + 16 + fr][0]);
      bf16x8 bh0 = *reinterpret_cast<const bf16x8*>(&sBh[kb][wc + fr][0]);
      bf16x8 bh1 = *reinterpret_cast<const bf16x8*>(&sBh[kb][wc + 16 + fr][0]);
      bf16x8 bl0 = *reinterpret_cast<const bf16x8*>(&sBl[kb][wc + fr][0]);
      bf16x8 bl1 = *reinterpret_cast<const bf16x8*>(&sBl[kb][wc + 16 + fr][0]);
      acc[0][0] = __builtin_amdgcn_mfma_f32_16x16x32_bf16(al0, bh0, acc[0][0], 0, 0, 0);
      acc[0][0] = __builtin_amdgcn_mfma_f32_16x16x32_bf16(ah0, bl0, acc[0][0], 0, 0, 0);
      acc[0][0] = __builtin_amdgcn_mfma_f32_16x16x32_bf16(ah0, bh0, acc[0][0], 0, 0, 0);
      acc[0][1] = __builtin_amdgcn_mfma_f32_16x16x32_bf16(al0, bh1, acc[0][1], 0, 0, 0);
      acc[0][1] = __builtin_amdgcn_mfma_f32_16x16x32_bf16(ah0, bl1, acc[0][1], 0, 0, 0);
      acc[0][1] = __builtin_amdgcn_mfma_f32_16x16x32_bf16(ah0, bh1, acc[0][1], 0, 0, 0);
      acc[1][0] = __builtin_amdgcn_mfma_f32_16x16x32_bf16(al1, bh0, acc[1][0], 0, 0, 0);
      acc[1][0] = __builtin_amdgcn_mfma_f32_16x16x32_bf16(ah1, bl0, acc[1][0], 0, 0, 0);
      acc[1][0] = __builtin_amdgcn_mfma_f32_16x16x32_bf16(ah1, bh0, acc[1][0], 0, 0, 0);
      acc[1][1] = __builtin_amdgcn_mfma_f32_16x16x32_bf16(al1, bh1, acc[1][1], 0, 0, 0);
      acc[1][1] = __builtin_amdgcn_mfma_f32_16x16x32_bf16(ah1, bl1, acc[1][1], 0, 0, 0);
      acc[1][1] = __builtin_amdgcn_mfma_f32_16x16x32_bf16(ah1, bh1, acc[1][1], 0, 0, 0);
    }
  }
  if (MODE == 1) {
    int head = bn >> 7;
    float ps[2][4] = {{0.f}}, pd[2][4] = {{0.f}};
#pragma unroll
    for (int j = 0; j < 2; j++) {
      int col = bn + wc + j * 16 + fr;
      float asc = att_s[col], adc = att_d[col];
#pragma unroll
      for (int i = 0; i < 2; i++) {
#pragma unroll
        for (int r = 0; r < 4; r++) {
          float v = acc[i][j][r];
          ps[i][r] += v * asc;
          pd[i][r] += v * adc;
          Cb[(size_t)(bm + wr + i * 16 + fk * 4 + r) * ldc + col] = f2bf_rne(v);
        }
      }
    }
#pragma unroll
    for (int o = 1; o < 16; o <<= 1) {
#pragma unroll
      for (int i = 0; i < 2; i++)
#pragma unroll
        for (int r = 0; r < 4; r++) {
          ps[i][r] += __shfl_xor(ps[i][r], o);
          pd[i][r] += __shfl_xor(pd[i][r], o);
        }
    }
    if (fr == 0) {
#pragma unroll
      for (int i = 0; i < 2; i++) {
#pragma unroll
        for (int r = 0; r < 4; r++) {
          int t = bm + wr + i * 16 + fk * 4 + r;
          int v = (t < BB) ? idx0[t] : NU + idx1[t - BB];
          if (mapv[v] == t) {   // rep task only (dups would double-count)
            atomicAdd(&a1s[(size_t)v * 2 + head], ps[i][r]);
            atomicAdd(&a1d[(size_t)v * 2 + head], pd[i][r]);
          }
        }
      }
    }
    return;
  }
  if (MODE == 2) {
    // fused prediction head: out[row] += sum_col relu(acc+pb1[col]) * pw2[col]
    float part[2][4] = {{0.f}};
#pragma unroll
    for (int j = 0; j < 2; j++) {
      int col = bn + wc + j * 16 + fr;
      float bj = bias[col];
      float wv = att_s[col];
#pragma unroll
      for (int i = 0; i < 2; i++) {
#pragma unroll
        for (int r = 0; r < 4; r++) {
          float v = fmaxf(acc[i][j][r] + bj, 0.f);
          part[i][r] += v * wv;
        }
      }
    }
#pragma unroll
    for (int o = 1; o < 16; o <<= 1) {
#pragma unroll
      for (int i = 0; i < 2; i++)
#pragma unroll
        for (int r = 0; r < 4; r++) part[i][r] += __shfl_xor(part[i][r], o);
    }
    if (fr == 0) {
#pragma unroll
      for (int i = 0; i < 2; i++) {
#pragma unroll
        for (int r = 0; r < 4; r++) {
          int row = bm + wr + i * 16 + fk * 4 + r;
          float add = part[i][r];
          if (bn == 0 && wc == 0) add += att_d[0];   // pb2 exactly once per row
          atomicAdd(&a1s[row], add);
        }
      }
    }
    return;
  }
#pragma unroll
  for (int j = 0; j < 2; j++) {
    int col = bn + wc + j * 16 + fr;
    float bj = bias ? bias[col] : 0.f;
#pragma unroll
    for (int i = 0; i < 2; i++) {
#pragma unroll
      for (int r = 0; r < 4; r++) {
        int row = bm + wr + i * 16 + fk * 4 + r;
        float v = acc[i][j][r] + bj;
        if (act == 1) v = fmaxf(v, 0.f);
        C[(size_t)row * ldc + col] = v;
      }
    }
  }
}

template <int GATHER, int MODE>
__global__ __launch_bounds__(256) void gemm_mfma(
    const float* __restrict__ A,
    const unsigned short* __restrict__ Bh, const unsigned short* __restrict__ Bl,
    const float* __restrict__ bias, float* __restrict__ C,
    unsigned short* __restrict__ Cb, int ldc,
    int M, int N, int K, int act,
    const int* __restrict__ idx0, const int* __restrict__ idx1,
    const int* __restrict__ mapv,
    const float* __restrict__ gA0, const float* __restrict__ gA1,
    const float* __restrict__ att_s, const float* __restrict__ att_d,
    float* __restrict__ a1s, float* __restrict__ a1d) {
  gemm_core<GATHER, MODE>(blockIdx.x * 64, blockIdx.y * 64,
                          A, Bh, Bl, bias, C, Cb, ldc, M, N, K, act,
                          idx0, idx1, mapv, gA0, gA1, att_s, att_d, a1s, a1d);
}

// cemb GEMM (gather-A) + CSR fill + needed-mark in ONE launch (independent work).
#define GEMMB 256  // (BB/64) * (DD/64)
__global__ __launch_bounds__(256) void cembfill_kernel(
    const unsigned short* __restrict__ wch, const unsigned short* __restrict__ wcl,
    const float* __restrict__ bc, float* __restrict__ XaC,
    const int* __restrict__ widx, const float* __restrict__ content,
    const int* __restrict__ ei, int* __restrict__ fill, int* __restrict__ col,
    const int* __restrict__ mapv, unsigned char* __restrict__ needed) {
  int bid = blockIdx.x;
  if (bid < GEMMB) {
    gemm_core<2, 0>((bid >> 1) * 64, (bid & 1) * 64,
                    nullptr, wch, wcl, bc, XaC, nullptr, 256,
                    BB, DD, 512, 0, widx, nullptr, nullptr, content, nullptr,
                    nullptr, nullptr, nullptr, nullptr);
    return;
  }
  int e = (bid - GEMMB) * 256 + threadIdx.x;
  if (e >= ET) return;
  int src, dst;
  if (e < EE) { src = ei[e]; dst = ei[EE + e]; }
  else { src = e - EE; dst = src; }
  int pos = atomicAdd(&fill[dst], 1);
  col[pos] = src;
  if (mapv[dst] >= 0) needed[src] = 1;
}

// ---------------- mega-setup: deg+winner atomics | weight split | Xa-emb+map ------
#define EB 2227    // ceil(ET/256)
#define SPLB 832   // (65536+65536+32768+49152)/256
#define XAB 4096   // NTASK/4
__global__ __launch_bounds__(256) void setup_kernel(
    const int* __restrict__ ei, const int* __restrict__ uid, const int* __restrict__ iid,
    int* __restrict__ deg, int* __restrict__ winner,
    const float* __restrict__ wc, unsigned short* wch, unsigned short* wcl,
    const float* __restrict__ w1, unsigned short* w1h, unsigned short* w1l,
    const float* __restrict__ w2, unsigned short* w2h, unsigned short* w2l,
    const float* __restrict__ pw1, unsigned short* p1h, unsigned short* p1l,
    const float* __restrict__ uemb, const float* __restrict__ iemb,
    float* __restrict__ Xa, int* __restrict__ map) {
  int bid = blockIdx.x, tid = threadIdx.x;
  if (bid < EB) {
    int e = bid * 256 + tid;
    if (e < BB) atomicMax(&winner[iid[e]], e);
    if (e >= ET) return;
    int dst = (e < EE) ? ei[EE + e] : (e - EE);
    atomicAdd(&deg[dst], 1);
    return;
  }
  if (bid < EB + SPLB) {
    int i = (bid - EB) * 256 + tid;
    const float* w; unsigned short* h; unsigned short* l; int idx;
    if (i < 65536) { w = wc; h = wch; l = wcl; idx = i; }
    else if (i < 131072) { w = w1; h = w1h; l = w1l; idx = i - 65536; }
    else if (i < 163840) { w = w2; h = w2h; l = w2l; idx = i - 131072; }
    else { w = pw1; h = p1h; l = p1l; idx = i - 163840; }
    float f = w[idx];
    unsigned short hh = f2bf_rne(f);
    h[idx] = hh;
    l[idx] = (unsigned short)(__builtin_bit_cast(unsigned int, f - bf2f(hh)) >> 16);
    return;
  }
  int t = (bid - EB - SPLB) * 4 + (tid >> 6);
  int lane = tid & 63;
  int c4 = lane * 4;
  if (t < BB) {
    int u = uid[t];
    float4 v = make_float4(0.f, 0.f, 0.f, 0.f);
    if (c4 < DD) v = *reinterpret_cast<const float4*>(&uemb[(size_t)u * DD + c4]);
    *reinterpret_cast<float4*>(&Xa[(size_t)t * 256 + c4]) = v;
    if (lane == 0) map[u] = t;
  } else {
    int it = iid[t - BB];
    if (c4 < DD) {
      float4 v = *reinterpret_cast<const float4*>(&iemb[(size_t)it * DD + c4]);
      *reinterpret_cast<float4*>(&Xa[(size_t)t * 256 + c4]) = v;
    }
    if (lane == 0) map[NU + it] = t;
  }
}

// rowstart + widx; last block computes the conv2 q-vectors.
__global__ void rowstart_kernel(const int* __restrict__ deg, const int* __restrict__ winner,
                                const int* __restrict__ iid,
                                int* __restrict__ rowstart, int* __restrict__ fill,
                                int* __restrict__ counter, int* __restrict__ widx,
                                const float* __restrict__ w2,
                                const float* __restrict__ att2s, const float* __restrict__ att2d,
                                float* __restrict__ qs, float* __restrict__ qd) {
  int blk = blockIdx.x;
  if (blk == (NN + 255) / 256) {
    int k = threadIdx.x;
    float s = 0.f, d = 0.f;
#pragma unroll 4
    for (int j = 0; j < DD; j++) {
      float w = w2[(size_t)j * 256 + k];
      s += att2s[j] * w;
      d += att2d[j] * w;
    }
    qs[k] = s;
    qd[k] = d;
    return;
  }
  int v = blk * 256 + threadIdx.x;
  if (v < BB) widx[v] = winner[iid[v]];
  if (v >= NN) return;
  int s = atomicAdd(counter, deg[v]);
  rowstart[v] = s;
  fill[v] = s;
}

// conv1 aggregation: bf16 Hb gather, needed-skip, NO-MAX softmax (shift-invariant,
// |scores|<~5 so exp is safe in f32), ballot-compacted gather, fused a2 scores.
__global__ __launch_bounds__(256) void conv1_agg_kernel(
    const int* __restrict__ col, const int* __restrict__ rowstart,
    const int* __restrict__ deg, const unsigned short* __restrict__ Hb,
    const int* __restrict__ map, const unsigned char* __restrict__ needed,
    const float* __restrict__ a1s, const float* __restrict__ a1d,
    const float* __restrict__ bias,
    const float* __restrict__ qs, const float* __restrict__ qd,
    unsigned short* __restrict__ x1b, float* __restrict__ a2s, float* __restrict__ a2d) {
  int v = blockIdx.x * 4 + (threadIdx.x >> 6);
  int lane = threadIdx.x & 63;
  if (!needed[v]) return;
  int head = lane >> 5;
  int d = deg[v], s0 = rowstart[v];
  float2 adv = *reinterpret_cast<const float2*>(&a1d[(size_t)v * 2]);
  float4 acc = make_float4(0.f, 0.f, 0.f, 0.f);
  float den0 = 0.f, den1 = 0.f;
  const unsigned short* hb = Hb + (lane << 2);
  for (int c0 = 0; c0 < d; c0 += 64) {
    int i = c0 + lane;
    bool act = i < d;
    int ci = act ? col[s0 + i] : 0;
    float2 asv = make_float2(0.f, 0.f);
    int ri = -1;
    if (act) {
      asv = *reinterpret_cast<const float2*>(&a1s[(size_t)ci * 2]);
      ri = map[ci];
    }
    float ex0 = act ? __expf(lrelu(asv.x + adv.x)) : 0.f;
    float ex1 = act ? __expf(lrelu(asv.y + adv.y)) : 0.f;
    den0 += ex0;
    den1 += ex1;
    // compacted gather: only lanes whose edge source is a batch node (~20%)
    unsigned long long msk = __ballot(act && ri >= 0);
    while (msk) {
      int s = __ffsll((unsigned long long)msk) - 1;
      msk &= msk - 1;
      int r = __shfl(ri, s);
      float e0 = __shfl(ex0, s), e1 = __shfl(ex1, s);
      float ex = head ? e1 : e0;
      ushort4 hv = *reinterpret_cast<const ushort4*>(&hb[(size_t)r << 8]);
      acc.x += ex * bf2f(hv.x); acc.y += ex * bf2f(hv.y);
      acc.z += ex * bf2f(hv.z); acc.w += ex * bf2f(hv.w);
    }
  }
#pragma unroll
  for (int o = 1; o < 64; o <<= 1) {
    den0 += __shfl_xor(den0, o);
    den1 += __shfl_xor(den1, o);
  }
  float inv = 1.f / (head ? den1 : den0);
  float4 b4 = *reinterpret_cast<const float4*>(&bias[lane << 2]);
  float4 o;
  o.x = fmaf(acc.x, inv, b4.x);
  o.y = fmaf(acc.y, inv, b4.y);
  o.z = fmaf(acc.z, inv, b4.z);
  o.w = fmaf(acc.w, inv, b4.w);
  o.x = o.x > 0.f ? o.x : __expf(o.x) - 1.f;
  o.y = o.y > 0.f ? o.y : __expf(o.y) - 1.f;
  o.z = o.z > 0.f ? o.z : __expf(o.z) - 1.f;
  o.w = o.w > 0.f ? o.w : __expf(o.w) - 1.f;
  ushort4 st;
  st.x = f2bf_rne(o.x); st.y = f2bf_rne(o.y);
  st.z = f2bf_rne(o.z); st.w = f2bf_rne(o.w);
  *reinterpret_cast<ushort4*>(&x1b[((size_t)v << 8) + (lane << 2)]) = st;
  float4 sv = *reinterpret_cast<const float4*>(&qs[lane << 2]);
  float4 dv = *reinterpret_cast<const float4*>(&qd[lane << 2]);
  float ps = o.x * sv.x + o.y * sv.y + o.z * sv.z + o.w * sv.w;
  float pd = o.x * dv.x + o.y * dv.y + o.z * dv.z + o.w * dv.w;
#pragma unroll
  for (int of = 1; of < 64; of <<= 1) { ps += __shfl_xor(ps, of); pd += __shfl_xor(pd, of); }
  if (lane == 0) { a2s[v] = ps; a2d[v] = pd; }
}

// conv2 aggregation, rep tasks only; NO-MAX softmax; bf16 x1 gather.
__global__ __launch_bounds__(256) void conv2_agg_kernel(
    const int* __restrict__ uid, const int* __restrict__ iid,
    const int* __restrict__ col, const int* __restrict__ rowstart,
    const int* __restrict__ deg, const int* __restrict__ map,
    const unsigned short* __restrict__ x1b,
    const float* __restrict__ a2s, const float* __restrict__ a2d,
    float* __restrict__ agg) {
  int t = blockIdx.x * 4 + (threadIdx.x >> 6);
  int lane = threadIdx.x & 63;
  int v = (t < BB) ? uid[t] : NU + iid[t - BB];
  if (map[v] != t) return;  // duplicates gather the rep's row via map in the ph GEMM
  int d = deg[v], s0 = rowstart[v];
  float ad = a2d[v];
  float4 acc = make_float4(0.f, 0.f, 0.f, 0.f);
  float den = 0.f;
  const unsigned short* xb = x1b + (lane << 2);
  for (int c0 = 0; c0 < d; c0 += 64) {
    int i = c0 + lane;
    bool act = i < d;
    int ci = act ? col[s0 + i] : 0;
    float as = act ? a2s[ci] : 0.f;
    float ex = act ? __expf(lrelu(as + ad)) : 0.f;
    den += ex;
    int n = min(64, d - c0);
#pragma unroll 2
    for (int i2 = 0; i2 < n; i2++) {
      int r = __shfl(ci, i2);
      float e = __shfl(ex, i2);
      ushort4 hv = *reinterpret_cast<const ushort4*>(&xb[(size_t)r << 8]);
      acc.x += e * bf2f(hv.x); acc.y += e * bf2f(hv.y);
      acc.z += e * bf2f(hv.z); acc.w += e * bf2f(hv.w);
    }
  }
#pragma unroll
  for (int o = 1; o < 64; o <<= 1) den += __shfl_xor(den, o);
  float inv = 1.f / den;
  float4 o = make_float4(acc.x * inv, acc.y * inv, acc.z * inv, acc.w * inv);
  *reinterpret_cast<float4*>(&agg[((size_t)t << 8) + (lane << 2)]) = o;
}

// ---------------- launcher ----------------
extern "C" void kernel_launch(void* const* d_in, const int* in_sizes, int n_in,
                              void* d_out, int out_size, void* d_ws, size_t ws_size,
                              hipStream_t stream) {
  const int* uid = (const int*)d_in[0];
  const int* iid = (const int*)d_in[1];
  const float* content = (const float*)d_in[2];
  const int* ei = (const int*)d_in[3];
  const float* uemb = (const float*)d_in[4];
  const float* iemb = (const float*)d_in[5];
  const float* wc = (const float*)d_in[6];
  const float* bc = (const float*)d_in[7];
  const float* w1 = (const float*)d_in[8];
  const float* att1s = (const float*)d_in[9];
  const float* att1d = (const float*)d_in[10];
  const float* b1 = (const float*)d_in[11];
  const float* w2 = (const float*)d_in[12];
  const float* att2s = (const float*)d_in[13];
  const float* att2d = (const float*)d_in[14];
  const float* b2c = (const float*)d_in[15];
  const float* pw1 = (const float*)d_in[16];
  const float* pb1 = (const float*)d_in[17];
  const float* pw2 = (const float*)d_in[18];
  const float* pb2 = (const float*)d_in[19];
  float* out = (float*)d_out;
  char* ws = (char*)d_ws;

  size_t off = 0;
  auto alloc = [&](size_t bytes) {
    size_t o = off;
    off += (bytes + 255) & ~(size_t)255;
    return o;
  };
  size_t o_winner  = alloc(NI * 4);
  size_t o_map     = alloc(NN * 4);
  size_t o_a1s     = alloc((size_t)NN * 2 * 4);
  size_t o_a1d     = alloc((size_t)NN * 2 * 4);
  size_t o_deg     = alloc(NN * 4);
  size_t o_rs      = alloc(NN * 4);
  size_t o_fill    = alloc(NN * 4);
  size_t o_cnt     = alloc(4);
  size_t o_needed  = alloc(NN);
  size_t o_col     = alloc((size_t)ET * 4);
  size_t o_a2s     = alloc(NN * 4);
  size_t o_a2d     = alloc(NN * 4);
  size_t o_qs      = alloc(256 * 4);
  size_t o_qd      = alloc(256 * 4);
  size_t o_widx    = alloc(BB * 4);
  size_t o_wch = alloc(65536 * 2),  o_wcl = alloc(65536 * 2);
  size_t o_w1h = alloc(65536 * 2),  o_w1l = alloc(65536 * 2);
  size_t o_w2h = alloc(32768 * 2),  o_w2l = alloc(32768 * 2);
  size_t o_p1h = alloc(49152 * 2),  o_p1l = alloc(49152 * 2);
  // region R1 (25.2MB): Xa f32 (16.78M) | Hb bf16 (8.39M)
  size_t o_r1    = alloc(16777216 + 8388608);
  size_t o_xa    = o_r1;
  size_t o_hb    = o_r1 + 16777216;
  size_t o_agg   = o_r1;
  size_t o_out2c = o_r1 + 16777216;
  size_t o_x1b   = alloc((size_t)NN * 256 * 2);
  (void)ws_size; (void)in_sizes; (void)n_in; (void)out_size;

  int*   winner = (int*)(ws + o_winner);
  int*   map    = (int*)(ws + o_map);
  float* a1s    = (float*)(ws + o_a1s);
  float* a1d    = (float*)(ws + o_a1d);
  int*   deg    = (int*)(ws + o_deg);
  int*   rs     = (int*)(ws + o_rs);
  int*   fill   = (int*)(ws + o_fill);
  int*   cnt    = (int*)(ws + o_cnt);
  unsigned char* needed = (unsigned char*)(ws + o_needed);
  int*   col    = (int*)(ws + o_col);
  float* a2s    = (float*)(ws + o_a2s);
  float* a2d    = (float*)(ws + o_a2d);
  float* qs     = (float*)(ws + o_qs);
  float* qd     = (float*)(ws + o_qd);
  int*   widx   = (int*)(ws + o_widx);
  unsigned short* wch = (unsigned short*)(ws + o_wch);
  unsigned short* wcl = (unsigned short*)(ws + o_wcl);
  unsigned short* w1h = (unsigned short*)(ws + o_w1h);
  unsigned short* w1l = (unsigned short*)(ws + o_w1l);
  unsigned short* w2h = (unsigned short*)(ws + o_w2h);
  unsigned short* w2l = (unsigned short*)(ws + o_w2l);
  unsigned short* p1h = (unsigned short*)(ws + o_p1h);
  unsigned short* p1l = (unsigned short*)(ws + o_p1l);
  float* Xa     = (float*)(ws + o_xa);
  unsigned short* Hb = (unsigned short*)(ws + o_hb);
  float* agg    = (float*)(ws + o_agg);
  float* out2c  = (float*)(ws + o_out2c);
  unsigned short* x1b = (unsigned short*)(ws + o_x1b);

  // one fast grid-strided clear replaces 4 slow runtime fills
  {
    unsigned int offA = (unsigned int)(o_winner >> 2);
    unsigned int nA   = (unsigned int)((o_map - o_winner) / 4 + NN);
    unsigned int offB = (unsigned int)(o_a1s >> 2);
    unsigned int nB   = (unsigned int)((o_a1d - o_a1s) / 4 + (size_t)NN * 2);
    unsigned int offC = (unsigned int)(o_deg >> 2);
    unsigned int nC   = (unsigned int)((o_needed - o_deg) / 4 + NN / 4);
    clear_kernel<<<1024, 256, 0, stream>>>((unsigned int*)ws, offA, nA, offB, nB,
                                           offC, nC, out);
  }

  setup_kernel<<<EB + SPLB + XAB, 256, 0, stream>>>(
      ei, uid, iid, deg, winner,
      wc, wch, wcl, w1, w1h, w1l, w2, w2h, w2l, pw1, p1h, p1l,
      uemb, iemb, Xa, map);
  rowstart_kernel<<<(NN + 255) / 256 + 1, 256, 0, stream>>>(
      deg, winner, iid, rs, fill, cnt, widx, w2, att2s, att2d, qs, qd);
  cembfill_kernel<<<GEMMB + EB, 256, 0, stream>>>(
      wch, wcl, bc, Xa + (size_t)BB * 256 + 128, widx, content,
      ei, fill, col, map, needed);
  // Hb = bf16(Xa @ W1^T), with fused a1 score atomics
  {
    dim3 g(NTASK / 64, 256 / 64);
    gemm_mfma<0, 1><<<g, 256, 0, stream>>>(
        Xa, w1h, w1l, nullptr, nullptr, Hb, 256,
        NTASK, 256, 256, 0, uid, iid, map, nullptr, nullptr,
        att1s, att1d, a1s, a1d);
  }
  conv1_agg_kernel<<<NN / 4, 256, 0, stream>>>(col, rs, deg, Hb, map, needed,
                                               a1s, a1d, b1, qs, qd, x1b, a2s, a2d);
  conv2_agg_kernel<<<NTASK / 4, 256, 0, stream>>>(uid, iid, col, rs, deg, map,
                                                  x1b, a2s, a2d, agg);
  // out2c = agg @ W2^T + b2c
  {
    dim3 g(NTASK / 64, DD / 64);
    gemm_mfma<0, 0><<<g, 256, 0, stream>>>(
        agg, w2h, w2l, b2c, out2c, nullptr, 128,
        NTASK, DD, 256, 0, nullptr, nullptr, nullptr, nullptr, nullptr,
        nullptr, nullptr, nullptr, nullptr);
  }
  // fused: out[b] = relu([uemb|out2c_i|out2c_u] @ pw1^T + pb1) . pw2 + pb2
  {
    dim3 g(BB / 64, DD / 64);
    gemm_mfma<1, 2><<<g, 256, 0, stream>>>(
        nullptr, p1h, p1l, pb1, nullptr, nullptr, 128,
        BB, DD, 384, 0, uid, iid, map, uemb, out2c,
        pw2, pb2, out, nullptr);
  }
}

// Round 14
// 196.083 us; speedup vs baseline: 1.2158x; 1.0013x over previous
//
#include <hip/hip_runtime.h>
#include <hip/hip_bf16.h>

#define NU 50000
#define NI 20000
#define NN 70000
#define DD 128
#define BB 8192
#define EE 500000
#define ET 570000   // EE + NN self loops
#define NTASK 16384 // 2*BB

__device__ __forceinline__ float lrelu(float x) { return x > 0.f ? x : 0.2f * x; }

typedef __attribute__((ext_vector_type(8))) short bf16x8;   // 8 bf16 = 4 VGPRs
typedef __attribute__((ext_vector_type(8))) unsigned short u16x8;
typedef __attribute__((ext_vector_type(4))) float f32x4;

__device__ __forceinline__ unsigned short f2bf_rne(float f) {
  unsigned int u = __builtin_bit_cast(unsigned int, f);
  u += 0x7FFFu + ((u >> 16) & 1u);
  return (unsigned short)(u >> 16);
}
__device__ __forceinline__ float bf2f(unsigned short h) {
  unsigned int u = ((unsigned int)h) << 16;
  return __builtin_bit_cast(float, u);
}

// ---------------- fast workspace clear (replaces slow hipMemsetAsync fills) -------
__global__ __launch_bounds__(256) void clear_kernel(
    unsigned int* __restrict__ wsw,
    unsigned int offA, unsigned int nA,
    unsigned int offB, unsigned int nB,
    unsigned int offC, unsigned int nC,
    float* __restrict__ out) {
  unsigned int idx = blockIdx.x * 256 + threadIdx.x;
  unsigned int stride = gridDim.x * 256;
  for (unsigned int i = idx; i < nA; i += stride) wsw[offA + i] = 0xFFFFFFFFu;
  for (unsigned int i = idx; i < nB; i += stride) wsw[offB + i] = 0u;
  for (unsigned int i = idx; i < nC; i += stride) wsw[offC + i] = 0u;
  for (unsigned int i = idx; i < BB; i += stride) out[i] = 0.f;
}

// ---------------- MFMA GEMM core: C[M,N] = A * Bt^T (+bias)(+relu) ----------------
// GATHER=0: A linear. GATHER=1: ph-style 3-section row gather. GATHER=2: row gather.
// MODE=0: f32 C. MODE=1: bf16 Cb + fused a1 attention-score atomics.
// MODE=2: fused final layer: relu(acc+bias) dot att_s(=pw2), + att_d[0](=pb2),
//         atomicAdd into a1s(=out). No C write.
template <int GATHER, int MODE>
__device__ __forceinline__ void gemm_core(
    int bm, int bn,
    const float* __restrict__ A,
    const unsigned short* __restrict__ Bh, const unsigned short* __restrict__ Bl,
    const float* __restrict__ bias, float* __restrict__ C,
    unsigned short* __restrict__ Cb, int ldc,
    int M, int N, int K, int act,
    const int* __restrict__ idx0, const int* __restrict__ idx1,
    const int* __restrict__ mapv,
    const float* __restrict__ gA0, const float* __restrict__ gA1,
    const float* __restrict__ att_s, const float* __restrict__ att_d,
    float* __restrict__ a1s, float* __restrict__ a1d) {
  __shared__ __align__(16) unsigned short sAh[8][64][8];
  __shared__ __align__(16) unsigned short sAl[8][64][8];
  __shared__ __align__(16) unsigned short sBh[8][64][8];
  __shared__ __align__(16) unsigned short sBl[8][64][8];
  int tid = threadIdx.x;
  int lane = tid & 63, w = tid >> 6;
  int wr = (w >> 1) * 32, wc = (w & 1) * 32;
  int fr = lane & 15, fk = lane >> 4;
  f32x4 acc[2][2] = {};

  for (int k0 = 0; k0 < K; k0 += 64) {
    __syncthreads();
#pragma unroll
    for (int t = 0; t < 2; t++) {
      int f = tid + t * 256;
      int row = f >> 3, kb = f & 7;
      int kg = k0 + kb * 8;
      const float* ap;
      if (GATHER == 1) {
        int sec = kg >> 7;           // 64-tiles never straddle 128-col sections
        int kc = kg & 127;
        int r = bm + row;
        if (sec == 0)      ap = &gA0[(size_t)idx0[r] * 128 + kc];
        else if (sec == 1) ap = &gA1[(size_t)mapv[NU + idx1[r]] * 128 + kc];
        else               ap = &gA1[(size_t)mapv[idx0[r]] * 128 + kc];
      } else if (GATHER == 2) {
        ap = &gA0[(size_t)idx0[bm + row] * K + kg];
      } else {
        ap = &A[(size_t)(bm + row) * K + kg];
      }
      float4 v0 = *reinterpret_cast<const float4*>(ap);
      float4 v1 = *reinterpret_cast<const float4*>(ap + 4);
      float vv[8] = {v0.x, v0.y, v0.z, v0.w, v1.x, v1.y, v1.z, v1.w};
      u16x8 hv, lv;
#pragma unroll
      for (int j = 0; j < 8; j++) {
        unsigned short hh = f2bf_rne(vv[j]);
        hv[j] = hh;
        lv[j] = (unsigned short)(__builtin_bit_cast(unsigned int, vv[j] - bf2f(hh)) >> 16);
      }
      *reinterpret_cast<u16x8*>(&sAh[kb][row][0]) = hv;
      *reinterpret_cast<u16x8*>(&sAl[kb][row][0]) = lv;
    }
#pragma unroll
    for (int t = 0; t < 2; t++) {
      int f = tid + t * 256;
      int row = f >> 3, kb = f & 7;
      int kg = k0 + kb * 8;
      *reinterpret_cast<u16x8*>(&sBh[kb][row][0]) =
          *reinterpret_cast<const u16x8*>(&Bh[(size_t)(bn + row) * K + kg]);
      *reinterpret_cast<u16x8*>(&sBl[kb][row][0]) =
          *reinterpret_cast<const u16x8*>(&Bl[(size_t)(bn + row) * K + kg]);
    }
    __syncthreads();
#pragma unroll
    for (int s = 0; s < 2; s++) {
      int kb = s * 4 + fk;
      bf16x8 ah0 = *reinterpret_cast<const bf16x8*>(&sAh[kb][wr + fr][0]);
      bf16x8 ah1 = *reinterpret_cast<const bf16x8*>(&sAh[kb][wr + 16 + fr][0]);
      bf16x8 al0 = *reinterpret_cast<const bf16x8*>(&sAl[kb][wr + fr][0]);
      bf16x8 al1 = *reinterpret_cast<const bf16x8*>(&sAl[kb][wr + 16 + fr][0]);
      bf16x8 bh0 = *reinterpret_cast<const bf16x8*>(&sBh[kb][wc + fr][0]);
      bf16x8 bh1 = *reinterpret_cast<const bf16x8*>(&sBh[kb][wc + 16 + fr][0]);
      bf16x8 bl0 = *reinterpret_cast<const bf16x8*>(&sBl[kb][wc + fr][0]);
      bf16x8 bl1 = *reinterpret_cast<const bf16x8*>(&sBl[kb][wc + 16 + fr][0]);
      acc[0][0] = __builtin_amdgcn_mfma_f32_16x16x32_bf16(al0, bh0, acc[0][0], 0, 0, 0);
      acc[0][0] = __builtin_amdgcn_mfma_f32_16x16x32_bf16(ah0, bl0, acc[0][0], 0, 0, 0);
      acc[0][0] = __builtin_amdgcn_mfma_f32_16x16x32_bf16(ah0, bh0, acc[0][0], 0, 0, 0);
      acc[0][1] = __builtin_amdgcn_mfma_f32_16x16x32_bf16(al0, bh1, acc[0][1], 0, 0, 0);
      acc[0][1] = __builtin_amdgcn_mfma_f32_16x16x32_bf16(ah0, bl1, acc[0][1], 0, 0, 0);
      acc[0][1] = __builtin_amdgcn_mfma_f32_16x16x32_bf16(ah0, bh1, acc[0][1], 0, 0, 0);
      acc[1][0] = __builtin_amdgcn_mfma_f32_16x16x32_bf16(al1, bh0, acc[1][0], 0, 0, 0);
      acc[1][0] = __builtin_amdgcn_mfma_f32_16x16x32_bf16(ah1, bl0, acc[1][0], 0, 0, 0);
      acc[1][0] = __builtin_amdgcn_mfma_f32_16x16x32_bf16(ah1, bh0, acc[1][0], 0, 0, 0);
      acc[1][1] = __builtin_amdgcn_mfma_f32_16x16x32_bf16(al1, bh1, acc[1][1], 0, 0, 0);
      acc[1][1] = __builtin_amdgcn_mfma_f32_16x16x32_bf16(ah1, bl1, acc[1][1], 0, 0, 0);
      acc[1][1] = __builtin_amdgcn_mfma_f32_16x16x32_bf16(ah1, bh1, acc[1][1], 0, 0, 0);
    }
  }
  if (MODE == 1) {
    int head = bn >> 7;
    float ps[2][4] = {{0.f}}, pd[2][4] = {{0.f}};
#pragma unroll
    for (int j = 0; j < 2; j++) {
      int col = bn + wc + j * 16 + fr;
      float asc = att_s[col], adc = att_d[col];
#pragma unroll
      for (int i = 0; i < 2; i++) {
#pragma unroll
        for (int r = 0; r < 4; r++) {
          float v = acc[i][j][r];
          ps[i][r] += v * asc;
          pd[i][r] += v * adc;
          Cb[(size_t)(bm + wr + i * 16 + fk * 4 + r) * ldc + col] = f2bf_rne(v);
        }
      }
    }
#pragma unroll
    for (int o = 1; o < 16; o <<= 1) {
#pragma unroll
      for (int i = 0; i < 2; i++)
#pragma unroll
        for (int r = 0; r < 4; r++) {
          ps[i][r] += __shfl_xor(ps[i][r], o);
          pd[i][r] += __shfl_xor(pd[i][r], o);
        }
    }
    if (fr == 0) {
#pragma unroll
      for (int i = 0; i < 2; i++) {
#pragma unroll
        for (int r = 0; r < 4; r++) {
          int t = bm + wr + i * 16 + fk * 4 + r;
          int v = (t < BB) ? idx0[t] : NU + idx1[t - BB];
          if (mapv[v] == t) {   // rep task only (dups would double-count)
            atomicAdd(&a1s[(size_t)v * 2 + head], ps[i][r]);
            atomicAdd(&a1d[(size_t)v * 2 + head], pd[i][r]);
          }
        }
      }
    }
    return;
  }
  if (MODE == 2) {
    // fused prediction head: out[row] += sum_col relu(acc+pb1[col]) * pw2[col]
    float part[2][4] = {{0.f}};
#pragma unroll
    for (int j = 0; j < 2; j++) {
      int col = bn + wc + j * 16 + fr;
      float bj = bias[col];
      float wv = att_s[col];
#pragma unroll
      for (int i = 0; i < 2; i++) {
#pragma unroll
        for (int r = 0; r < 4; r++) {
          float v = fmaxf(acc[i][j][r] + bj, 0.f);
          part[i][r] += v * wv;
        }
      }
    }
#pragma unroll
    for (int o = 1; o < 16; o <<= 1) {
#pragma unroll
      for (int i = 0; i < 2; i++)
#pragma unroll
        for (int r = 0; r < 4; r++) part[i][r] += __shfl_xor(part[i][r], o);
    }
    if (fr == 0) {
#pragma unroll
      for (int i = 0; i < 2; i++) {
#pragma unroll
        for (int r = 0; r < 4; r++) {
          int row = bm + wr + i * 16 + fk * 4 + r;
          float add = part[i][r];
          if (bn == 0 && wc == 0) add += att_d[0];   // pb2 exactly once per row
          atomicAdd(&a1s[row], add);
        }
      }
    }
    return;
  }
#pragma unroll
  for (int j = 0; j < 2; j++) {
    int col = bn + wc + j * 16 + fr;
    float bj = bias ? bias[col] : 0.f;
#pragma unroll
    for (int i = 0; i < 2; i++) {
#pragma unroll
      for (int r = 0; r < 4; r++) {
        int row = bm + wr + i * 16 + fk * 4 + r;
        float v = acc[i][j][r] + bj;
        if (act == 1) v = fmaxf(v, 0.f);
        C[(size_t)row * ldc + col] = v;
      }
    }
  }
}

template <int GATHER, int MODE>
__global__ __launch_bounds__(256) void gemm_mfma(
    const float* __restrict__ A,
    const unsigned short* __restrict__ Bh, const unsigned short* __restrict__ Bl,
    const float* __restrict__ bias, float* __restrict__ C,
    unsigned short* __restrict__ Cb, int ldc,
    int M, int N, int K, int act,
    const int* __restrict__ idx0, const int* __restrict__ idx1,
    const int* __restrict__ mapv,
    const float* __restrict__ gA0, const float* __restrict__ gA1,
    const float* __restrict__ att_s, const float* __restrict__ att_d,
    float* __restrict__ a1s, float* __restrict__ a1d) {
  gemm_core<GATHER, MODE>(blockIdx.x * 64, blockIdx.y * 64,
                          A, Bh, Bl, bias, C, Cb, ldc, M, N, K, act,
                          idx0, idx1, mapv, gA0, gA1, att_s, att_d, a1s, a1d);
}

// cemb GEMM (gather-A) + CSR fill + needed-mark in ONE launch (independent work).
#define GEMMB 256  // (BB/64) * (DD/64)
__global__ __launch_bounds__(256) void cembfill_kernel(
    const unsigned short* __restrict__ wch, const unsigned short* __restrict__ wcl,
    const float* __restrict__ bc, float* __restrict__ XaC,
    const int* __restrict__ widx, const float* __restrict__ content,
    const int* __restrict__ ei, int* __restrict__ fill, int* __restrict__ col,
    const int* __restrict__ mapv, unsigned char* __restrict__ needed) {
  int bid = blockIdx.x;
  if (bid < GEMMB) {
    gemm_core<2, 0>((bid >> 1) * 64, (bid & 1) * 64,
                    nullptr, wch, wcl, bc, XaC, nullptr, 256,
                    BB, DD, 512, 0, widx, nullptr, nullptr, content, nullptr,
                    nullptr, nullptr, nullptr, nullptr);
    return;
  }
  int e = (bid - GEMMB) * 256 + threadIdx.x;
  if (e >= ET) return;
  int src, dst;
  if (e < EE) { src = ei[e]; dst = ei[EE + e]; }
  else { src = e - EE; dst = src; }
  int pos = atomicAdd(&fill[dst], 1);
  col[pos] = src;
  if (mapv[dst] >= 0) needed[src] = 1;
}

// ---------------- mega-setup: deg+winner atomics | weight split | Xa-emb+map ------
#define EB 2227    // ceil(ET/256)
#define SPLB 832   // (65536+65536+32768+49152)/256
#define XAB 4096   // NTASK/4
__global__ __launch_bounds__(256) void setup_kernel(
    const int* __restrict__ ei, const int* __restrict__ uid, const int* __restrict__ iid,
    int* __restrict__ deg, int* __restrict__ winner,
    const float* __restrict__ wc, unsigned short* wch, unsigned short* wcl,
    const float* __restrict__ w1, unsigned short* w1h, unsigned short* w1l,
    const float* __restrict__ w2, unsigned short* w2h, unsigned short* w2l,
    const float* __restrict__ pw1, unsigned short* p1h, unsigned short* p1l,
    const float* __restrict__ uemb, const float* __restrict__ iemb,
    float* __restrict__ Xa, int* __restrict__ map) {
  int bid = blockIdx.x, tid = threadIdx.x;
  if (bid < EB) {
    int e = bid * 256 + tid;
    if (e < BB) atomicMax(&winner[iid[e]], e);
    if (e >= ET) return;
    int dst = (e < EE) ? ei[EE + e] : (e - EE);
    atomicAdd(&deg[dst], 1);
    return;
  }
  if (bid < EB + SPLB) {
    int i = (bid - EB) * 256 + tid;
    const float* w; unsigned short* h; unsigned short* l; int idx;
    if (i < 65536) { w = wc; h = wch; l = wcl; idx = i; }
    else if (i < 131072) { w = w1; h = w1h; l = w1l; idx = i - 65536; }
    else if (i < 163840) { w = w2; h = w2h; l = w2l; idx = i - 131072; }
    else { w = pw1; h = p1h; l = p1l; idx = i - 163840; }
    float f = w[idx];
    unsigned short hh = f2bf_rne(f);
    h[idx] = hh;
    l[idx] = (unsigned short)(__builtin_bit_cast(unsigned int, f - bf2f(hh)) >> 16);
    return;
  }
  int t = (bid - EB - SPLB) * 4 + (tid >> 6);
  int lane = tid & 63;
  int c4 = lane * 4;
  if (t < BB) {
    int u = uid[t];
    float4 v = make_float4(0.f, 0.f, 0.f, 0.f);
    if (c4 < DD) v = *reinterpret_cast<const float4*>(&uemb[(size_t)u * DD + c4]);
    *reinterpret_cast<float4*>(&Xa[(size_t)t * 256 + c4]) = v;
    if (lane == 0) map[u] = t;
  } else {
    int it = iid[t - BB];
    if (c4 < DD) {
      float4 v = *reinterpret_cast<const float4*>(&iemb[(size_t)it * DD + c4]);
      *reinterpret_cast<float4*>(&Xa[(size_t)t * 256 + c4]) = v;
    }
    if (lane == 0) map[NU + it] = t;
  }
}

// rowstart + widx via wave-level prefix scan: ONE atomic per wave (not per node).
// Last block computes the conv2 q-vectors.
__global__ void rowstart_kernel(const int* __restrict__ deg, const int* __restrict__ winner,
                                const int* __restrict__ iid,
                                int* __restrict__ rowstart, int* __restrict__ fill,
                                int* __restrict__ counter, int* __restrict__ widx,
                                const float* __restrict__ w2,
                                const float* __restrict__ att2s, const float* __restrict__ att2d,
                                float* __restrict__ qs, float* __restrict__ qd) {
  int blk = blockIdx.x;
  if (blk == (NN + 255) / 256) {
    int k = threadIdx.x;
    float s = 0.f, d = 0.f;
#pragma unroll 4
    for (int j = 0; j < DD; j++) {
      float w = w2[(size_t)j * 256 + k];
      s += att2s[j] * w;
      d += att2d[j] * w;
    }
    qs[k] = s;
    qd[k] = d;
    return;
  }
  int v = blk * 256 + threadIdx.x;
  if (v < BB) widx[v] = winner[iid[v]];
  int lane = threadIdx.x & 63;
  int dv = (v < NN) ? deg[v] : 0;
  // wave-inclusive prefix scan
  int x = dv;
#pragma unroll
  for (int o = 1; o < 64; o <<= 1) {
    int y = __shfl_up(x, o);
    if (lane >= o) x += y;
  }
  int tot = __shfl(x, 63);     // wave total
  int base = 0;
  if (lane == 63) base = atomicAdd(counter, tot);
  base = __shfl(base, 63);
  if (v < NN) {
    int s = base + x - dv;     // exclusive prefix + wave base
    rowstart[v] = s;
    fill[v] = s;
  }
}

// conv1 aggregation: bf16 Hb gather, needed-skip, NO-MAX softmax (shift-invariant,
// |scores|<~5 so exp is safe in f32), ballot-compacted gather, fused a2 scores.
__global__ __launch_bounds__(256) void conv1_agg_kernel(
    const int* __restrict__ col, const int* __restrict__ rowstart,
    const int* __restrict__ deg, const unsigned short* __restrict__ Hb,
    const int* __restrict__ map, const unsigned char* __restrict__ needed,
    const float* __restrict__ a1s, const float* __restrict__ a1d,
    const float* __restrict__ bias,
    const float* __restrict__ qs, const float* __restrict__ qd,
    unsigned short* __restrict__ x1b, float* __restrict__ a2s, float* __restrict__ a2d) {
  int v = blockIdx.x * 4 + (threadIdx.x >> 6);
  int lane = threadIdx.x & 63;
  if (!needed[v]) return;
  int head = lane >> 5;
  int d = deg[v], s0 = rowstart[v];
  float2 adv = *reinterpret_cast<const float2*>(&a1d[(size_t)v * 2]);
  float4 acc = make_float4(0.f, 0.f, 0.f, 0.f);
  float den0 = 0.f, den1 = 0.f;
  const unsigned short* hb = Hb + (lane << 2);
  for (int c0 = 0; c0 < d; c0 += 64) {
    int i = c0 + lane;
    bool act = i < d;
    int ci = act ? col[s0 + i] : 0;
    float2 asv = make_float2(0.f, 0.f);
    int ri = -1;
    if (act) {
      asv = *reinterpret_cast<const float2*>(&a1s[(size_t)ci * 2]);
      ri = map[ci];
    }
    float ex0 = act ? __expf(lrelu(asv.x + adv.x)) : 0.f;
    float ex1 = act ? __expf(lrelu(asv.y + adv.y)) : 0.f;
    den0 += ex0;
    den1 += ex1;
    // compacted gather: only lanes whose edge source is a batch node (~20%)
    unsigned long long msk = __ballot(act && ri >= 0);
    while (msk) {
      int s = __ffsll((unsigned long long)msk) - 1;
      msk &= msk - 1;
      int r = __shfl(ri, s);
      float e0 = __shfl(ex0, s), e1 = __shfl(ex1, s);
      float ex = head ? e1 : e0;
      ushort4 hv = *reinterpret_cast<const ushort4*>(&hb[(size_t)r << 8]);
      acc.x += ex * bf2f(hv.x); acc.y += ex * bf2f(hv.y);
      acc.z += ex * bf2f(hv.z); acc.w += ex * bf2f(hv.w);
    }
  }
#pragma unroll
  for (int o = 1; o < 64; o <<= 1) {
    den0 += __shfl_xor(den0, o);
    den1 += __shfl_xor(den1, o);
  }
  float inv = 1.f / (head ? den1 : den0);
  float4 b4 = *reinterpret_cast<const float4*>(&bias[lane << 2]);
  float4 o;
  o.x = fmaf(acc.x, inv, b4.x);
  o.y = fmaf(acc.y, inv, b4.y);
  o.z = fmaf(acc.z, inv, b4.z);
  o.w = fmaf(acc.w, inv, b4.w);
  o.x = o.x > 0.f ? o.x : __expf(o.x) - 1.f;
  o.y = o.y > 0.f ? o.y : __expf(o.y) - 1.f;
  o.z = o.z > 0.f ? o.z : __expf(o.z) - 1.f;
  o.w = o.w > 0.f ? o.w : __expf(o.w) - 1.f;
  ushort4 st;
  st.x = f2bf_rne(o.x); st.y = f2bf_rne(o.y);
  st.z = f2bf_rne(o.z); st.w = f2bf_rne(o.w);
  *reinterpret_cast<ushort4*>(&x1b[((size_t)v << 8) + (lane << 2)]) = st;
  float4 sv = *reinterpret_cast<const float4*>(&qs[lane << 2]);
  float4 dv = *reinterpret_cast<const float4*>(&qd[lane << 2]);
  float ps = o.x * sv.x + o.y * sv.y + o.z * sv.z + o.w * sv.w;
  float pd = o.x * dv.x + o.y * dv.y + o.z * dv.z + o.w * dv.w;
#pragma unroll
  for (int of = 1; of < 64; of <<= 1) { ps += __shfl_xor(ps, of); pd += __shfl_xor(pd, of); }
  if (lane == 0) { a2s[v] = ps; a2d[v] = pd; }
}

// conv2 aggregation, rep tasks only; NO-MAX softmax; bf16 x1 gather.
__global__ __launch_bounds__(256) void conv2_agg_kernel(
    const int* __restrict__ uid, const int* __restrict__ iid,
    const int* __restrict__ col, const int* __restrict__ rowstart,
    const int* __restrict__ deg, const int* __restrict__ map,
    const unsigned short* __restrict__ x1b,
    const float* __restrict__ a2s, const float* __restrict__ a2d,
    float* __restrict__ agg) {
  int t = blockIdx.x * 4 + (threadIdx.x >> 6);
  int lane = threadIdx.x & 63;
  int v = (t < BB) ? uid[t] : NU + iid[t - BB];
  if (map[v] != t) return;  // duplicates gather the rep's row via map in the ph GEMM
  int d = deg[v], s0 = rowstart[v];
  float ad = a2d[v];
  float4 acc = make_float4(0.f, 0.f, 0.f, 0.f);
  float den = 0.f;
  const unsigned short* xb = x1b + (lane << 2);
  for (int c0 = 0; c0 < d; c0 += 64) {
    int i = c0 + lane;
    bool act = i < d;
    int ci = act ? col[s0 + i] : 0;
    float as = act ? a2s[ci] : 0.f;
    float ex = act ? __expf(lrelu(as + ad)) : 0.f;
    den += ex;
    int n = min(64, d - c0);
#pragma unroll 2
    for (int i2 = 0; i2 < n; i2++) {
      int r = __shfl(ci, i2);
      float e = __shfl(ex, i2);
      ushort4 hv = *reinterpret_cast<const ushort4*>(&xb[(size_t)r << 8]);
      acc.x += e * bf2f(hv.x); acc.y += e * bf2f(hv.y);
      acc.z += e * bf2f(hv.z); acc.w += e * bf2f(hv.w);
    }
  }
#pragma unroll
  for (int o = 1; o < 64; o <<= 1) den += __shfl_xor(den, o);
  float inv = 1.f / den;
  float4 o = make_float4(acc.x * inv, acc.y * inv, acc.z * inv, acc.w * inv);
  *reinterpret_cast<float4*>(&agg[((size_t)t << 8) + (lane << 2)]) = o;
}

// ---------------- launcher ----------------
extern "C" void kernel_launch(void* const* d_in, const int* in_sizes, int n_in,
                              void* d_out, int out_size, void* d_ws, size_t ws_size,
                              hipStream_t stream) {
  const int* uid = (const int*)d_in[0];
  const int* iid = (const int*)d_in[1];
  const float* content = (const float*)d_in[2];
  const int* ei = (const int*)d_in[3];
  const float* uemb = (const float*)d_in[4];
  const float* iemb = (const float*)d_in[5];
  const float* wc = (const float*)d_in[6];
  const float* bc = (const float*)d_in[7];
  const float* w1 = (const float*)d_in[8];
  const float* att1s = (const float*)d_in[9];
  const float* att1d = (const float*)d_in[10];
  const float* b1 = (const float*)d_in[11];
  const float* w2 = (const float*)d_in[12];
  const float* att2s = (const float*)d_in[13];
  const float* att2d = (const float*)d_in[14];
  const float* b2c = (const float*)d_in[15];
  const float* pw1 = (const float*)d_in[16];
  const float* pb1 = (const float*)d_in[17];
  const float* pw2 = (const float*)d_in[18];
  const float* pb2 = (const float*)d_in[19];
  float* out = (float*)d_out;
  char* ws = (char*)d_ws;

  size_t off = 0;
  auto alloc = [&](size_t bytes) {
    size_t o = off;
    off += (bytes + 255) & ~(size_t)255;
    return o;
  };
  size_t o_winner  = alloc(NI * 4);
  size_t o_map     = alloc(NN * 4);
  size_t o_a1s     = alloc((size_t)NN * 2 * 4);
  size_t o_a1d     = alloc((size_t)NN * 2 * 4);
  size_t o_deg     = alloc(NN * 4);
  size_t o_rs      = alloc(NN * 4);
  size_t o_fill    = alloc(NN * 4);
  size_t o_cnt     = alloc(4);
  size_t o_needed  = alloc(NN);
  size_t o_col     = alloc((size_t)ET * 4);
  size_t o_a2s     = alloc(NN * 4);
  size_t o_a2d     = alloc(NN * 4);
  size_t o_qs      = alloc(256 * 4);
  size_t o_qd      = alloc(256 * 4);
  size_t o_widx    = alloc(BB * 4);
  size_t o_wch = alloc(65536 * 2),  o_wcl = alloc(65536 * 2);
  size_t o_w1h = alloc(65536 * 2),  o_w1l = alloc(65536 * 2);
  size_t o_w2h = alloc(32768 * 2),  o_w2l = alloc(32768 * 2);
  size_t o_p1h = alloc(49152 * 2),  o_p1l = alloc(49152 * 2);
  // region R1 (25.2MB): Xa f32 (16.78M) | Hb bf16 (8.39M)
  size_t o_r1    = alloc(16777216 + 8388608);
  size_t o_xa    = o_r1;
  size_t o_hb    = o_r1 + 16777216;
  size_t o_agg   = o_r1;
  size_t o_out2c = o_r1 + 16777216;
  size_t o_x1b   = alloc((size_t)NN * 256 * 2);
  (void)ws_size; (void)in_sizes; (void)n_in; (void)out_size;

  int*   winner = (int*)(ws + o_winner);
  int*   map    = (int*)(ws + o_map);
  float* a1s    = (float*)(ws + o_a1s);
  float* a1d    = (float*)(ws + o_a1d);
  int*   deg    = (int*)(ws + o_deg);
  int*   rs     = (int*)(ws + o_rs);
  int*   fill   = (int*)(ws + o_fill);
  int*   cnt    = (int*)(ws + o_cnt);
  unsigned char* needed = (unsigned char*)(ws + o_needed);
  int*   col    = (int*)(ws + o_col);
  float* a2s    = (float*)(ws + o_a2s);
  float* a2d    = (float*)(ws + o_a2d);
  float* qs     = (float*)(ws + o_qs);
  float* qd     = (float*)(ws + o_qd);
  int*   widx   = (int*)(ws + o_widx);
  unsigned short* wch = (unsigned short*)(ws + o_wch);
  unsigned short* wcl = (unsigned short*)(ws + o_wcl);
  unsigned short* w1h = (unsigned short*)(ws + o_w1h);
  unsigned short* w1l = (unsigned short*)(ws + o_w1l);
  unsigned short* w2h = (unsigned short*)(ws + o_w2h);
  unsigned short* w2l = (unsigned short*)(ws + o_w2l);
  unsigned short* p1h = (unsigned short*)(ws + o_p1h);
  unsigned short* p1l = (unsigned short*)(ws + o_p1l);
  float* Xa     = (float*)(ws + o_xa);
  unsigned short* Hb = (unsigned short*)(ws + o_hb);
  float* agg    = (float*)(ws + o_agg);
  float* out2c  = (float*)(ws + o_out2c);
  unsigned short* x1b = (unsigned short*)(ws + o_x1b);

  // one fast grid-strided clear replaces 4 slow runtime fills
  {
    unsigned int offA = (unsigned int)(o_winner >> 2);
    unsigned int nA   = (unsigned int)((o_map - o_winner) / 4 + NN);
    unsigned int offB = (unsigned int)(o_a1s >> 2);
    unsigned int nB   = (unsigned int)((o_a1d - o_a1s) / 4 + (size_t)NN * 2);
    unsigned int offC = (unsigned int)(o_deg >> 2);
    unsigned int nC   = (unsigned int)((o_needed - o_deg) / 4 + NN / 4);
    clear_kernel<<<1024, 256, 0, stream>>>((unsigned int*)ws, offA, nA, offB, nB,
                                           offC, nC, out);
  }

  setup_kernel<<<EB + SPLB + XAB, 256, 0, stream>>>(
      ei, uid, iid, deg, winner,
      wc, wch, wcl, w1, w1h, w1l, w2, w2h, w2l, pw1, p1h, p1l,
      uemb, iemb, Xa, map);
  rowstart_kernel<<<(NN + 255) / 256 + 1, 256, 0, stream>>>(
      deg, winner, iid, rs, fill, cnt, widx, w2, att2s, att2d, qs, qd);
  cembfill_kernel<<<GEMMB + EB, 256, 0, stream>>>(
      wch, wcl, bc, Xa + (size_t)BB * 256 + 128, widx, content,
      ei, fill, col, map, needed);
  // Hb = bf16(Xa @ W1^T), with fused a1 score atomics
  {
    dim3 g(NTASK / 64, 256 / 64);
    gemm_mfma<0, 1><<<g, 256, 0, stream>>>(
        Xa, w1h, w1l, nullptr, nullptr, Hb, 256,
        NTASK, 256, 256, 0, uid, iid, map, nullptr, nullptr,
        att1s, att1d, a1s, a1d);
  }
  conv1_agg_kernel<<<NN / 4, 256, 0, stream>>>(col, rs, deg, Hb, map, needed,
                                               a1s, a1d, b1, qs, qd, x1b, a2s, a2d);
  conv2_agg_kernel<<<NTASK / 4, 256, 0, stream>>>(uid, iid, col, rs, deg, map,
                                                  x1b, a2s, a2d, agg);
  // out2c = agg @ W2^T + b2c
  {
    dim3 g(NTASK / 64, DD / 64);
    gemm_mfma<0, 0><<<g, 256, 0, stream>>>(
        agg, w2h, w2l, b2c, out2c, nullptr, 128,
        NTASK, DD, 256, 0, nullptr, nullptr, nullptr, nullptr, nullptr,
        nullptr, nullptr, nullptr, nullptr);
  }
  // fused: out[b] = relu([uemb|out2c_i|out2c_u] @ pw1^T + pb1) . pw2 + pb2
  {
    dim3 g(BB / 64, DD / 64);
    gemm_mfma<1, 2><<<g, 256, 0, stream>>>(
        nullptr, p1h, p1l, pb1, nullptr, nullptr, 128,
        BB, DD, 384, 0, uid, iid, map, uemb, out2c,
        pw2, pb2, out, nullptr);
  }
}

// Round 15
// 194.980 us; speedup vs baseline: 1.2227x; 1.0057x over previous
//
#include <hip/hip_runtime.h>
#include <hip/hip_bf16.h>

#define NU 50000
#define NI 20000
#define NN 70000
#define DD 128
#define BB 8192
#define EE 500000
#define ET 570000   // EE + NN self loops
#define NTASK 16384 // 2*BB

__device__ __forceinline__ float lrelu(float x) { return x > 0.f ? x : 0.2f * x; }

typedef __attribute__((ext_vector_type(8))) short bf16x8;   // 8 bf16 = 4 VGPRs
typedef __attribute__((ext_vector_type(8))) unsigned short u16x8;
typedef __attribute__((ext_vector_type(4))) float f32x4;

__device__ __forceinline__ unsigned short f2bf_rne(float f) {
  unsigned int u = __builtin_bit_cast(unsigned int, f);
  u += 0x7FFFu + ((u >> 16) & 1u);
  return (unsigned short)(u >> 16);
}
__device__ __forceinline__ float bf2f(unsigned short h) {
  unsigned int u = ((unsigned int)h) << 16;
  return __builtin_bit_cast(float, u);
}

// ---------------- fast workspace clear ----------------
__global__ __launch_bounds__(256) void clear_kernel(
    unsigned int* __restrict__ wsw,
    unsigned int offA, unsigned int nA,
    unsigned int offB, unsigned int nB,
    unsigned int offC, unsigned int nC,
    float* __restrict__ out) {
  unsigned int idx = blockIdx.x * 256 + threadIdx.x;
  unsigned int stride = gridDim.x * 256;
  for (unsigned int i = idx; i < nA; i += stride) wsw[offA + i] = 0xFFFFFFFFu;
  for (unsigned int i = idx; i < nB; i += stride) wsw[offB + i] = 0u;
  for (unsigned int i = idx; i < nC; i += stride) wsw[offC + i] = 0u;
  for (unsigned int i = idx; i < BB; i += stride) out[i] = 0.f;
}

// ---------------- MFMA GEMM core: C[M,N] = A * Bt^T (+bias)(+relu) ----------------
// GATHER=0: A linear. GATHER=1: ph-style 3-section row gather. GATHER=2: row gather
// via idx0. GATHER=3: row gather via mapv[idx0[r]] (content[winner[iid[r]]]).
// MODE=0: f32 C. MODE=1: bf16 Cb + fused a1 attention-score atomics.
// MODE=2: fused final layer: relu(acc+bias) dot att_s(=pw2), + att_d[0](=pb2),
//         atomicAdd into a1s(=out). No C write.
template <int GATHER, int MODE>
__device__ __forceinline__ void gemm_core(
    int bm, int bn,
    const float* __restrict__ A,
    const unsigned short* __restrict__ Bh, const unsigned short* __restrict__ Bl,
    const float* __restrict__ bias, float* __restrict__ C,
    unsigned short* __restrict__ Cb, int ldc,
    int M, int N, int K, int act,
    const int* __restrict__ idx0, const int* __restrict__ idx1,
    const int* __restrict__ mapv,
    const float* __restrict__ gA0, const float* __restrict__ gA1,
    const float* __restrict__ att_s, const float* __restrict__ att_d,
    float* __restrict__ a1s, float* __restrict__ a1d) {
  __shared__ __align__(16) unsigned short sAh[8][64][8];
  __shared__ __align__(16) unsigned short sAl[8][64][8];
  __shared__ __align__(16) unsigned short sBh[8][64][8];
  __shared__ __align__(16) unsigned short sBl[8][64][8];
  int tid = threadIdx.x;
  int lane = tid & 63, w = tid >> 6;
  int wr = (w >> 1) * 32, wc = (w & 1) * 32;
  int fr = lane & 15, fk = lane >> 4;
  f32x4 acc[2][2] = {};

  for (int k0 = 0; k0 < K; k0 += 64) {
    __syncthreads();
#pragma unroll
    for (int t = 0; t < 2; t++) {
      int f = tid + t * 256;
      int row = f >> 3, kb = f & 7;
      int kg = k0 + kb * 8;
      const float* ap;
      if (GATHER == 1) {
        int sec = kg >> 7;           // 64-tiles never straddle 128-col sections
        int kc = kg & 127;
        int r = bm + row;
        if (sec == 0)      ap = &gA0[(size_t)idx0[r] * 128 + kc];
        else if (sec == 1) ap = &gA1[(size_t)mapv[NU + idx1[r]] * 128 + kc];
        else               ap = &gA1[(size_t)mapv[idx0[r]] * 128 + kc];
      } else if (GATHER == 2) {
        ap = &gA0[(size_t)idx0[bm + row] * K + kg];
      } else if (GATHER == 3) {
        ap = &gA0[(size_t)mapv[idx0[bm + row]] * K + kg];
      } else {
        ap = &A[(size_t)(bm + row) * K + kg];
      }
      float4 v0 = *reinterpret_cast<const float4*>(ap);
      float4 v1 = *reinterpret_cast<const float4*>(ap + 4);
      float vv[8] = {v0.x, v0.y, v0.z, v0.w, v1.x, v1.y, v1.z, v1.w};
      u16x8 hv, lv;
#pragma unroll
      for (int j = 0; j < 8; j++) {
        unsigned short hh = f2bf_rne(vv[j]);
        hv[j] = hh;
        lv[j] = (unsigned short)(__builtin_bit_cast(unsigned int, vv[j] - bf2f(hh)) >> 16);
      }
      *reinterpret_cast<u16x8*>(&sAh[kb][row][0]) = hv;
      *reinterpret_cast<u16x8*>(&sAl[kb][row][0]) = lv;
    }
#pragma unroll
    for (int t = 0; t < 2; t++) {
      int f = tid + t * 256;
      int row = f >> 3, kb = f & 7;
      int kg = k0 + kb * 8;
      *reinterpret_cast<u16x8*>(&sBh[kb][row][0]) =
          *reinterpret_cast<const u16x8*>(&Bh[(size_t)(bn + row) * K + kg]);
      *reinterpret_cast<u16x8*>(&sBl[kb][row][0]) =
          *reinterpret_cast<const u16x8*>(&Bl[(size_t)(bn + row) * K + kg]);
    }
    __syncthreads();
#pragma unroll
    for (int s = 0; s < 2; s++) {
      int kb = s * 4 + fk;
      bf16x8 ah0 = *reinterpret_cast<const bf16x8*>(&sAh[kb][wr + fr][0]);
      bf16x8 ah1 = *reinterpret_cast<const bf16x8*>(&sAh[kb][wr + 16 + fr][0]);
      bf16x8 al0 = *reinterpret_cast<const bf16x8*>(&sAl[kb][wr + fr][0]);
      bf16x8 al1 = *reinterpret_cast<const bf16x8*>(&sAl[kb][wr + 16 + fr][0]);
      bf16x8 bh0 = *reinterpret_cast<const bf16x8*>(&sBh[kb][wc + fr][0]);
      bf16x8 bh1 = *reinterpret_cast<const bf16x8*>(&sBh[kb][wc + 16 + fr][0]);
      bf16x8 bl0 = *reinterpret_cast<const bf16x8*>(&sBl[kb][wc + fr][0]);
      bf16x8 bl1 = *reinterpret_cast<const bf16x8*>(&sBl[kb][wc + 16 + fr][0]);
      acc[0][0] = __builtin_amdgcn_mfma_f32_16x16x32_bf16(al0, bh0, acc[0][0], 0, 0, 0);
      acc[0][0] = __builtin_amdgcn_mfma_f32_16x16x32_bf16(ah0, bl0, acc[0][0], 0, 0, 0);
      acc[0][0] = __builtin_amdgcn_mfma_f32_16x16x32_bf16(ah0, bh0, acc[0][0], 0, 0, 0);
      acc[0][1] = __builtin_amdgcn_mfma_f32_16x16x32_bf16(al0, bh1, acc[0][1], 0, 0, 0);
      acc[0][1] = __builtin_amdgcn_mfma_f32_16x16x32_bf16(ah0, bl1, acc[0][1], 0, 0, 0);
      acc[0][1] = __builtin_amdgcn_mfma_f32_16x16x32_bf16(ah0, bh1, acc[0][1], 0, 0, 0);
      acc[1][0] = __builtin_amdgcn_mfma_f32_16x16x32_bf16(al1, bh0, acc[1][0], 0, 0, 0);
      acc[1][0] = __builtin_amdgcn_mfma_f32_16x16x32_bf16(ah1, bl0, acc[1][0], 0, 0, 0);
      acc[1][0] = __builtin_amdgcn_mfma_f32_16x16x32_bf16(ah1, bh0, acc[1][0], 0, 0, 0);
      acc[1][1] = __builtin_amdgcn_mfma_f32_16x16x32_bf16(al1, bh1, acc[1][1], 0, 0, 0);
      acc[1][1] = __builtin_amdgcn_mfma_f32_16x16x32_bf16(ah1, bl1, acc[1][1], 0, 0, 0);
      acc[1][1] = __builtin_amdgcn_mfma_f32_16x16x32_bf16(ah1, bh1, acc[1][1], 0, 0, 0);
    }
  }
  if (MODE == 1) {
    int head = bn >> 7;
    float ps[2][4] = {{0.f}}, pd[2][4] = {{0.f}};
#pragma unroll
    for (int j = 0; j < 2; j++) {
      int col = bn + wc + j * 16 + fr;
      float asc = att_s[col], adc = att_d[col];
#pragma unroll
      for (int i = 0; i < 2; i++) {
#pragma unroll
        for (int r = 0; r < 4; r++) {
          float v = acc[i][j][r];
          ps[i][r] += v * asc;
          pd[i][r] += v * adc;
          Cb[(size_t)(bm + wr + i * 16 + fk * 4 + r) * ldc + col] = f2bf_rne(v);
        }
      }
    }
#pragma unroll
    for (int o = 1; o < 16; o <<= 1) {
#pragma unroll
      for (int i = 0; i < 2; i++)
#pragma unroll
        for (int r = 0; r < 4; r++) {
          ps[i][r] += __shfl_xor(ps[i][r], o);
          pd[i][r] += __shfl_xor(pd[i][r], o);
        }
    }
    if (fr == 0) {
#pragma unroll
      for (int i = 0; i < 2; i++) {
#pragma unroll
        for (int r = 0; r < 4; r++) {
          int t = bm + wr + i * 16 + fk * 4 + r;
          int v = (t < BB) ? idx0[t] : NU + idx1[t - BB];
          if (mapv[v] == t) {   // rep task only (dups would double-count)
            atomicAdd(&a1s[(size_t)v * 2 + head], ps[i][r]);
            atomicAdd(&a1d[(size_t)v * 2 + head], pd[i][r]);
          }
        }
      }
    }
    return;
  }
  if (MODE == 2) {
    float part[2][4] = {{0.f}};
#pragma unroll
    for (int j = 0; j < 2; j++) {
      int col = bn + wc + j * 16 + fr;
      float bj = bias[col];
      float wv = att_s[col];
#pragma unroll
      for (int i = 0; i < 2; i++) {
#pragma unroll
        for (int r = 0; r < 4; r++) {
          float v = fmaxf(acc[i][j][r] + bj, 0.f);
          part[i][r] += v * wv;
        }
      }
    }
#pragma unroll
    for (int o = 1; o < 16; o <<= 1) {
#pragma unroll
      for (int i = 0; i < 2; i++)
#pragma unroll
        for (int r = 0; r < 4; r++) part[i][r] += __shfl_xor(part[i][r], o);
    }
    if (fr == 0) {
#pragma unroll
      for (int i = 0; i < 2; i++) {
#pragma unroll
        for (int r = 0; r < 4; r++) {
          int row = bm + wr + i * 16 + fk * 4 + r;
          float add = part[i][r];
          if (bn == 0 && wc == 0) add += att_d[0];   // pb2 exactly once per row
          atomicAdd(&a1s[row], add);
        }
      }
    }
    return;
  }
#pragma unroll
  for (int j = 0; j < 2; j++) {
    int col = bn + wc + j * 16 + fr;
    float bj = bias ? bias[col] : 0.f;
#pragma unroll
    for (int i = 0; i < 2; i++) {
#pragma unroll
      for (int r = 0; r < 4; r++) {
        int row = bm + wr + i * 16 + fk * 4 + r;
        float v = acc[i][j][r] + bj;
        if (act == 1) v = fmaxf(v, 0.f);
        C[(size_t)row * ldc + col] = v;
      }
    }
  }
}

template <int GATHER, int MODE>
__global__ __launch_bounds__(256) void gemm_mfma(
    const float* __restrict__ A,
    const unsigned short* __restrict__ Bh, const unsigned short* __restrict__ Bl,
    const float* __restrict__ bias, float* __restrict__ C,
    unsigned short* __restrict__ Cb, int ldc,
    int M, int N, int K, int act,
    const int* __restrict__ idx0, const int* __restrict__ idx1,
    const int* __restrict__ mapv,
    const float* __restrict__ gA0, const float* __restrict__ gA1,
    const float* __restrict__ att_s, const float* __restrict__ att_d,
    float* __restrict__ a1s, float* __restrict__ a1d) {
  gemm_core<GATHER, MODE>(blockIdx.x * 64, blockIdx.y * 64,
                          A, Bh, Bl, bias, C, Cb, ldc, M, N, K, act,
                          idx0, idx1, mapv, gA0, gA1, att_s, att_d, a1s, a1d);
}

// ---------------- mega-setup: deg+winner atomics | weight split | Xa-emb+map ------
#define EB 2227    // ceil(ET/256)
#define SPLB 832   // (65536+65536+32768+49152)/256
#define XAB 4096   // NTASK/4
__global__ __launch_bounds__(256) void setup_kernel(
    const int* __restrict__ ei, const int* __restrict__ uid, const int* __restrict__ iid,
    int* __restrict__ deg, int* __restrict__ winner,
    const float* __restrict__ wc, unsigned short* wch, unsigned short* wcl,
    const float* __restrict__ w1, unsigned short* w1h, unsigned short* w1l,
    const float* __restrict__ w2, unsigned short* w2h, unsigned short* w2l,
    const float* __restrict__ pw1, unsigned short* p1h, unsigned short* p1l,
    const float* __restrict__ uemb, const float* __restrict__ iemb,
    float* __restrict__ Xa, int* __restrict__ map) {
  int bid = blockIdx.x, tid = threadIdx.x;
  if (bid < EB) {
    int e = bid * 256 + tid;
    if (e < BB) atomicMax(&winner[iid[e]], e);
    if (e >= ET) return;
    int dst = (e < EE) ? ei[EE + e] : (e - EE);
    atomicAdd(&deg[dst], 1);
    return;
  }
  if (bid < EB + SPLB) {
    int i = (bid - EB) * 256 + tid;
    const float* w; unsigned short* h; unsigned short* l; int idx;
    if (i < 65536) { w = wc; h = wch; l = wcl; idx = i; }
    else if (i < 131072) { w = w1; h = w1h; l = w1l; idx = i - 65536; }
    else if (i < 163840) { w = w2; h = w2h; l = w2l; idx = i - 131072; }
    else { w = pw1; h = p1h; l = p1l; idx = i - 163840; }
    float f = w[idx];
    unsigned short hh = f2bf_rne(f);
    h[idx] = hh;
    l[idx] = (unsigned short)(__builtin_bit_cast(unsigned int, f - bf2f(hh)) >> 16);
    return;
  }
  int t = (bid - EB - SPLB) * 4 + (tid >> 6);
  int lane = tid & 63;
  int c4 = lane * 4;
  if (t < BB) {
    int u = uid[t];
    float4 v = make_float4(0.f, 0.f, 0.f, 0.f);
    if (c4 < DD) v = *reinterpret_cast<const float4*>(&uemb[(size_t)u * DD + c4]);
    *reinterpret_cast<float4*>(&Xa[(size_t)t * 256 + c4]) = v;
    if (lane == 0) map[u] = t;
  } else {
    int it = iid[t - BB];
    if (c4 < DD) {
      float4 v = *reinterpret_cast<const float4*>(&iemb[(size_t)it * DD + c4]);
      *reinterpret_cast<float4*>(&Xa[(size_t)t * 256 + c4]) = v;
    }
    if (lane == 0) map[NU + it] = t;
  }
}

// rowstart scan + qvec + cemb GEMM (content[winner[iid]] gather) in ONE launch.
#define RSB 274     // ceil(NN/256)
#define CEMBB 256   // (BB/64) * (DD/64)
__global__ __launch_bounds__(256) void rowcemb_kernel(
    const int* __restrict__ deg,
    int* __restrict__ rowstart, int* __restrict__ fill, int* __restrict__ counter,
    const float* __restrict__ w2,
    const float* __restrict__ att2s, const float* __restrict__ att2d,
    float* __restrict__ qs, float* __restrict__ qd,
    const unsigned short* __restrict__ wch, const unsigned short* __restrict__ wcl,
    const float* __restrict__ bc, float* __restrict__ XaC,
    const int* __restrict__ iid, const int* __restrict__ winner,
    const float* __restrict__ content) {
  int blk = blockIdx.x;
  if (blk < RSB) {
    int v = blk * 256 + threadIdx.x;
    int lane = threadIdx.x & 63;
    int dv = (v < NN) ? deg[v] : 0;
    int x = dv;
#pragma unroll
    for (int o = 1; o < 64; o <<= 1) {
      int y = __shfl_up(x, o);
      if (lane >= o) x += y;
    }
    int tot = __shfl(x, 63);
    int base = 0;
    if (lane == 63) base = atomicAdd(counter, tot);
    base = __shfl(base, 63);
    if (v < NN) {
      int s = base + x - dv;
      rowstart[v] = s;
      fill[v] = s;
    }
    return;
  }
  if (blk == RSB) {
    int k = threadIdx.x;
    float s = 0.f, d = 0.f;
#pragma unroll 4
    for (int j = 0; j < DD; j++) {
      float w = w2[(size_t)j * 256 + k];
      s += att2s[j] * w;
      d += att2d[j] * w;
    }
    qs[k] = s;
    qd[k] = d;
    return;
  }
  int t = blk - RSB - 1;   // 0..255 cemb GEMM tiles
  gemm_core<3, 0>((t >> 1) * 64, (t & 1) * 64,
                  nullptr, wch, wcl, bc, XaC, nullptr, 256,
                  BB, DD, 512, 0, iid, nullptr, winner, content, nullptr,
                  nullptr, nullptr, nullptr, nullptr);
}

// CSR fill + needed-mark + Hb GEMM (bf16 out, fused a1 scores) in ONE launch.
#define HBB 1024    // (NTASK/64) * (256/64)
__global__ __launch_bounds__(256) void fillhb_kernel(
    const int* __restrict__ ei, int* __restrict__ fill, int* __restrict__ col,
    const int* __restrict__ mapv, unsigned char* __restrict__ needed,
    const float* __restrict__ Xa,
    const unsigned short* __restrict__ w1h, const unsigned short* __restrict__ w1l,
    unsigned short* __restrict__ Hb,
    const int* __restrict__ uid, const int* __restrict__ iid,
    const float* __restrict__ att1s, const float* __restrict__ att1d,
    float* __restrict__ a1s, float* __restrict__ a1d) {
  int bid = blockIdx.x;
  if (bid < EB) {
    int e = bid * 256 + threadIdx.x;
    if (e >= ET) return;
    int src, dst;
    if (e < EE) { src = ei[e]; dst = ei[EE + e]; }
    else { src = e - EE; dst = src; }
    int pos = atomicAdd(&fill[dst], 1);
    col[pos] = src;
    if (mapv[dst] >= 0) needed[src] = 1;
    return;
  }
  int t = bid - EB;   // 0..1023 Hb GEMM tiles
  gemm_core<0, 1>((t >> 2) * 64, (t & 3) * 64,
                  Xa, w1h, w1l, nullptr, nullptr, Hb, 256,
                  NTASK, 256, 256, 0, uid, iid, mapv, nullptr, nullptr,
                  att1s, att1d, a1s, a1d);
}

// conv1 aggregation: bf16 Hb gather, needed-skip, NO-MAX softmax, ballot-compacted
// gather, fused a2 scores.
__global__ __launch_bounds__(256) void conv1_agg_kernel(
    const int* __restrict__ col, const int* __restrict__ rowstart,
    const int* __restrict__ deg, const unsigned short* __restrict__ Hb,
    const int* __restrict__ map, const unsigned char* __restrict__ needed,
    const float* __restrict__ a1s, const float* __restrict__ a1d,
    const float* __restrict__ bias,
    const float* __restrict__ qs, const float* __restrict__ qd,
    unsigned short* __restrict__ x1b, float* __restrict__ a2s, float* __restrict__ a2d) {
  int v = blockIdx.x * 4 + (threadIdx.x >> 6);
  int lane = threadIdx.x & 63;
  if (!needed[v]) return;
  int head = lane >> 5;
  int d = deg[v], s0 = rowstart[v];
  float2 adv = *reinterpret_cast<const float2*>(&a1d[(size_t)v * 2]);
  float4 acc = make_float4(0.f, 0.f, 0.f, 0.f);
  float den0 = 0.f, den1 = 0.f;
  const unsigned short* hb = Hb + (lane << 2);
  for (int c0 = 0; c0 < d; c0 += 64) {
    int i = c0 + lane;
    bool act = i < d;
    int ci = act ? col[s0 + i] : 0;
    float2 asv = make_float2(0.f, 0.f);
    int ri = -1;
    if (act) {
      asv = *reinterpret_cast<const float2*>(&a1s[(size_t)ci * 2]);
      ri = map[ci];
    }
    float ex0 = act ? __expf(lrelu(asv.x + adv.x)) : 0.f;
    float ex1 = act ? __expf(lrelu(asv.y + adv.y)) : 0.f;
    den0 += ex0;
    den1 += ex1;
    unsigned long long msk = __ballot(act && ri >= 0);
    while (msk) {
      int s = __ffsll((unsigned long long)msk) - 1;
      msk &= msk - 1;
      int r = __shfl(ri, s);
      float e0 = __shfl(ex0, s), e1 = __shfl(ex1, s);
      float ex = head ? e1 : e0;
      ushort4 hv = *reinterpret_cast<const ushort4*>(&hb[(size_t)r << 8]);
      acc.x += ex * bf2f(hv.x); acc.y += ex * bf2f(hv.y);
      acc.z += ex * bf2f(hv.z); acc.w += ex * bf2f(hv.w);
    }
  }
#pragma unroll
  for (int o = 1; o < 64; o <<= 1) {
    den0 += __shfl_xor(den0, o);
    den1 += __shfl_xor(den1, o);
  }
  float inv = 1.f / (head ? den1 : den0);
  float4 b4 = *reinterpret_cast<const float4*>(&bias[lane << 2]);
  float4 o;
  o.x = fmaf(acc.x, inv, b4.x);
  o.y = fmaf(acc.y, inv, b4.y);
  o.z = fmaf(acc.z, inv, b4.z);
  o.w = fmaf(acc.w, inv, b4.w);
  o.x = o.x > 0.f ? o.x : __expf(o.x) - 1.f;
  o.y = o.y > 0.f ? o.y : __expf(o.y) - 1.f;
  o.z = o.z > 0.f ? o.z : __expf(o.z) - 1.f;
  o.w = o.w > 0.f ? o.w : __expf(o.w) - 1.f;
  ushort4 st;
  st.x = f2bf_rne(o.x); st.y = f2bf_rne(o.y);
  st.z = f2bf_rne(o.z); st.w = f2bf_rne(o.w);
  *reinterpret_cast<ushort4*>(&x1b[((size_t)v << 8) + (lane << 2)]) = st;
  float4 sv = *reinterpret_cast<const float4*>(&qs[lane << 2]);
  float4 dv = *reinterpret_cast<const float4*>(&qd[lane << 2]);
  float ps = o.x * sv.x + o.y * sv.y + o.z * sv.z + o.w * sv.w;
  float pd = o.x * dv.x + o.y * dv.y + o.z * dv.z + o.w * dv.w;
#pragma unroll
  for (int of = 1; of < 64; of <<= 1) { ps += __shfl_xor(ps, of); pd += __shfl_xor(pd, of); }
  if (lane == 0) { a2s[v] = ps; a2d[v] = pd; }
}

// conv2 aggregation, rep tasks only; NO-MAX softmax; bf16 x1 gather.
__global__ __launch_bounds__(256) void conv2_agg_kernel(
    const int* __restrict__ uid, const int* __restrict__ iid,
    const int* __restrict__ col, const int* __restrict__ rowstart,
    const int* __restrict__ deg, const int* __restrict__ map,
    const unsigned short* __restrict__ x1b,
    const float* __restrict__ a2s, const float* __restrict__ a2d,
    float* __restrict__ agg) {
  int t = blockIdx.x * 4 + (threadIdx.x >> 6);
  int lane = threadIdx.x & 63;
  int v = (t < BB) ? uid[t] : NU + iid[t - BB];
  if (map[v] != t) return;
  int d = deg[v], s0 = rowstart[v];
  float ad = a2d[v];
  float4 acc = make_float4(0.f, 0.f, 0.f, 0.f);
  float den = 0.f;
  const unsigned short* xb = x1b + (lane << 2);
  for (int c0 = 0; c0 < d; c0 += 64) {
    int i = c0 + lane;
    bool act = i < d;
    int ci = act ? col[s0 + i] : 0;
    float as = act ? a2s[ci] : 0.f;
    float ex = act ? __expf(lrelu(as + ad)) : 0.f;
    den += ex;
    int n = min(64, d - c0);
#pragma unroll 2
    for (int i2 = 0; i2 < n; i2++) {
      int r = __shfl(ci, i2);
      float e = __shfl(ex, i2);
      ushort4 hv = *reinterpret_cast<const ushort4*>(&xb[(size_t)r << 8]);
      acc.x += e * bf2f(hv.x); acc.y += e * bf2f(hv.y);
      acc.z += e * bf2f(hv.z); acc.w += e * bf2f(hv.w);
    }
  }
#pragma unroll
  for (int o = 1; o < 64; o <<= 1) den += __shfl_xor(den, o);
  float inv = 1.f / den;
  float4 o = make_float4(acc.x * inv, acc.y * inv, acc.z * inv, acc.w * inv);
  *reinterpret_cast<float4*>(&agg[((size_t)t << 8) + (lane << 2)]) = o;
}

// ---------------- launcher ----------------
extern "C" void kernel_launch(void* const* d_in, const int* in_sizes, int n_in,
                              void* d_out, int out_size, void* d_ws, size_t ws_size,
                              hipStream_t stream) {
  const int* uid = (const int*)d_in[0];
  const int* iid = (const int*)d_in[1];
  const float* content = (const float*)d_in[2];
  const int* ei = (const int*)d_in[3];
  const float* uemb = (const float*)d_in[4];
  const float* iemb = (const float*)d_in[5];
  const float* wc = (const float*)d_in[6];
  const float* bc = (const float*)d_in[7];
  const float* w1 = (const float*)d_in[8];
  const float* att1s = (const float*)d_in[9];
  const float* att1d = (const float*)d_in[10];
  const float* b1 = (const float*)d_in[11];
  const float* w2 = (const float*)d_in[12];
  const float* att2s = (const float*)d_in[13];
  const float* att2d = (const float*)d_in[14];
  const float* b2c = (const float*)d_in[15];
  const float* pw1 = (const float*)d_in[16];
  const float* pb1 = (const float*)d_in[17];
  const float* pw2 = (const float*)d_in[18];
  const float* pb2 = (const float*)d_in[19];
  float* out = (float*)d_out;
  char* ws = (char*)d_ws;

  size_t off = 0;
  auto alloc = [&](size_t bytes) {
    size_t o = off;
    off += (bytes + 255) & ~(size_t)255;
    return o;
  };
  size_t o_winner  = alloc(NI * 4);
  size_t o_map     = alloc(NN * 4);
  size_t o_a1s     = alloc((size_t)NN * 2 * 4);
  size_t o_a1d     = alloc((size_t)NN * 2 * 4);
  size_t o_deg     = alloc(NN * 4);
  size_t o_rs      = alloc(NN * 4);
  size_t o_fill    = alloc(NN * 4);
  size_t o_cnt     = alloc(4);
  size_t o_needed  = alloc(NN);
  size_t o_col     = alloc((size_t)ET * 4);
  size_t o_a2s     = alloc(NN * 4);
  size_t o_a2d     = alloc(NN * 4);
  size_t o_qs      = alloc(256 * 4);
  size_t o_qd      = alloc(256 * 4);
  size_t o_wch = alloc(65536 * 2),  o_wcl = alloc(65536 * 2);
  size_t o_w1h = alloc(65536 * 2),  o_w1l = alloc(65536 * 2);
  size_t o_w2h = alloc(32768 * 2),  o_w2l = alloc(32768 * 2);
  size_t o_p1h = alloc(49152 * 2),  o_p1l = alloc(49152 * 2);
  // region R1 (25.2MB): Xa f32 (16.78M) | Hb bf16 (8.39M)
  size_t o_r1    = alloc(16777216 + 8388608);
  size_t o_xa    = o_r1;
  size_t o_hb    = o_r1 + 16777216;
  size_t o_agg   = o_r1;
  size_t o_out2c = o_r1 + 16777216;
  size_t o_x1b   = alloc((size_t)NN * 256 * 2);
  (void)ws_size; (void)in_sizes; (void)n_in; (void)out_size;

  int*   winner = (int*)(ws + o_winner);
  int*   map    = (int*)(ws + o_map);
  float* a1s    = (float*)(ws + o_a1s);
  float* a1d    = (float*)(ws + o_a1d);
  int*   deg    = (int*)(ws + o_deg);
  int*   rs     = (int*)(ws + o_rs);
  int*   fill   = (int*)(ws + o_fill);
  int*   cnt    = (int*)(ws + o_cnt);
  unsigned char* needed = (unsigned char*)(ws + o_needed);
  int*   col    = (int*)(ws + o_col);
  float* a2s    = (float*)(ws + o_a2s);
  float* a2d    = (float*)(ws + o_a2d);
  float* qs     = (float*)(ws + o_qs);
  float* qd     = (float*)(ws + o_qd);
  unsigned short* wch = (unsigned short*)(ws + o_wch);
  unsigned short* wcl = (unsigned short*)(ws + o_wcl);
  unsigned short* w1h = (unsigned short*)(ws + o_w1h);
  unsigned short* w1l = (unsigned short*)(ws + o_w1l);
  unsigned short* w2h = (unsigned short*)(ws + o_w2h);
  unsigned short* w2l = (unsigned short*)(ws + o_w2l);
  unsigned short* p1h = (unsigned short*)(ws + o_p1h);
  unsigned short* p1l = (unsigned short*)(ws + o_p1l);
  float* Xa     = (float*)(ws + o_xa);
  unsigned short* Hb = (unsigned short*)(ws + o_hb);
  float* agg    = (float*)(ws + o_agg);
  float* out2c  = (float*)(ws + o_out2c);
  unsigned short* x1b = (unsigned short*)(ws + o_x1b);

  // one fast grid-strided clear replaces 4 slow runtime fills
  {
    unsigned int offA = (unsigned int)(o_winner >> 2);
    unsigned int nA   = (unsigned int)((o_map - o_winner) / 4 + NN);
    unsigned int offB = (unsigned int)(o_a1s >> 2);
    unsigned int nB   = (unsigned int)((o_a1d - o_a1s) / 4 + (size_t)NN * 2);
    unsigned int offC = (unsigned int)(o_deg >> 2);
    unsigned int nC   = (unsigned int)((o_needed - o_deg) / 4 + NN / 4);
    clear_kernel<<<1024, 256, 0, stream>>>((unsigned int*)ws, offA, nA, offB, nB,
                                           offC, nC, out);
  }

  setup_kernel<<<EB + SPLB + XAB, 256, 0, stream>>>(
      ei, uid, iid, deg, winner,
      wc, wch, wcl, w1, w1h, w1l, w2, w2h, w2l, pw1, p1h, p1l,
      uemb, iemb, Xa, map);
  // rowstart scan | qvec | cemb GEMM (content gather into Xa's content section)
  rowcemb_kernel<<<RSB + 1 + CEMBB, 256, 0, stream>>>(
      deg, rs, fill, cnt, w2, att2s, att2d, qs, qd,
      wch, wcl, bc, Xa + (size_t)BB * 256 + 128, iid, winner, content);
  // CSR fill + mark | Hb GEMM (bf16 out + fused a1 scores)
  fillhb_kernel<<<EB + HBB, 256, 0, stream>>>(
      ei, fill, col, map, needed, Xa, w1h, w1l, Hb,
      uid, iid, att1s, att1d, a1s, a1d);
  conv1_agg_kernel<<<NN / 4, 256, 0, stream>>>(col, rs, deg, Hb, map, needed,
                                               a1s, a1d, b1, qs, qd, x1b, a2s, a2d);
  conv2_agg_kernel<<<NTASK / 4, 256, 0, stream>>>(uid, iid, col, rs, deg, map,
                                                  x1b, a2s, a2d, agg);
  // out2c = agg @ W2^T + b2c
  {
    dim3 g(NTASK / 64, DD / 64);
    gemm_mfma<0, 0><<<g, 256, 0, stream>>>(
        agg, w2h, w2l, b2c, out2c, nullptr, 128,
        NTASK, DD, 256, 0, nullptr, nullptr, nullptr, nullptr, nullptr,
        nullptr, nullptr, nullptr, nullptr);
  }
  // fused: out[b] = relu([uemb|out2c_i|out2c_u] @ pw1^T + pb1) . pw2 + pb2
  {
    dim3 g(BB / 64, DD / 64);
    gemm_mfma<1, 2><<<g, 256, 0, stream>>>(
        nullptr, p1h, p1l, pb1, nullptr, nullptr, 128,
        BB, DD, 384, 0, uid, iid, map, uemb, out2c,
        pw2, pb2, out, nullptr);
  }
}

// Round 16
// 191.950 us; speedup vs baseline: 1.2420x; 1.0158x over previous
//
#include <hip/hip_runtime.h>
#include <hip/hip_bf16.h>

#define NU 50000
#define NI 20000
#define NN 70000
#define DD 128
#define BB 8192
#define EE 500000
#define ET 570000   // EE + NN self loops
#define NTASK 16384 // 2*BB

__device__ __forceinline__ float lrelu(float x) { return x > 0.f ? x : 0.2f * x; }

typedef __attribute__((ext_vector_type(8))) short bf16x8;   // 8 bf16 = 4 VGPRs
typedef __attribute__((ext_vector_type(8))) unsigned short u16x8;
typedef __attribute__((ext_vector_type(4))) float f32x4;

__device__ __forceinline__ unsigned short f2bf_rne(float f) {
  unsigned int u = __builtin_bit_cast(unsigned int, f);
  u += 0x7FFFu + ((u >> 16) & 1u);
  return (unsigned short)(u >> 16);
}
__device__ __forceinline__ float bf2f(unsigned short h) {
  unsigned int u = ((unsigned int)h) << 16;
  return __builtin_bit_cast(float, u);
}

// ---------------- fast workspace clear ----------------
__global__ __launch_bounds__(256) void clear_kernel(
    unsigned int* __restrict__ wsw,
    unsigned int offA, unsigned int nA,
    unsigned int offB, unsigned int nB,
    unsigned int offC, unsigned int nC,
    float* __restrict__ out) {
  unsigned int idx = blockIdx.x * 256 + threadIdx.x;
  unsigned int stride = gridDim.x * 256;
  for (unsigned int i = idx; i < nA; i += stride) wsw[offA + i] = 0xFFFFFFFFu;
  for (unsigned int i = idx; i < nB; i += stride) wsw[offB + i] = 0u;
  for (unsigned int i = idx; i < nC; i += stride) wsw[offC + i] = 0u;
  for (unsigned int i = idx; i < BB; i += stride) out[i] = 0.f;
}

// ---------------- MFMA GEMM core: C[M,N] = A * Bt^T (+bias)(+relu) ----------------
// GATHER=0: A linear. GATHER=1: ph-style 3-section row gather. GATHER=2: row gather
// via idx0. GATHER=3: row gather via mapv[idx0[r]] (content[winner[iid[r]]]).
// MODE=0: f32 C. MODE=1: bf16 Cb (LDS-staged coalesced stores) + fused a1 scores.
// MODE=2: fused final layer: relu(acc+bias) dot att_s(=pw2), + att_d[0](=pb2),
//         atomicAdd into a1s(=out). No C write.
template <int GATHER, int MODE>
__device__ __forceinline__ void gemm_core(
    int bm, int bn,
    const float* __restrict__ A,
    const unsigned short* __restrict__ Bh, const unsigned short* __restrict__ Bl,
    const float* __restrict__ bias, float* __restrict__ C,
    unsigned short* __restrict__ Cb, int ldc,
    int M, int N, int K, int act,
    const int* __restrict__ idx0, const int* __restrict__ idx1,
    const int* __restrict__ mapv,
    const float* __restrict__ gA0, const float* __restrict__ gA1,
    const float* __restrict__ att_s, const float* __restrict__ att_d,
    float* __restrict__ a1s, float* __restrict__ a1d) {
  __shared__ __align__(16) unsigned short sAh[8][64][8];
  __shared__ __align__(16) unsigned short sAl[8][64][8];
  __shared__ __align__(16) unsigned short sBh[8][64][8];
  __shared__ __align__(16) unsigned short sBl[8][64][8];
  int tid = threadIdx.x;
  int lane = tid & 63, w = tid >> 6;
  int wr = (w >> 1) * 32, wc = (w & 1) * 32;
  int fr = lane & 15, fk = lane >> 4;
  f32x4 acc[2][2] = {};

  for (int k0 = 0; k0 < K; k0 += 64) {
    __syncthreads();
#pragma unroll
    for (int t = 0; t < 2; t++) {
      int f = tid + t * 256;
      int row = f >> 3, kb = f & 7;
      int kg = k0 + kb * 8;
      const float* ap;
      if (GATHER == 1) {
        int sec = kg >> 7;           // 64-tiles never straddle 128-col sections
        int kc = kg & 127;
        int r = bm + row;
        if (sec == 0)      ap = &gA0[(size_t)idx0[r] * 128 + kc];
        else if (sec == 1) ap = &gA1[(size_t)mapv[NU + idx1[r]] * 128 + kc];
        else               ap = &gA1[(size_t)mapv[idx0[r]] * 128 + kc];
      } else if (GATHER == 2) {
        ap = &gA0[(size_t)idx0[bm + row] * K + kg];
      } else if (GATHER == 3) {
        ap = &gA0[(size_t)mapv[idx0[bm + row]] * K + kg];
      } else {
        ap = &A[(size_t)(bm + row) * K + kg];
      }
      float4 v0 = *reinterpret_cast<const float4*>(ap);
      float4 v1 = *reinterpret_cast<const float4*>(ap + 4);
      float vv[8] = {v0.x, v0.y, v0.z, v0.w, v1.x, v1.y, v1.z, v1.w};
      u16x8 hv, lv;
#pragma unroll
      for (int j = 0; j < 8; j++) {
        unsigned short hh = f2bf_rne(vv[j]);
        hv[j] = hh;
        lv[j] = (unsigned short)(__builtin_bit_cast(unsigned int, vv[j] - bf2f(hh)) >> 16);
      }
      *reinterpret_cast<u16x8*>(&sAh[kb][row][0]) = hv;
      *reinterpret_cast<u16x8*>(&sAl[kb][row][0]) = lv;
    }
#pragma unroll
    for (int t = 0; t < 2; t++) {
      int f = tid + t * 256;
      int row = f >> 3, kb = f & 7;
      int kg = k0 + kb * 8;
      *reinterpret_cast<u16x8*>(&sBh[kb][row][0]) =
          *reinterpret_cast<const u16x8*>(&Bh[(size_t)(bn + row) * K + kg]);
      *reinterpret_cast<u16x8*>(&sBl[kb][row][0]) =
          *reinterpret_cast<const u16x8*>(&Bl[(size_t)(bn + row) * K + kg]);
    }
    __syncthreads();
#pragma unroll
    for (int s = 0; s < 2; s++) {
      int kb = s * 4 + fk;
      bf16x8 ah0 = *reinterpret_cast<const bf16x8*>(&sAh[kb][wr + fr][0]);
      bf16x8 ah1 = *reinterpret_cast<const bf16x8*>(&sAh[kb][wr + 16 + fr][0]);
      bf16x8 al0 = *reinterpret_cast<const bf16x8*>(&sAl[kb][wr + fr][0]);
      bf16x8 al1 = *reinterpret_cast<const bf16x8*>(&sAl[kb][wr + 16 + fr][0]);
      bf16x8 bh0 = *reinterpret_cast<const bf16x8*>(&sBh[kb][wc + fr][0]);
      bf16x8 bh1 = *reinterpret_cast<const bf16x8*>(&sBh[kb][wc + 16 + fr][0]);
      bf16x8 bl0 = *reinterpret_cast<const bf16x8*>(&sBl[kb][wc + fr][0]);
      bf16x8 bl1 = *reinterpret_cast<const bf16x8*>(&sBl[kb][wc + 16 + fr][0]);
      acc[0][0] = __builtin_amdgcn_mfma_f32_16x16x32_bf16(al0, bh0, acc[0][0], 0, 0, 0);
      acc[0][0] = __builtin_amdgcn_mfma_f32_16x16x32_bf16(ah0, bl0, acc[0][0], 0, 0, 0);
      acc[0][0] = __builtin_amdgcn_mfma_f32_16x16x32_bf16(ah0, bh0, acc[0][0], 0, 0, 0);
      acc[0][1] = __builtin_amdgcn_mfma_f32_16x16x32_bf16(al0, bh1, acc[0][1], 0, 0, 0);
      acc[0][1] = __builtin_amdgcn_mfma_f32_16x16x32_bf16(ah0, bl1, acc[0][1], 0, 0, 0);
      acc[0][1] = __builtin_amdgcn_mfma_f32_16x16x32_bf16(ah0, bh1, acc[0][1], 0, 0, 0);
      acc[1][0] = __builtin_amdgcn_mfma_f32_16x16x32_bf16(al1, bh0, acc[1][0], 0, 0, 0);
      acc[1][0] = __builtin_amdgcn_mfma_f32_16x16x32_bf16(ah1, bl0, acc[1][0], 0, 0, 0);
      acc[1][0] = __builtin_amdgcn_mfma_f32_16x16x32_bf16(ah1, bh0, acc[1][0], 0, 0, 0);
      acc[1][1] = __builtin_amdgcn_mfma_f32_16x16x32_bf16(al1, bh1, acc[1][1], 0, 0, 0);
      acc[1][1] = __builtin_amdgcn_mfma_f32_16x16x32_bf16(ah1, bl1, acc[1][1], 0, 0, 0);
      acc[1][1] = __builtin_amdgcn_mfma_f32_16x16x32_bf16(ah1, bh1, acc[1][1], 0, 0, 0);
    }
  }
  if (MODE == 1) {
    int head = bn >> 7;
    float ps[2][4] = {{0.f}}, pd[2][4] = {{0.f}};
#pragma unroll
    for (int j = 0; j < 2; j++) {
      int col = bn + wc + j * 16 + fr;
      float asc = att_s[col], adc = att_d[col];
#pragma unroll
      for (int i = 0; i < 2; i++) {
#pragma unroll
        for (int r = 0; r < 4; r++) {
          float v = acc[i][j][r];
          ps[i][r] += v * asc;
          pd[i][r] += v * adc;
        }
      }
    }
    // stage bf16 tile in LDS (reuse sAh: 64x64 ushort = 8KB) for coalesced stores
    unsigned short* sC = &sAh[0][0][0];
    __syncthreads();
#pragma unroll
    for (int j = 0; j < 2; j++)
#pragma unroll
      for (int i = 0; i < 2; i++)
#pragma unroll
        for (int r = 0; r < 4; r++)
          sC[(wr + i * 16 + fk * 4 + r) * 64 + wc + j * 16 + fr] =
              f2bf_rne(acc[i][j][r]);
#pragma unroll
    for (int o = 1; o < 16; o <<= 1) {
#pragma unroll
      for (int i = 0; i < 2; i++)
#pragma unroll
        for (int r = 0; r < 4; r++) {
          ps[i][r] += __shfl_xor(ps[i][r], o);
          pd[i][r] += __shfl_xor(pd[i][r], o);
        }
    }
    if (fr == 0) {
#pragma unroll
      for (int i = 0; i < 2; i++) {
#pragma unroll
        for (int r = 0; r < 4; r++) {
          int t = bm + wr + i * 16 + fk * 4 + r;
          int v = (t < BB) ? idx0[t] : NU + idx1[t - BB];
          if (mapv[v] == t) {   // rep task only (dups would double-count)
            atomicAdd(&a1s[(size_t)v * 2 + head], ps[i][r]);
            atomicAdd(&a1d[(size_t)v * 2 + head], pd[i][r]);
          }
        }
      }
    }
    __syncthreads();
    int row = tid >> 2, cb = (tid & 3) << 4;
    u16x8 v0 = *reinterpret_cast<const u16x8*>(&sC[row * 64 + cb]);
    u16x8 v1 = *reinterpret_cast<const u16x8*>(&sC[row * 64 + cb + 8]);
    *reinterpret_cast<u16x8*>(&Cb[(size_t)(bm + row) * ldc + bn + cb]) = v0;
    *reinterpret_cast<u16x8*>(&Cb[(size_t)(bm + row) * ldc + bn + cb + 8]) = v1;
    return;
  }
  if (MODE == 2) {
    float part[2][4] = {{0.f}};
#pragma unroll
    for (int j = 0; j < 2; j++) {
      int col = bn + wc + j * 16 + fr;
      float bj = bias[col];
      float wv = att_s[col];
#pragma unroll
      for (int i = 0; i < 2; i++) {
#pragma unroll
        for (int r = 0; r < 4; r++) {
          float v = fmaxf(acc[i][j][r] + bj, 0.f);
          part[i][r] += v * wv;
        }
      }
    }
#pragma unroll
    for (int o = 1; o < 16; o <<= 1) {
#pragma unroll
      for (int i = 0; i < 2; i++)
#pragma unroll
        for (int r = 0; r < 4; r++) part[i][r] += __shfl_xor(part[i][r], o);
    }
    if (fr == 0) {
#pragma unroll
      for (int i = 0; i < 2; i++) {
#pragma unroll
        for (int r = 0; r < 4; r++) {
          int row = bm + wr + i * 16 + fk * 4 + r;
          float add = part[i][r];
          if (bn == 0 && wc == 0) add += att_d[0];   // pb2 exactly once per row
          atomicAdd(&a1s[row], add);
        }
      }
    }
    return;
  }
#pragma unroll
  for (int j = 0; j < 2; j++) {
    int col = bn + wc + j * 16 + fr;
    float bj = bias ? bias[col] : 0.f;
#pragma unroll
    for (int i = 0; i < 2; i++) {
#pragma unroll
      for (int r = 0; r < 4; r++) {
        int row = bm + wr + i * 16 + fk * 4 + r;
        float v = acc[i][j][r] + bj;
        if (act == 1) v = fmaxf(v, 0.f);
        C[(size_t)row * ldc + col] = v;
      }
    }
  }
}

template <int GATHER, int MODE>
__global__ __launch_bounds__(256) void gemm_mfma(
    const float* __restrict__ A,
    const unsigned short* __restrict__ Bh, const unsigned short* __restrict__ Bl,
    const float* __restrict__ bias, float* __restrict__ C,
    unsigned short* __restrict__ Cb, int ldc,
    int M, int N, int K, int act,
    const int* __restrict__ idx0, const int* __restrict__ idx1,
    const int* __restrict__ mapv,
    const float* __restrict__ gA0, const float* __restrict__ gA1,
    const float* __restrict__ att_s, const float* __restrict__ att_d,
    float* __restrict__ a1s, float* __restrict__ a1d) {
  gemm_core<GATHER, MODE>(blockIdx.x * 64, blockIdx.y * 64,
                          A, Bh, Bl, bias, C, Cb, ldc, M, N, K, act,
                          idx0, idx1, mapv, gA0, gA1, att_s, att_d, a1s, a1d);
}

// ---------------- mega-setup: deg+winner atomics | weight split | Xa-emb+map ------
#define EB 2227    // ceil(ET/256)
#define SPLB 832   // (65536+65536+32768+49152)/256
#define XAB 4096   // NTASK/4
__global__ __launch_bounds__(256) void setup_kernel(
    const int* __restrict__ ei, const int* __restrict__ uid, const int* __restrict__ iid,
    int* __restrict__ deg, int* __restrict__ winner,
    const float* __restrict__ wc, unsigned short* wch, unsigned short* wcl,
    const float* __restrict__ w1, unsigned short* w1h, unsigned short* w1l,
    const float* __restrict__ w2, unsigned short* w2h, unsigned short* w2l,
    const float* __restrict__ pw1, unsigned short* p1h, unsigned short* p1l,
    const float* __restrict__ uemb, const float* __restrict__ iemb,
    float* __restrict__ Xa, int* __restrict__ map) {
  int bid = blockIdx.x, tid = threadIdx.x;
  if (bid < EB) {
    int e = bid * 256 + tid;
    if (e < BB) atomicMax(&winner[iid[e]], e);
    if (e >= ET) return;
    int dst = (e < EE) ? ei[EE + e] : (e - EE);
    atomicAdd(&deg[dst], 1);
    return;
  }
  if (bid < EB + SPLB) {
    int i = (bid - EB) * 256 + tid;
    const float* w; unsigned short* h; unsigned short* l; int idx;
    if (i < 65536) { w = wc; h = wch; l = wcl; idx = i; }
    else if (i < 131072) { w = w1; h = w1h; l = w1l; idx = i - 65536; }
    else if (i < 163840) { w = w2; h = w2h; l = w2l; idx = i - 131072; }
    else { w = pw1; h = p1h; l = p1l; idx = i - 163840; }
    float f = w[idx];
    unsigned short hh = f2bf_rne(f);
    h[idx] = hh;
    l[idx] = (unsigned short)(__builtin_bit_cast(unsigned int, f - bf2f(hh)) >> 16);
    return;
  }
  int t = (bid - EB - SPLB) * 4 + (tid >> 6);
  int lane = tid & 63;
  int c4 = lane * 4;
  if (t < BB) {
    int u = uid[t];
    float4 v = make_float4(0.f, 0.f, 0.f, 0.f);
    if (c4 < DD) v = *reinterpret_cast<const float4*>(&uemb[(size_t)u * DD + c4]);
    *reinterpret_cast<float4*>(&Xa[(size_t)t * 256 + c4]) = v;
    if (lane == 0) map[u] = t;
  } else {
    int it = iid[t - BB];
    if (c4 < DD) {
      float4 v = *reinterpret_cast<const float4*>(&iemb[(size_t)it * DD + c4]);
      *reinterpret_cast<float4*>(&Xa[(size_t)t * 256 + c4]) = v;
    }
    if (lane == 0) map[NU + it] = t;
  }
}

// rowstart scan + qvec + cemb GEMM (content[winner[iid]] gather) in ONE launch.
#define RSB 274     // ceil(NN/256)
#define CEMBB 256   // (BB/64) * (DD/64)
__global__ __launch_bounds__(256) void rowcemb_kernel(
    const int* __restrict__ deg,
    int* __restrict__ rowstart, int* __restrict__ fill, int* __restrict__ counter,
    const float* __restrict__ w2,
    const float* __restrict__ att2s, const float* __restrict__ att2d,
    float* __restrict__ qs, float* __restrict__ qd,
    const unsigned short* __restrict__ wch, const unsigned short* __restrict__ wcl,
    const float* __restrict__ bc, float* __restrict__ XaC,
    const int* __restrict__ iid, const int* __restrict__ winner,
    const float* __restrict__ content) {
  int blk = blockIdx.x;
  if (blk < RSB) {
    int v = blk * 256 + threadIdx.x;
    int lane = threadIdx.x & 63;
    int dv = (v < NN) ? deg[v] : 0;
    int x = dv;
#pragma unroll
    for (int o = 1; o < 64; o <<= 1) {
      int y = __shfl_up(x, o);
      if (lane >= o) x += y;
    }
    int tot = __shfl(x, 63);
    int base = 0;
    if (lane == 63) base = atomicAdd(counter, tot);
    base = __shfl(base, 63);
    if (v < NN) {
      int s = base + x - dv;
      rowstart[v] = s;
      fill[v] = s;
    }
    return;
  }
  if (blk == RSB) {
    int k = threadIdx.x;
    float s = 0.f, d = 0.f;
#pragma unroll 4
    for (int j = 0; j < DD; j++) {
      float w = w2[(size_t)j * 256 + k];
      s += att2s[j] * w;
      d += att2d[j] * w;
    }
    qs[k] = s;
    qd[k] = d;
    return;
  }
  // cemb GEMM tiles, XCD-grouped: both bn-tiles of one bm on the same XCD
  int t = blk - RSB - 1;       // 0..255
  int rr = t & 7, g = t >> 3;
  int bm64 = rr + ((g >> 1) << 3);   // 0..127
  int bnt = g & 1;
  gemm_core<3, 0>(bm64 * 64, bnt * 64,
                  nullptr, wch, wcl, bc, XaC, nullptr, 256,
                  BB, DD, 512, 0, iid, nullptr, winner, content, nullptr,
                  nullptr, nullptr, nullptr, nullptr);
}

// CSR fill + needed-mark + Hb GEMM (bf16 out, fused a1 scores) in ONE launch.
#define HBB 1024    // (NTASK/64) * (256/64)
__global__ __launch_bounds__(256) void fillhb_kernel(
    const int* __restrict__ ei, int* __restrict__ fill, int* __restrict__ col,
    const int* __restrict__ mapv, unsigned char* __restrict__ needed,
    const float* __restrict__ Xa,
    const unsigned short* __restrict__ w1h, const unsigned short* __restrict__ w1l,
    unsigned short* __restrict__ Hb,
    const int* __restrict__ uid, const int* __restrict__ iid,
    const float* __restrict__ att1s, const float* __restrict__ att1d,
    float* __restrict__ a1s, float* __restrict__ a1d) {
  int bid = blockIdx.x;
  if (bid < EB) {
    int e = bid * 256 + threadIdx.x;
    if (e >= ET) return;
    int src, dst;
    if (e < EE) { src = ei[e]; dst = ei[EE + e]; }
    else { src = e - EE; dst = src; }
    int pos = atomicAdd(&fill[dst], 1);
    col[pos] = src;
    if (mapv[dst] >= 0) needed[src] = 1;
    return;
  }
  // Hb GEMM tiles, XCD-grouped: the 4 bn-tiles of one bm share an XCD ->
  // A panel fetched from HBM once, then L2-hit (same-XCD L2).
  int t = bid - EB;            // 0..1023
  int rr = t & 7, g = t >> 3;
  int bm64 = rr + ((g >> 2) << 3);   // 0..255
  int bnt = g & 3;
  gemm_core<0, 1>(bm64 * 64, bnt * 64,
                  Xa, w1h, w1l, nullptr, nullptr, Hb, 256,
                  NTASK, 256, 256, 0, uid, iid, mapv, nullptr, nullptr,
                  att1s, att1d, a1s, a1d);
}

// conv1 aggregation: bf16 Hb gather, needed-skip, NO-MAX softmax, ballot-compacted
// gather, fused a2 scores.
__global__ __launch_bounds__(256) void conv1_agg_kernel(
    const int* __restrict__ col, const int* __restrict__ rowstart,
    const int* __restrict__ deg, const unsigned short* __restrict__ Hb,
    const int* __restrict__ map, const unsigned char* __restrict__ needed,
    const float* __restrict__ a1s, const float* __restrict__ a1d,
    const float* __restrict__ bias,
    const float* __restrict__ qs, const float* __restrict__ qd,
    unsigned short* __restrict__ x1b, float* __restrict__ a2s, float* __restrict__ a2d) {
  int v = blockIdx.x * 4 + (threadIdx.x >> 6);
  int lane = threadIdx.x & 63;
  if (!needed[v]) return;
  int head = lane >> 5;
  int d = deg[v], s0 = rowstart[v];
  float2 adv = *reinterpret_cast<const float2*>(&a1d[(size_t)v * 2]);
  float4 acc = make_float4(0.f, 0.f, 0.f, 0.f);
  float den0 = 0.f, den1 = 0.f;
  const unsigned short* hb = Hb + (lane << 2);
  for (int c0 = 0; c0 < d; c0 += 64) {
    int i = c0 + lane;
    bool act = i < d;
    int ci = act ? col[s0 + i] : 0;
    float2 asv = make_float2(0.f, 0.f);
    int ri = -1;
    if (act) {
      asv = *reinterpret_cast<const float2*>(&a1s[(size_t)ci * 2]);
      ri = map[ci];
    }
    float ex0 = act ? __expf(lrelu(asv.x + adv.x)) : 0.f;
    float ex1 = act ? __expf(lrelu(asv.y + adv.y)) : 0.f;
    den0 += ex0;
    den1 += ex1;
    unsigned long long msk = __ballot(act && ri >= 0);
    while (msk) {
      int s = __ffsll((unsigned long long)msk) - 1;
      msk &= msk - 1;
      int r = __shfl(ri, s);
      float e0 = __shfl(ex0, s), e1 = __shfl(ex1, s);
      float ex = head ? e1 : e0;
      ushort4 hv = *reinterpret_cast<const ushort4*>(&hb[(size_t)r << 8]);
      acc.x += ex * bf2f(hv.x); acc.y += ex * bf2f(hv.y);
      acc.z += ex * bf2f(hv.z); acc.w += ex * bf2f(hv.w);
    }
  }
#pragma unroll
  for (int o = 1; o < 64; o <<= 1) {
    den0 += __shfl_xor(den0, o);
    den1 += __shfl_xor(den1, o);
  }
  float inv = 1.f / (head ? den1 : den0);
  float4 b4 = *reinterpret_cast<const float4*>(&bias[lane << 2]);
  float4 o;
  o.x = fmaf(acc.x, inv, b4.x);
  o.y = fmaf(acc.y, inv, b4.y);
  o.z = fmaf(acc.z, inv, b4.z);
  o.w = fmaf(acc.w, inv, b4.w);
  o.x = o.x > 0.f ? o.x : __expf(o.x) - 1.f;
  o.y = o.y > 0.f ? o.y : __expf(o.y) - 1.f;
  o.z = o.z > 0.f ? o.z : __expf(o.z) - 1.f;
  o.w = o.w > 0.f ? o.w : __expf(o.w) - 1.f;
  ushort4 st;
  st.x = f2bf_rne(o.x); st.y = f2bf_rne(o.y);
  st.z = f2bf_rne(o.z); st.w = f2bf_rne(o.w);
  *reinterpret_cast<ushort4*>(&x1b[((size_t)v << 8) + (lane << 2)]) = st;
  float4 sv = *reinterpret_cast<const float4*>(&qs[lane << 2]);
  float4 dv = *reinterpret_cast<const float4*>(&qd[lane << 2]);
  float ps = o.x * sv.x + o.y * sv.y + o.z * sv.z + o.w * sv.w;
  float pd = o.x * dv.x + o.y * dv.y + o.z * dv.z + o.w * dv.w;
#pragma unroll
  for (int of = 1; of < 64; of <<= 1) { ps += __shfl_xor(ps, of); pd += __shfl_xor(pd, of); }
  if (lane == 0) { a2s[v] = ps; a2d[v] = pd; }
}

// conv2 aggregation, rep tasks only; NO-MAX softmax; bf16 x1 gather.
__global__ __launch_bounds__(256) void conv2_agg_kernel(
    const int* __restrict__ uid, const int* __restrict__ iid,
    const int* __restrict__ col, const int* __restrict__ rowstart,
    const int* __restrict__ deg, const int* __restrict__ map,
    const unsigned short* __restrict__ x1b,
    const float* __restrict__ a2s, const float* __restrict__ a2d,
    float* __restrict__ agg) {
  int t = blockIdx.x * 4 + (threadIdx.x >> 6);
  int lane = threadIdx.x & 63;
  int v = (t < BB) ? uid[t] : NU + iid[t - BB];
  if (map[v] != t) return;
  int d = deg[v], s0 = rowstart[v];
  float ad = a2d[v];
  float4 acc = make_float4(0.f, 0.f, 0.f, 0.f);
  float den = 0.f;
  const unsigned short* xb = x1b + (lane << 2);
  for (int c0 = 0; c0 < d; c0 += 64) {
    int i = c0 + lane;
    bool act = i < d;
    int ci = act ? col[s0 + i] : 0;
    float as = act ? a2s[ci] : 0.f;
    float ex = act ? __expf(lrelu(as + ad)) : 0.f;
    den += ex;
    int n = min(64, d - c0);
#pragma unroll 2
    for (int i2 = 0; i2 < n; i2++) {
      int r = __shfl(ci, i2);
      float e = __shfl(ex, i2);
      ushort4 hv = *reinterpret_cast<const ushort4*>(&xb[(size_t)r << 8]);
      acc.x += e * bf2f(hv.x); acc.y += e * bf2f(hv.y);
      acc.z += e * bf2f(hv.z); acc.w += e * bf2f(hv.w);
    }
  }
#pragma unroll
  for (int o = 1; o < 64; o <<= 1) den += __shfl_xor(den, o);
  float inv = 1.f / den;
  float4 o = make_float4(acc.x * inv, acc.y * inv, acc.z * inv, acc.w * inv);
  *reinterpret_cast<float4*>(&agg[((size_t)t << 8) + (lane << 2)]) = o;
}

// ---------------- launcher ----------------
extern "C" void kernel_launch(void* const* d_in, const int* in_sizes, int n_in,
                              void* d_out, int out_size, void* d_ws, size_t ws_size,
                              hipStream_t stream) {
  const int* uid = (const int*)d_in[0];
  const int* iid = (const int*)d_in[1];
  const float* content = (const float*)d_in[2];
  const int* ei = (const int*)d_in[3];
  const float* uemb = (const float*)d_in[4];
  const float* iemb = (const float*)d_in[5];
  const float* wc = (const float*)d_in[6];
  const float* bc = (const float*)d_in[7];
  const float* w1 = (const float*)d_in[8];
  const float* att1s = (const float*)d_in[9];
  const float* att1d = (const float*)d_in[10];
  const float* b1 = (const float*)d_in[11];
  const float* w2 = (const float*)d_in[12];
  const float* att2s = (const float*)d_in[13];
  const float* att2d = (const float*)d_in[14];
  const float* b2c = (const float*)d_in[15];
  const float* pw1 = (const float*)d_in[16];
  const float* pb1 = (const float*)d_in[17];
  const float* pw2 = (const float*)d_in[18];
  const float* pb2 = (const float*)d_in[19];
  float* out = (float*)d_out;
  char* ws = (char*)d_ws;

  size_t off = 0;
  auto alloc = [&](size_t bytes) {
    size_t o = off;
    off += (bytes + 255) & ~(size_t)255;
    return o;
  };
  size_t o_winner  = alloc(NI * 4);
  size_t o_map     = alloc(NN * 4);
  size_t o_a1s     = alloc((size_t)NN * 2 * 4);
  size_t o_a1d     = alloc((size_t)NN * 2 * 4);
  size_t o_deg     = alloc(NN * 4);
  size_t o_rs      = alloc(NN * 4);
  size_t o_fill    = alloc(NN * 4);
  size_t o_cnt     = alloc(4);
  size_t o_needed  = alloc(NN);
  size_t o_col     = alloc((size_t)ET * 4);
  size_t o_a2s     = alloc(NN * 4);
  size_t o_a2d     = alloc(NN * 4);
  size_t o_qs      = alloc(256 * 4);
  size_t o_qd      = alloc(256 * 4);
  size_t o_wch = alloc(65536 * 2),  o_wcl = alloc(65536 * 2);
  size_t o_w1h = alloc(65536 * 2),  o_w1l = alloc(65536 * 2);
  size_t o_w2h = alloc(32768 * 2),  o_w2l = alloc(32768 * 2);
  size_t o_p1h = alloc(49152 * 2),  o_p1l = alloc(49152 * 2);
  // region R1 (25.2MB): Xa f32 (16.78M) | Hb bf16 (8.39M)
  size_t o_r1    = alloc(16777216 + 8388608);
  size_t o_xa    = o_r1;
  size_t o_hb    = o_r1 + 16777216;
  size_t o_agg   = o_r1;
  size_t o_out2c = o_r1 + 16777216;
  size_t o_x1b   = alloc((size_t)NN * 256 * 2);
  (void)ws_size; (void)in_sizes; (void)n_in; (void)out_size;

  int*   winner = (int*)(ws + o_winner);
  int*   map    = (int*)(ws + o_map);
  float* a1s    = (float*)(ws + o_a1s);
  float* a1d    = (float*)(ws + o_a1d);
  int*   deg    = (int*)(ws + o_deg);
  int*   rs     = (int*)(ws + o_rs);
  int*   fill   = (int*)(ws + o_fill);
  int*   cnt    = (int*)(ws + o_cnt);
  unsigned char* needed = (unsigned char*)(ws + o_needed);
  int*   col    = (int*)(ws + o_col);
  float* a2s    = (float*)(ws + o_a2s);
  float* a2d    = (float*)(ws + o_a2d);
  float* qs     = (float*)(ws + o_qs);
  float* qd     = (float*)(ws + o_qd);
  unsigned short* wch = (unsigned short*)(ws + o_wch);
  unsigned short* wcl = (unsigned short*)(ws + o_wcl);
  unsigned short* w1h = (unsigned short*)(ws + o_w1h);
  unsigned short* w1l = (unsigned short*)(ws + o_w1l);
  unsigned short* w2h = (unsigned short*)(ws + o_w2h);
  unsigned short* w2l = (unsigned short*)(ws + o_w2l);
  unsigned short* p1h = (unsigned short*)(ws + o_p1h);
  unsigned short* p1l = (unsigned short*)(ws + o_p1l);
  float* Xa     = (float*)(ws + o_xa);
  unsigned short* Hb = (unsigned short*)(ws + o_hb);
  float* agg    = (float*)(ws + o_agg);
  float* out2c  = (float*)(ws + o_out2c);
  unsigned short* x1b = (unsigned short*)(ws + o_x1b);

  // one fast grid-strided clear replaces 4 slow runtime fills
  {
    unsigned int offA = (unsigned int)(o_winner >> 2);
    unsigned int nA   = (unsigned int)((o_map - o_winner) / 4 + NN);
    unsigned int offB = (unsigned int)(o_a1s >> 2);
    unsigned int nB   = (unsigned int)((o_a1d - o_a1s) / 4 + (size_t)NN * 2);
    unsigned int offC = (unsigned int)(o_deg >> 2);
    unsigned int nC   = (unsigned int)((o_needed - o_deg) / 4 + NN / 4);
    clear_kernel<<<1024, 256, 0, stream>>>((unsigned int*)ws, offA, nA, offB, nB,
                                           offC, nC, out);
  }

  setup_kernel<<<EB + SPLB + XAB, 256, 0, stream>>>(
      ei, uid, iid, deg, winner,
      wc, wch, wcl, w1, w1h, w1l, w2, w2h, w2l, pw1, p1h, p1l,
      uemb, iemb, Xa, map);
  // rowstart scan | qvec | cemb GEMM (content gather into Xa's content section)
  rowcemb_kernel<<<RSB + 1 + CEMBB, 256, 0, stream>>>(
      deg, rs, fill, cnt, w2, att2s, att2d, qs, qd,
      wch, wcl, bc, Xa + (size_t)BB * 256 + 128, iid, winner, content);
  // CSR fill + mark | Hb GEMM (bf16 out + fused a1 scores)
  fillhb_kernel<<<EB + HBB, 256, 0, stream>>>(
      ei, fill, col, map, needed, Xa, w1h, w1l, Hb,
      uid, iid, att1s, att1d, a1s, a1d);
  conv1_agg_kernel<<<NN / 4, 256, 0, stream>>>(col, rs, deg, Hb, map, needed,
                                               a1s, a1d, b1, qs, qd, x1b, a2s, a2d);
  conv2_agg_kernel<<<NTASK / 4, 256, 0, stream>>>(uid, iid, col, rs, deg, map,
                                                  x1b, a2s, a2d, agg);
  // out2c = agg @ W2^T + b2c
  {
    dim3 g(NTASK / 64, DD / 64);
    gemm_mfma<0, 0><<<g, 256, 0, stream>>>(
        agg, w2h, w2l, b2c, out2c, nullptr, 128,
        NTASK, DD, 256, 0, nullptr, nullptr, nullptr, nullptr, nullptr,
        nullptr, nullptr, nullptr, nullptr);
  }
  // fused: out[b] = relu([uemb|out2c_i|out2c_u] @ pw1^T + pb1) . pw2 + pb2
  {
    dim3 g(BB / 64, DD / 64);
    gemm_mfma<1, 2><<<g, 256, 0, stream>>>(
        nullptr, p1h, p1l, pb1, nullptr, nullptr, 128,
        BB, DD, 384, 0, uid, iid, map, uemb, out2c,
        pw2, pb2, out, nullptr);
  }
}